// Round 6
// baseline (252.976 us; speedup 1.0000x reference)
//
#include <hip/hip_runtime.h>
#include <math.h>

#define HW   1024
#define NCH  768

typedef __bf16 bf16x8 __attribute__((ext_vector_type(8)));
typedef float f32x4 __attribute__((ext_vector_type(4)));
typedef unsigned short ushort_t;

__device__ __forceinline__ ushort_t f2bf(float f) {
    unsigned u = __builtin_bit_cast(unsigned, f);
    u += 0x7fffu + ((u >> 16) & 1u);           // round-to-nearest-even
    return (ushort_t)(u >> 16);
}
__device__ __forceinline__ float bf2f(ushort_t s) {
    unsigned u = ((unsigned)s) << 16;
    return __builtin_bit_cast(float, u);
}

#define GLOAD16(g, l) __builtin_amdgcn_global_load_lds( \
    (const __attribute__((address_space(1))) void*)(g), \
    (__attribute__((address_space(3))) void*)(l), 16, 0, 0)

// ---------------------------------------------------------------------------
// prep_x: x [img][b][256][32][32] fp32 -> xpadT [slab][34][34][256] bf16.
// (R4 version: halo zeroed by hipMemsetAsync before this kernel.)
// ---------------------------------------------------------------------------
__global__ __launch_bounds__(256) void prep_x_kernel(
    const float* __restrict__ x1, const float* __restrict__ x2, const float* __restrict__ x12,
    ushort_t* __restrict__ xpadT)
{
    const int row  = blockIdx.x;
    const int slab = blockIdx.y;
    const int img  = slab >> 2, b = slab & 3;
    const float* x  = (img == 0) ? x1 : (img == 1) ? x2 : x12;
    const float* xb = x + (size_t)b * 256 * HW + row * 32;

    __shared__ float xs[32][257];
    const int tid = threadIdx.x;
    for (int idx = tid; idx < 256 * 32; idx += 256) {
        int ci = idx >> 5, col = idx & 31;
        xs[col][ci] = xb[(size_t)ci * HW + col];
    }
    __syncthreads();
    ushort_t* ob = xpadT + ((size_t)slab * 34 * 34 + (size_t)(row + 1) * 34 + 1) * 256;
    for (int col = 0; col < 32; ++col)
        ob[(size_t)col * 256 + tid] = f2bf(xs[col][tid]);
}

// ---------------------------------------------------------------------------
// prep_w: pre-swizzled bf16 A-tiles for conv (unchanged).
// ---------------------------------------------------------------------------
__global__ __launch_bounds__(256) void prep_w_kernel(
    const float* __restrict__ W1, const float* __restrict__ W2, const float* __restrict__ W3,
    ushort_t* __restrict__ Wb)
{
    int g = blockIdx.x * 256 + threadIdx.x;
    if (g >= 3 * 768 * 256) return;
    int ci  = g & 255;
    int co  = (g >> 8) % 768;
    int img = g / (768 * 256);
    const float* Wt  = (img == 0) ? W1 : (img == 1) ? W2 : W3;
    const float* src = Wt + (size_t)co * (256 * 9) + ci * 9;

    int coc = co >> 7, row = co & 127;
    int cic = ci >> 5;
    int cil = ci & 31;
    int s = cil >> 3, e = cil & 7;
    int phys  = s ^ ((row ^ (row >> 2)) & 3);
    int inner = row * 32 + phys * 8 + e;
    #pragma unroll
    for (int t = 0; t < 9; ++t) {
        size_t tile = (((size_t)img * 9 + t) * 8 + cic) * 6 + coc;
        Wb[tile * 4096 + inner] = f2bf(src[t]);
    }
}

// ---------------------------------------------------------------------------
// conv_mfma: implicit-GEMM 3x3 conv. B-staging addresses hoisted to
// loop-invariant pixoff[r] + uniform per-iter koff (addresses identical to R4).
// Outputs: ch<256 -> Qf fp32 (bias+q-scale), 256-511 -> Kb bf16, 512-767 -> Vb.
// ---------------------------------------------------------------------------
__global__ __launch_bounds__(256) void conv_mfma_kernel(
    const ushort_t* __restrict__ Wb, const ushort_t* __restrict__ xpadT,
    const float* __restrict__ B1, const float* __restrict__ B2, const float* __restrict__ B3,
    float* __restrict__ Qf, ushort_t* __restrict__ Kb, ushort_t* __restrict__ Vb)
{
    const int bx   = blockIdx.x;
    const int by   = blockIdx.y;
    const int slab = blockIdx.z;
    const int img  = slab >> 2;
    const float* Bs_bias = (img == 0) ? B1 : (img == 1) ? B2 : B3;

    __shared__ ushort_t As[2][4096];
    __shared__ ushort_t Bsh[2][4096];

    const int tid  = threadIdx.x;
    const int lane = tid & 63;
    const int wid  = tid >> 6;
    const int wr   = wid >> 1, wc = wid & 1;

    const ushort_t* WbI = Wb + (size_t)img * 9 * 8 * 6 * 4096;
    const ushort_t* xpI = xpadT + (size_t)slab * 34 * 34 * 256;
    const int r0 = bx * 4;

    // loop-invariant staging offsets
    size_t pixoff[2];
    #pragma unroll
    for (int r = 0; r < 2; ++r) {
        int o    = r * 4096 + tid * 16;
        int p    = o >> 6;
        int phys = (o >> 4) & 3;
        int s    = phys ^ ((p ^ (p >> 2)) & 3);
        int pr   = p >> 5, c = p & 31;
        pixoff[r] = ((size_t)((r0 + pr) * 34 + c)) * 256 + s * 8;
    }

    f32x4 acc[4][4];
    #pragma unroll
    for (int m = 0; m < 4; ++m)
        #pragma unroll
        for (int n = 0; n < 4; ++n) acc[m][n] = (f32x4){0.f, 0.f, 0.f, 0.f};

    int aoff[4], boff[4];
    #pragma unroll
    for (int m = 0; m < 4; ++m) {
        int row  = wr * 64 + m * 16 + (lane & 15);
        int phys = (lane >> 4) ^ ((row ^ (row >> 2)) & 3);
        aoff[m] = row * 32 + phys * 8;
    }
    #pragma unroll
    for (int n = 0; n < 4; ++n) {
        int row  = wc * 64 + n * 16 + (lane & 15);
        int phys = (lane >> 4) ^ ((row ^ (row >> 2)) & 3);
        boff[n] = row * 32 + phys * 8;
    }

    auto stage = [&](int kk, int buf) {
        int t = kk >> 3, cic = kk & 7;
        int dy = t / 3, dx = t - dy * 3;
        int koff = (dy * 34 + dx) * 256 + cic * 32;              // wave-uniform
        const ushort_t* wtile = WbI + ((size_t)(t * 8 + cic) * 6 + by) * 4096;
        #pragma unroll
        for (int r = 0; r < 2; ++r)
            GLOAD16(wtile + r * 2048 + tid * 8, (ushort_t*)As[buf] + r * 2048 + tid * 8);
        #pragma unroll
        for (int r = 0; r < 2; ++r)
            GLOAD16(xpI + pixoff[r] + koff, (ushort_t*)Bsh[buf] + r * 2048 + tid * 8);
    };

    stage(0, 0);
    asm volatile("s_waitcnt vmcnt(0)" ::: "memory");
    __builtin_amdgcn_s_barrier();

    for (int kk = 0; kk < 72; ++kk) {
        int cur = kk & 1;
        if (kk < 71) stage(kk + 1, cur ^ 1);

        const ushort_t* Ab = As[cur];
        const ushort_t* Bb = Bsh[cur];
        bf16x8 af[4], bfr[4];
        #pragma unroll
        for (int m = 0; m < 4; ++m) af[m] = *(const bf16x8*)(Ab + aoff[m]);
        #pragma unroll
        for (int n = 0; n < 4; ++n) bfr[n] = *(const bf16x8*)(Bb + boff[n]);

        #pragma unroll
        for (int m = 0; m < 4; ++m)
            #pragma unroll
            for (int n = 0; n < 4; ++n)
                acc[m][n] = __builtin_amdgcn_mfma_f32_16x16x32_bf16(af[m], bfr[n], acc[m][n], 0, 0, 0);

        asm volatile("s_waitcnt vmcnt(0)" ::: "memory");
        __builtin_amdgcn_s_barrier();
    }

    const int co_base = by * 128 + wr * 64;
    const int p_base  = bx * 128 + wc * 64;
    const int rsub = (lane >> 4) * 4;
    const int csub = lane & 15;
    #pragma unroll
    for (int m = 0; m < 4; ++m) {
        #pragma unroll
        for (int rg = 0; rg < 4; ++rg) {
            int ch = co_base + m * 16 + rsub + rg;
            float bias = Bs_bias[ch];
            #pragma unroll
            for (int nn = 0; nn < 4; ++nn) {
                int p = p_base + nn * 16 + csub;
                float v = acc[m][nn][rg] + bias;
                if (ch < 256)
                    Qf[((size_t)slab * 256 + ch) * HW + p] = v * 0.17677669529663687f;
                else if (ch < 512)
                    Kb[((size_t)slab * 256 + (ch - 256)) * HW + p] = f2bf(v);
                else
                    Vb[((size_t)slab * 256 + (ch - 512)) * HW + p] = f2bf(v);
            }
        }
    }
}

// ---------------------------------------------------------------------------
// trans_kernel: build attention MFMA operand tensors (R4 exact).
// ---------------------------------------------------------------------------
__global__ __launch_bounds__(256) void trans_kernel(
    const float* __restrict__ Qf, const ushort_t* __restrict__ Kb,
    ushort_t* __restrict__ QThi, ushort_t* __restrict__ QTlo,
    ushort_t* __restrict__ K12T, ushort_t* __restrict__ KdT)
{
    const int z  = blockIdx.y;
    const int k0 = blockIdx.x * 256;
    const int tid = threadIdx.x;
    __shared__ float ts[32][257];

    if (z < 96) {
        int slab = z >> 3, n = z & 7;
        const float* src = Qf + ((size_t)slab * 256 + n * 32) * HW + k0;
        for (int idx = tid; idx < 8192; idx += 256) {
            int d = idx >> 8, k = idx & 255;
            ts[d][k] = src[(size_t)d * HW + k];
        }
        __syncthreads();
        ushort_t* dh = QThi + (size_t)z * 32768 + (size_t)k0 * 32;
        ushort_t* dl = QTlo + (size_t)z * 32768 + (size_t)k0 * 32;
        for (int idx = tid; idx < 8192; idx += 256) {
            int k = idx >> 5, d = idx & 31;
            float v = ts[d][k];
            ushort_t hi = f2bf(v);
            dh[(size_t)k * 32 + d] = hi;
            dl[(size_t)k * 32 + d] = f2bf(v - bf2f(hi));
        }
    } else if (z < 128) {
        int bn = z - 96, b = bn >> 3, n = bn & 7;
        const ushort_t* src = Kb + ((size_t)(8 + b) * 256 + n * 32) * HW + k0;
        for (int idx = tid; idx < 8192; idx += 256) {
            int d = idx >> 8, k = idx & 255;
            ts[d][k] = bf2f(src[(size_t)d * HW + k]);
        }
        __syncthreads();
        ushort_t* dst = K12T + (size_t)bn * 32768 + (size_t)k0 * 32;
        for (int idx = tid; idx < 8192; idx += 256) {
            int k = idx >> 5, d = idx & 31;
            dst[(size_t)k * 32 + d] = f2bf(ts[d][k]);
        }
    } else {
        int bn = z - 128, b = bn >> 3, n = bn & 7;
        const ushort_t* sA = Kb + ((size_t)b * 256 + n * 32) * HW + k0;
        const ushort_t* sB = Kb + ((size_t)(4 + b) * 256 + n * 32) * HW + k0;
        for (int idx = tid; idx < 8192; idx += 256) {
            int d = idx >> 8, k = idx & 255;
            ts[d][k] = bf2f(sA[(size_t)d * HW + k]) - bf2f(sB[(size_t)d * HW + k]);
        }
        __syncthreads();
        ushort_t* dst = KdT + (size_t)bn * 32768 + (size_t)k0 * 32;
        for (int idx = tid; idx < 8192; idx += 256) {
            int k = idx >> 5, d = idx & 31;
            dst[(size_t)k * 32 + d] = f2bf(ts[d][k]);
        }
    }
}

// ---------------------------------------------------------------------------
// rel_kernel: RW'/RH' tables from FP32 Q. grid (4 qchunk, 2 mhalf, 32 bn):
// the two mhalf blocks write disjoint mm ranges, same per-mm FMA order.
// ---------------------------------------------------------------------------
__global__ __launch_bounds__(256) void rel_kernel(
    const float* __restrict__ Qf,
    const float* __restrict__ krw, const float* __restrict__ krh,
    float* __restrict__ RWp, float* __restrict__ RHp)
{
    const int tid = threadIdx.x;
    const int mh  = blockIdx.y;        // 0/1 -> m range [16mh, 16mh+16)
    const int bn  = blockIdx.z;
    const int b   = bn >> 3, n = bn & 7;
    const int q   = blockIdx.x * 256 + tid;
    const int r   = q >> 5, c = q & 31;

    __shared__ float rwl[63 * 33 + 1];
    __shared__ float rhl[63 * 33 + 1];
    for (int idx = tid; idx < 63 * 32; idx += 256) {
        int mp = idx >> 5, d = idx & 31;
        rwl[mp * 33 + d] = krw[idx];
        rhl[mp * 33 + d] = krh[idx];
    }
    __syncthreads();

    float qv[32];
    const float* qp = Qf + ((size_t)b * 256 + n * 32) * HW;   // img0 slab = b
    #pragma unroll
    for (int d = 0; d < 32; ++d) qv[d] = qp[(size_t)d * HW + q];

    float* rw = RWp + ((size_t)bn * 1024 + q) * 32;
    float* rh = RHp + ((size_t)bn * 1024 + q) * 32;
    #pragma unroll
    for (int m = 0; m < 16; ++m) {
        int mm = mh * 16 + m;
        const float* t1 = rwl + (mm + 31 - c) * 33;
        const float* t2 = rhl + (mm + 31 - r) * 33;
        float s1 = 0.f, s2 = 0.f;
        #pragma unroll
        for (int d = 0; d < 32; ++d) { s1 = fmaf(qv[d], t1[d], s1); s2 = fmaf(qv[d], t2[d], s2); }
        rw[mm] = s1;
        rh[mm] = s2;
    }
}

// ---------------------------------------------------------------------------
// attn_mfma: R4 EXACT. Flash attention, swapped operands (S^T = K x Q),
// Q hi/lo split via LDS staging, P hi/lo split LDS round-trip.
// ---------------------------------------------------------------------------
__global__ __launch_bounds__(256) void attn_mfma_kernel(
    const ushort_t* __restrict__ QThi, const ushort_t* __restrict__ QTlo,
    const ushort_t* __restrict__ K12T, const ushort_t* __restrict__ KdT,
    const ushort_t* __restrict__ Vb,
    const float* __restrict__ RWp, const float* __restrict__ RHp,
    float* __restrict__ yw)
{
    const int qt = blockIdx.x;
    const int bn = blockIdx.y;
    const int br = blockIdx.z;
    const int b  = bn >> 3, n = bn & 7;
    const int tid = threadIdx.x, lane = tid & 63, wid = tid >> 6;
    const int q0 = qt * 128;

    __shared__ ushort_t qt_l[2][4096];     // [hi/lo][128 q][32 d] linear
    __shared__ ushort_t kt_l[2][2048];     // [64 k][32 d] linear (dbuf)
    __shared__ ushort_t v_l[2][2048];      // [32 d][64 k], chunk^(d&7) (dbuf)
    __shared__ ushort_t p_l[4][4096];      // per-wave [hi | lo], each [32 q][64 k]

    const int slab = br * 4 + b;
    const size_t qoff = ((size_t)(slab * 8 + n) * 1024 + q0) * 32;
    const ushort_t* KTb = ((br == 2) ? KdT : K12T) + (size_t)bn * 32768;
    const ushort_t* Vg  = Vb + ((size_t)slab * 256 + n * 32) * HW;

    GLOAD16((const char*)(QThi + qoff) + tid * 16,        (char*)qt_l[0] + tid * 16);
    GLOAD16((const char*)(QThi + qoff) + 4096 + tid * 16, (char*)qt_l[0] + 4096 + tid * 16);
    GLOAD16((const char*)(QTlo + qoff) + tid * 16,        (char*)qt_l[1] + tid * 16);
    GLOAD16((const char*)(QTlo + qoff) + 4096 + tid * 16, (char*)qt_l[1] + 4096 + tid * 16);

    const int vd = tid >> 3, vpc = tid & 7;
    const char* Vrow = (const char*)Vg + (size_t)vd * 2048 + ((vpc ^ (vd & 7)) * 16);
    auto stage = [&](int t, int buf) {
        GLOAD16((const char*)KTb + t * 4096 + tid * 16, (char*)kt_l[buf] + tid * 16);
        GLOAD16(Vrow + t * 128,                          (char*)v_l[buf] + tid * 16);
    };
    stage(0, 0);

    float rwc[2][8];
    if (br == 0) {
        #pragma unroll
        for (int m = 0; m < 2; ++m) {
            int q = q0 + wid * 32 + m * 16 + (lane & 15);
            const float* rwp = RWp + ((size_t)bn * 1024 + q) * 32;
            #pragma unroll
            for (int i = 0; i < 2; ++i)
                #pragma unroll
                for (int r = 0; r < 4; ++r)
                    rwc[m][i * 4 + r] = rwp[i * 16 + 4 * (lane >> 4) + r];
        }
    }

    asm volatile("s_waitcnt vmcnt(0)" ::: "memory");
    __builtin_amdgcn_s_barrier();

    bf16x8 qfh[2], qfl[2];
    #pragma unroll
    for (int m = 0; m < 2; ++m) {
        int off = (wid * 32 + m * 16 + (lane & 15)) * 32 + (lane >> 4) * 8;
        qfh[m] = *(const bf16x8*)(qt_l[0] + off);
        qfl[m] = *(const bf16x8*)(qt_l[1] + off);
    }

    f32x4 oacc[2][2];
    #pragma unroll
    for (int ds = 0; ds < 2; ++ds)
        #pragma unroll
        for (int m = 0; m < 2; ++m) oacc[ds][m] = (f32x4){0.f, 0.f, 0.f, 0.f};
    float m_run[2] = {-INFINITY, -INFINITY}, l_run[2] = {0.f, 0.f};
    const f32x4 zero4 = (f32x4){0.f, 0.f, 0.f, 0.f};

    for (int t = 0; t < 16; ++t) {
        int cur = t & 1;

        float rh[2][2];
        if (br == 0) {
            #pragma unroll
            for (int m = 0; m < 2; ++m) {
                int q = q0 + wid * 32 + m * 16 + (lane & 15);
                const float* rhp = RHp + ((size_t)bn * 1024 + q) * 32 + 2 * t;
                rh[m][0] = rhp[0];
                rh[m][1] = rhp[1];
            }
        }
        if (t < 15) stage(t + 1, cur ^ 1);

        bf16x8 kf[4];
        #pragma unroll
        for (int s = 0; s < 4; ++s)
            kf[s] = *(const bf16x8*)(kt_l[cur] + (s * 16 + (lane & 15)) * 32 + (lane >> 4) * 8);

        f32x4 sa[4][2];
        #pragma unroll
        for (int s = 0; s < 4; ++s)
            #pragma unroll
            for (int m = 0; m < 2; ++m) {
                sa[s][m] = __builtin_amdgcn_mfma_f32_16x16x32_bf16(kf[s], qfl[m], zero4, 0, 0, 0);
                sa[s][m] = __builtin_amdgcn_mfma_f32_16x16x32_bf16(kf[s], qfh[m], sa[s][m], 0, 0, 0);
            }

        if (br == 0) {
            #pragma unroll
            for (int s = 0; s < 4; ++s)
                #pragma unroll
                for (int m = 0; m < 2; ++m)
                    #pragma unroll
                    for (int r = 0; r < 4; ++r)
                        sa[s][m][r] += rwc[m][(s & 1) * 4 + r] + rh[m][s >> 1];
        }

        #pragma unroll
        for (int m = 0; m < 2; ++m) {
            float mx = sa[0][m][0];
            #pragma unroll
            for (int s = 0; s < 4; ++s)
                #pragma unroll
                for (int r = 0; r < 4; ++r) mx = fmaxf(mx, sa[s][m][r]);
            mx = fmaxf(mx, __shfl_xor(mx, 16));
            mx = fmaxf(mx, __shfl_xor(mx, 32));
            float mnew = fmaxf(m_run[m], mx);
            float sc = __expf(m_run[m] - mnew);
            float ps = 0.f;
            #pragma unroll
            for (int s = 0; s < 4; ++s)
                #pragma unroll
                for (int r = 0; r < 4; ++r) {
                    float p = __expf(sa[s][m][r] - mnew);
                    sa[s][m][r] = p;
                    ps += p;
                }
            ps += __shfl_xor(ps, 16);
            ps += __shfl_xor(ps, 32);
            l_run[m] = l_run[m] * sc + ps;
            m_run[m] = mnew;
            oacc[0][m] = oacc[0][m] * sc;
            oacc[1][m] = oacc[1][m] * sc;
        }

        // P -> bf16 hi/lo -> per-wave LDS (chunk-XOR swizzle)
        const int g = lane >> 4;
        #pragma unroll
        for (int s = 0; s < 4; ++s)
            #pragma unroll
            for (int m = 0; m < 2; ++m) {
                int qrow = m * 16 + (lane & 15);
                int chunk = (2 * s + (g >> 1)) ^ (qrow & 7);
                char* basep = (char*)p_l[wid] + qrow * 128 + chunk * 16 + 8 * (g & 1);
                #pragma unroll
                for (int h = 0; h < 2; ++h) {
                    float pa = sa[s][m][2 * h], pb = sa[s][m][2 * h + 1];
                    ushort_t ha = f2bf(pa), hb = f2bf(pb);
                    ushort_t la = f2bf(pa - bf2f(ha)), lb = f2bf(pb - bf2f(hb));
                    *(unsigned*)(basep + 4 * h)        = (unsigned)ha | ((unsigned)hb << 16);
                    *(unsigned*)(basep + 4096 + 4 * h) = (unsigned)la | ((unsigned)lb << 16);
                }
            }

        // PV: O^T += V^T x (P_hi + P_lo)
        #pragma unroll
        for (int ks = 0; ks < 2; ++ks) {
            bf16x8 vf[2], pfh[2], pfl[2];
            #pragma unroll
            for (int ds = 0; ds < 2; ++ds) {
                int drow = ds * 16 + (lane & 15);
                int chunk = (4 * ks + g) ^ (drow & 7);
                vf[ds] = *(const bf16x8*)((char*)v_l[cur] + drow * 128 + chunk * 16);
            }
            #pragma unroll
            for (int m = 0; m < 2; ++m) {
                int qrow = m * 16 + (lane & 15);
                int chunk = (4 * ks + g) ^ (qrow & 7);
                pfh[m] = *(const bf16x8*)((char*)p_l[wid] + qrow * 128 + chunk * 16);
                pfl[m] = *(const bf16x8*)((char*)p_l[wid] + 4096 + qrow * 128 + chunk * 16);
            }
            #pragma unroll
            for (int ds = 0; ds < 2; ++ds)
                #pragma unroll
                for (int m = 0; m < 2; ++m) {
                    oacc[ds][m] = __builtin_amdgcn_mfma_f32_16x16x32_bf16(vf[ds], pfh[m], oacc[ds][m], 0, 0, 0);
                    oacc[ds][m] = __builtin_amdgcn_mfma_f32_16x16x32_bf16(vf[ds], pfl[m], oacc[ds][m], 0, 0, 0);
                }
        }

        asm volatile("s_waitcnt vmcnt(0)" ::: "memory");
        __builtin_amdgcn_s_barrier();
    }

    #pragma unroll
    for (int m = 0; m < 2; ++m) {
        float inv = 1.0f / l_run[m];
        int q = q0 + wid * 32 + m * 16 + (lane & 15);
        int rr = q >> 5, cc = q & 31;
        float* yb = yw + ((size_t)((br * 4 + b) * 256 + n * 32 + rr)) * HW + cc * 32;
        #pragma unroll
        for (int ds = 0; ds < 2; ++ds) {
            int dbase = ds * 16 + (lane >> 4) * 4;
            float4 o = make_float4(oacc[ds][m][0] * inv, oacc[ds][m][1] * inv,
                                   oacc[ds][m][2] * inv, oacc[ds][m][3] * inv);
            *reinterpret_cast<float4*>(yb + dbase) = o;
        }
    }
}

// ---------------------------------------------------------------------------
// conv1x1: 512-pixel tile, 2 pixels/thread, ci-chunks of 16.
// grid (16 co-tiles, 2 p-tiles, 12 slabs), block 256.
// ---------------------------------------------------------------------------
__global__ __launch_bounds__(256) void conv1x1_kernel(
    const float* __restrict__ yw, const float* __restrict__ Wo,
    const float* __restrict__ bo, float* __restrict__ out)
{
    const int co0  = blockIdx.x * 16;
    const int p0   = blockIdx.y * 512;
    const int slab = blockIdx.z;
    const float* yb = yw + (size_t)slab * 256 * HW;
    float* ob       = out + (size_t)slab * 256 * HW;

    __shared__ float ys[16][512];
    __shared__ float wsl[16][16];

    const int tid = threadIdx.x;
    float acc0[16], acc1[16];
    #pragma unroll
    for (int co = 0; co < 16; ++co) { acc0[co] = 0.f; acc1[co] = 0.f; }

    for (int ci0 = 0; ci0 < 256; ci0 += 16) {
        __syncthreads();
        for (int idx = tid; idx < 16 * 512; idx += 256) {
            int ci = idx >> 9, p = idx & 511;
            ys[ci][p] = yb[(size_t)(ci0 + ci) * HW + p0 + p];
        }
        {
            int ci = tid >> 4, co = tid & 15;
            wsl[ci][co] = Wo[(size_t)(co0 + co) * 256 + ci0 + ci];
        }
        __syncthreads();
        #pragma unroll
        for (int ci = 0; ci < 16; ++ci) {
            float xv0 = ys[ci][tid];
            float xv1 = ys[ci][tid + 256];
            const float4* wp = reinterpret_cast<const float4*>(&wsl[ci][0]);
            float4 w0 = wp[0], w1 = wp[1], w2 = wp[2], w3 = wp[3];
            acc0[0]  = fmaf(w0.x, xv0, acc0[0]);  acc1[0]  = fmaf(w0.x, xv1, acc1[0]);
            acc0[1]  = fmaf(w0.y, xv0, acc0[1]);  acc1[1]  = fmaf(w0.y, xv1, acc1[1]);
            acc0[2]  = fmaf(w0.z, xv0, acc0[2]);  acc1[2]  = fmaf(w0.z, xv1, acc1[2]);
            acc0[3]  = fmaf(w0.w, xv0, acc0[3]);  acc1[3]  = fmaf(w0.w, xv1, acc1[3]);
            acc0[4]  = fmaf(w1.x, xv0, acc0[4]);  acc1[4]  = fmaf(w1.x, xv1, acc1[4]);
            acc0[5]  = fmaf(w1.y, xv0, acc0[5]);  acc1[5]  = fmaf(w1.y, xv1, acc1[5]);
            acc0[6]  = fmaf(w1.z, xv0, acc0[6]);  acc1[6]  = fmaf(w1.z, xv1, acc1[6]);
            acc0[7]  = fmaf(w1.w, xv0, acc0[7]);  acc1[7]  = fmaf(w1.w, xv1, acc1[7]);
            acc0[8]  = fmaf(w2.x, xv0, acc0[8]);  acc1[8]  = fmaf(w2.x, xv1, acc1[8]);
            acc0[9]  = fmaf(w2.y, xv0, acc0[9]);  acc1[9]  = fmaf(w2.y, xv1, acc1[9]);
            acc0[10] = fmaf(w2.z, xv0, acc0[10]); acc1[10] = fmaf(w2.z, xv1, acc1[10]);
            acc0[11] = fmaf(w2.w, xv0, acc0[11]); acc1[11] = fmaf(w2.w, xv1, acc1[11]);
            acc0[12] = fmaf(w3.x, xv0, acc0[12]); acc1[12] = fmaf(w3.x, xv1, acc1[12]);
            acc0[13] = fmaf(w3.y, xv0, acc0[13]); acc1[13] = fmaf(w3.y, xv1, acc1[13]);
            acc0[14] = fmaf(w3.z, xv0, acc0[14]); acc1[14] = fmaf(w3.z, xv1, acc1[14]);
            acc0[15] = fmaf(w3.w, xv0, acc0[15]); acc1[15] = fmaf(w3.w, xv1, acc1[15]);
        }
    }
    #pragma unroll
    for (int co = 0; co < 16; ++co) {
        float bb = bo[co0 + co];
        ob[(size_t)(co0 + co) * HW + p0 + tid]       = acc0[co] + bb;
        ob[(size_t)(co0 + co) * HW + p0 + tid + 256] = acc1[co] + bb;
    }
}

// ---------------------------------------------------------------------------
extern "C" void kernel_launch(void* const* d_in, const int* in_sizes, int n_in,
                              void* d_out, int out_size, void* d_ws, size_t ws_size,
                              hipStream_t stream)
{
    const float* x1   = (const float*)d_in[0];
    const float* x2   = (const float*)d_in[1];
    const float* x12  = (const float*)d_in[2];
    const float* Wq1  = (const float*)d_in[3];
    const float* bq1  = (const float*)d_in[4];
    const float* Wq2  = (const float*)d_in[5];
    const float* bq2  = (const float*)d_in[6];
    const float* Wq12 = (const float*)d_in[7];
    const float* bq12 = (const float*)d_in[8];
    const float* Wo   = (const float*)d_in[9];
    const float* bo   = (const float*)d_in[10];
    const float* krw  = (const float*)d_in[11];
    const float* krh  = (const float*)d_in[12];

    // workspace layout (identical to R4)
    char* base = (char*)d_ws;
    float*    Qf    = (float*)base;
    float*    yw    = (float*)base;                      // alias: attn out
    ushort_t* Kb    = (ushort_t*)(base + 12582912);
    ushort_t* Vb    = (ushort_t*)(base + 18874368);
    ushort_t* QThi  = (ushort_t*)(base + 25165824);
    ushort_t* QTlo  = (ushort_t*)(base + 31457280);
    ushort_t* K12T  = (ushort_t*)(base + 37748736);
    ushort_t* KdT   = (ushort_t*)(base + 39845888);
    float*    RWp   = (float*)(base + 41943040);
    float*    RHp   = (float*)(base + 46137344);
    ushort_t* Wb    = (ushort_t*)(base + 25165824);      // alias, dead after conv
    ushort_t* xpadT = (ushort_t*)(base + 35782656);      // alias, dead after conv
    float*    outf  = (float*)d_out;

    const size_t xpad_bytes = (size_t)12 * 34 * 34 * 256 * 2;
    hipMemsetAsync(xpadT, 0, xpad_bytes, stream);

    hipLaunchKernelGGL(prep_x_kernel, dim3(32, 12), dim3(256), 0, stream,
                       x1, x2, x12, xpadT);
    hipLaunchKernelGGL(prep_w_kernel, dim3(2304), dim3(256), 0, stream,
                       Wq1, Wq2, Wq12, Wb);
    hipLaunchKernelGGL(conv_mfma_kernel, dim3(8, 6, 12), dim3(256), 0, stream,
                       Wb, xpadT, bq1, bq2, bq12, Qf, Kb, Vb);
    hipLaunchKernelGGL(trans_kernel, dim3(4, 160), dim3(256), 0, stream,
                       Qf, Kb, QThi, QTlo, K12T, KdT);
    hipLaunchKernelGGL(rel_kernel, dim3(4, 2, 32), dim3(256), 0, stream,
                       Qf, krw, krh, RWp, RHp);
    hipLaunchKernelGGL(attn_mfma_kernel, dim3(8, 32, 3), dim3(256), 0, stream,
                       QThi, QTlo, K12T, KdT, Vb, RWp, RHp, yw);
    hipLaunchKernelGGL(conv1x1_kernel, dim3(16, 2, 12), dim3(256), 0, stream,
                       yw, Wo, bo, outf);
}

// Round 7
// 236.620 us; speedup vs baseline: 1.0691x; 1.0691x over previous
//
#include <hip/hip_runtime.h>
#include <math.h>

#define HW   1024
#define NCH  768

typedef __bf16 bf16x8 __attribute__((ext_vector_type(8)));
typedef float f32x4 __attribute__((ext_vector_type(4)));
typedef unsigned short ushort_t;

__device__ __forceinline__ ushort_t f2bf(float f) {
    unsigned u = __builtin_bit_cast(unsigned, f);
    u += 0x7fffu + ((u >> 16) & 1u);           // round-to-nearest-even
    return (ushort_t)(u >> 16);
}
__device__ __forceinline__ float bf2f(ushort_t s) {
    unsigned u = ((unsigned)s) << 16;
    return __builtin_bit_cast(float, u);
}

#define GLOAD16(g, l) __builtin_amdgcn_global_load_lds( \
    (const __attribute__((address_space(1))) void*)(g), \
    (__attribute__((address_space(3))) void*)(l), 16, 0, 0)

// ---------------------------------------------------------------------------
// prep_x: x [img][b][256][32][32] fp32 -> xpadT [slab][34][34][256] bf16.
// (halo zeroed by hipMemsetAsync before this kernel.)
// ---------------------------------------------------------------------------
__global__ __launch_bounds__(256) void prep_x_kernel(
    const float* __restrict__ x1, const float* __restrict__ x2, const float* __restrict__ x12,
    ushort_t* __restrict__ xpadT)
{
    const int row  = blockIdx.x;
    const int slab = blockIdx.y;
    const int img  = slab >> 2, b = slab & 3;
    const float* x  = (img == 0) ? x1 : (img == 1) ? x2 : x12;
    const float* xb = x + (size_t)b * 256 * HW + row * 32;

    __shared__ float xs[32][257];
    const int tid = threadIdx.x;
    for (int idx = tid; idx < 256 * 32; idx += 256) {
        int ci = idx >> 5, col = idx & 31;
        xs[col][ci] = xb[(size_t)ci * HW + col];
    }
    __syncthreads();
    ushort_t* ob = xpadT + ((size_t)slab * 34 * 34 + (size_t)(row + 1) * 34 + 1) * 256;
    for (int col = 0; col < 32; ++col)
        ob[(size_t)col * 256 + tid] = f2bf(xs[col][tid]);
}

// ---------------------------------------------------------------------------
// prep_w: pre-swizzled bf16 A-tiles for conv (unchanged).
// ---------------------------------------------------------------------------
__global__ __launch_bounds__(256) void prep_w_kernel(
    const float* __restrict__ W1, const float* __restrict__ W2, const float* __restrict__ W3,
    ushort_t* __restrict__ Wb)
{
    int g = blockIdx.x * 256 + threadIdx.x;
    if (g >= 3 * 768 * 256) return;
    int ci  = g & 255;
    int co  = (g >> 8) % 768;
    int img = g / (768 * 256);
    const float* Wt  = (img == 0) ? W1 : (img == 1) ? W2 : W3;
    const float* src = Wt + (size_t)co * (256 * 9) + ci * 9;

    int coc = co >> 7, row = co & 127;
    int cic = ci >> 5;
    int cil = ci & 31;
    int s = cil >> 3, e = cil & 7;
    int phys  = s ^ ((row ^ (row >> 2)) & 3);
    int inner = row * 32 + phys * 8 + e;
    #pragma unroll
    for (int t = 0; t < 9; ++t) {
        size_t tile = (((size_t)img * 9 + t) * 8 + cic) * 6 + coc;
        Wb[tile * 4096 + inner] = f2bf(src[t]);
    }
}

// ---------------------------------------------------------------------------
// conv_mfma: implicit-GEMM 3x3 conv. Tile 128co x 64p, 4 waves (2x2:
// wave = 64co x 32p, acc[4][2]). grid (16 p-tiles, 6 co-tiles, 12 slabs)
// = 1152 blocks (4.5/CU; was 576 = 2.25/CU). LDS 24KB double-buffered.
// Outputs: ch<256 -> Qf fp32 (bias+q-scale), 256-511 -> Kb bf16, 512-767 -> Vb.
// ---------------------------------------------------------------------------
__global__ __launch_bounds__(256) void conv_mfma_kernel(
    const ushort_t* __restrict__ Wb, const ushort_t* __restrict__ xpadT,
    const float* __restrict__ B1, const float* __restrict__ B2, const float* __restrict__ B3,
    float* __restrict__ Qf, ushort_t* __restrict__ Kb, ushort_t* __restrict__ Vb)
{
    const int bx   = blockIdx.x;      // p-tile (64 pixels = 2 image rows)
    const int by   = blockIdx.y;      // co-tile (128 ch)
    const int slab = blockIdx.z;
    const int img  = slab >> 2;
    const float* Bs_bias = (img == 0) ? B1 : (img == 1) ? B2 : B3;

    __shared__ ushort_t As[2][4096];   // [128 co][4 slot][8] swizzled
    __shared__ ushort_t Bsh[2][2048];  // [64 p ][4 slot][8] swizzled

    const int tid  = threadIdx.x;
    const int lane = tid & 63;
    const int wid  = tid >> 6;
    const int wr   = wid >> 1, wc = wid & 1;

    const ushort_t* WbI = Wb + (size_t)img * 9 * 8 * 6 * 4096;
    const ushort_t* xpI = xpadT + (size_t)slab * 34 * 34 * 256;
    const int r0 = bx * 2;            // first image row of this tile

    // loop-invariant B staging offset (1 GLOAD16/thread)
    size_t pixoff;
    {
        int o    = tid * 16;          // dest byte offset in Bsh
        int p    = o >> 6;            // pixel row in tile [0,64)
        int phys = (o >> 4) & 3;
        int s    = phys ^ ((p ^ (p >> 2)) & 3);
        int pr   = p >> 5, c = p & 31;
        pixoff = ((size_t)((r0 + pr) * 34 + c)) * 256 + s * 8;
    }

    f32x4 acc[4][2];
    #pragma unroll
    for (int m = 0; m < 4; ++m)
        #pragma unroll
        for (int n = 0; n < 2; ++n) acc[m][n] = (f32x4){0.f, 0.f, 0.f, 0.f};

    int aoff[4], boff[2];
    #pragma unroll
    for (int m = 0; m < 4; ++m) {
        int row  = wr * 64 + m * 16 + (lane & 15);
        int phys = (lane >> 4) ^ ((row ^ (row >> 2)) & 3);
        aoff[m] = row * 32 + phys * 8;
    }
    #pragma unroll
    for (int n = 0; n < 2; ++n) {
        int row  = wc * 32 + n * 16 + (lane & 15);
        int phys = (lane >> 4) ^ ((row ^ (row >> 2)) & 3);
        boff[n] = row * 32 + phys * 8;
    }

    auto stage = [&](int kk, int buf) {
        int t = kk >> 3, cic = kk & 7;
        int dy = t / 3, dx = t - dy * 3;
        int koff = (dy * 34 + dx) * 256 + cic * 32;              // wave-uniform
        const ushort_t* wtile = WbI + ((size_t)(t * 8 + cic) * 6 + by) * 4096;
        #pragma unroll
        for (int r = 0; r < 2; ++r)
            GLOAD16(wtile + r * 2048 + tid * 8, (ushort_t*)As[buf] + r * 2048 + tid * 8);
        GLOAD16(xpI + pixoff + koff, (ushort_t*)Bsh[buf] + tid * 8);
    };

    stage(0, 0);
    asm volatile("s_waitcnt vmcnt(0)" ::: "memory");
    __builtin_amdgcn_s_barrier();

    for (int kk = 0; kk < 72; ++kk) {
        int cur = kk & 1;
        if (kk < 71) stage(kk + 1, cur ^ 1);

        const ushort_t* Ab = As[cur];
        const ushort_t* Bb = Bsh[cur];
        bf16x8 af[4], bfr[2];
        #pragma unroll
        for (int m = 0; m < 4; ++m) af[m] = *(const bf16x8*)(Ab + aoff[m]);
        #pragma unroll
        for (int n = 0; n < 2; ++n) bfr[n] = *(const bf16x8*)(Bb + boff[n]);

        #pragma unroll
        for (int m = 0; m < 4; ++m)
            #pragma unroll
            for (int n = 0; n < 2; ++n)
                acc[m][n] = __builtin_amdgcn_mfma_f32_16x16x32_bf16(af[m], bfr[n], acc[m][n], 0, 0, 0);

        asm volatile("s_waitcnt vmcnt(0)" ::: "memory");
        __builtin_amdgcn_s_barrier();
    }

    const int co_base = by * 128 + wr * 64;
    const int p_base  = bx * 64 + wc * 32;
    const int rsub = (lane >> 4) * 4;
    const int csub = lane & 15;
    #pragma unroll
    for (int m = 0; m < 4; ++m) {
        #pragma unroll
        for (int rg = 0; rg < 4; ++rg) {
            int ch = co_base + m * 16 + rsub + rg;
            float bias = Bs_bias[ch];
            #pragma unroll
            for (int nn = 0; nn < 2; ++nn) {
                int p = p_base + nn * 16 + csub;
                float v = acc[m][nn][rg] + bias;
                if (ch < 256)
                    Qf[((size_t)slab * 256 + ch) * HW + p] = v * 0.17677669529663687f;
                else if (ch < 512)
                    Kb[((size_t)slab * 256 + (ch - 256)) * HW + p] = f2bf(v);
                else
                    Vb[((size_t)slab * 256 + (ch - 512)) * HW + p] = f2bf(v);
            }
        }
    }
}

// ---------------------------------------------------------------------------
// trans_kernel: build attention MFMA operand tensors (unchanged).
// ---------------------------------------------------------------------------
__global__ __launch_bounds__(256) void trans_kernel(
    const float* __restrict__ Qf, const ushort_t* __restrict__ Kb,
    ushort_t* __restrict__ QThi, ushort_t* __restrict__ QTlo,
    ushort_t* __restrict__ K12T, ushort_t* __restrict__ KdT)
{
    const int z  = blockIdx.y;
    const int k0 = blockIdx.x * 256;
    const int tid = threadIdx.x;
    __shared__ float ts[32][257];

    if (z < 96) {
        int slab = z >> 3, n = z & 7;
        const float* src = Qf + ((size_t)slab * 256 + n * 32) * HW + k0;
        for (int idx = tid; idx < 8192; idx += 256) {
            int d = idx >> 8, k = idx & 255;
            ts[d][k] = src[(size_t)d * HW + k];
        }
        __syncthreads();
        ushort_t* dh = QThi + (size_t)z * 32768 + (size_t)k0 * 32;
        ushort_t* dl = QTlo + (size_t)z * 32768 + (size_t)k0 * 32;
        for (int idx = tid; idx < 8192; idx += 256) {
            int k = idx >> 5, d = idx & 31;
            float v = ts[d][k];
            ushort_t hi = f2bf(v);
            dh[(size_t)k * 32 + d] = hi;
            dl[(size_t)k * 32 + d] = f2bf(v - bf2f(hi));
        }
    } else if (z < 128) {
        int bn = z - 96, b = bn >> 3, n = bn & 7;
        const ushort_t* src = Kb + ((size_t)(8 + b) * 256 + n * 32) * HW + k0;
        for (int idx = tid; idx < 8192; idx += 256) {
            int d = idx >> 8, k = idx & 255;
            ts[d][k] = bf2f(src[(size_t)d * HW + k]);
        }
        __syncthreads();
        ushort_t* dst = K12T + (size_t)bn * 32768 + (size_t)k0 * 32;
        for (int idx = tid; idx < 8192; idx += 256) {
            int k = idx >> 5, d = idx & 31;
            dst[(size_t)k * 32 + d] = f2bf(ts[d][k]);
        }
    } else {
        int bn = z - 128, b = bn >> 3, n = bn & 7;
        const ushort_t* sA = Kb + ((size_t)b * 256 + n * 32) * HW + k0;
        const ushort_t* sB = Kb + ((size_t)(4 + b) * 256 + n * 32) * HW + k0;
        for (int idx = tid; idx < 8192; idx += 256) {
            int d = idx >> 8, k = idx & 255;
            ts[d][k] = bf2f(sA[(size_t)d * HW + k]) - bf2f(sB[(size_t)d * HW + k]);
        }
        __syncthreads();
        ushort_t* dst = KdT + (size_t)bn * 32768 + (size_t)k0 * 32;
        for (int idx = tid; idx < 8192; idx += 256) {
            int k = idx >> 5, d = idx & 31;
            dst[(size_t)k * 32 + d] = f2bf(ts[d][k]);
        }
    }
}

// ---------------------------------------------------------------------------
// rel_kernel: RW'/RH' tables from FP32 Q. grid (4 qchunk, 2 mhalf, 32 bn).
// ---------------------------------------------------------------------------
__global__ __launch_bounds__(256) void rel_kernel(
    const float* __restrict__ Qf,
    const float* __restrict__ krw, const float* __restrict__ krh,
    float* __restrict__ RWp, float* __restrict__ RHp)
{
    const int tid = threadIdx.x;
    const int mh  = blockIdx.y;
    const int bn  = blockIdx.z;
    const int b   = bn >> 3, n = bn & 7;
    const int q   = blockIdx.x * 256 + tid;
    const int r   = q >> 5, c = q & 31;

    __shared__ float rwl[63 * 33 + 1];
    __shared__ float rhl[63 * 33 + 1];
    for (int idx = tid; idx < 63 * 32; idx += 256) {
        int mp = idx >> 5, d = idx & 31;
        rwl[mp * 33 + d] = krw[idx];
        rhl[mp * 33 + d] = krh[idx];
    }
    __syncthreads();

    float qv[32];
    const float* qp = Qf + ((size_t)b * 256 + n * 32) * HW;
    #pragma unroll
    for (int d = 0; d < 32; ++d) qv[d] = qp[(size_t)d * HW + q];

    float* rw = RWp + ((size_t)bn * 1024 + q) * 32;
    float* rh = RHp + ((size_t)bn * 1024 + q) * 32;
    #pragma unroll
    for (int m = 0; m < 16; ++m) {
        int mm = mh * 16 + m;
        const float* t1 = rwl + (mm + 31 - c) * 33;
        const float* t2 = rhl + (mm + 31 - r) * 33;
        float s1 = 0.f, s2 = 0.f;
        #pragma unroll
        for (int d = 0; d < 32; ++d) { s1 = fmaf(qv[d], t1[d], s1); s2 = fmaf(qv[d], t2[d], s2); }
        rw[mm] = s1;
        rh[mm] = s2;
    }
}

// ---------------------------------------------------------------------------
// attn_mfma: flash attention, swapped operands (S^T = K x Q).
// Q hi/lo split via LDS staging (as R6); P SINGLE bf16 plane (error budget:
// P in [0,1], relative 2^-9, averaged over >=1024 keys -> ~5e-4 output).
// LDS = qt 16KB + kt 8KB + v 8KB + p 16KB = 48KB -> 3 blocks/CU.
// ---------------------------------------------------------------------------
__global__ __launch_bounds__(256) void attn_mfma_kernel(
    const ushort_t* __restrict__ QThi, const ushort_t* __restrict__ QTlo,
    const ushort_t* __restrict__ K12T, const ushort_t* __restrict__ KdT,
    const ushort_t* __restrict__ Vb,
    const float* __restrict__ RWp, const float* __restrict__ RHp,
    float* __restrict__ yw)
{
    const int qt = blockIdx.x;
    const int bn = blockIdx.y;
    const int br = blockIdx.z;
    const int b  = bn >> 3, n = bn & 7;
    const int tid = threadIdx.x, lane = tid & 63, wid = tid >> 6;
    const int q0 = qt * 128;

    __shared__ ushort_t qt_l[2][4096];     // [hi/lo][128 q][32 d] linear
    __shared__ ushort_t kt_l[2][2048];     // [64 k][32 d] linear (dbuf)
    __shared__ ushort_t v_l[2][2048];      // [32 d][64 k], chunk^(d&7) (dbuf)
    __shared__ ushort_t p_l[4][2048];      // per-wave [32 q][64 k], chunk-XOR

    const int slab = br * 4 + b;
    const size_t qoff = ((size_t)(slab * 8 + n) * 1024 + q0) * 32;
    const ushort_t* KTb = ((br == 2) ? KdT : K12T) + (size_t)bn * 32768;
    const ushort_t* Vg  = Vb + ((size_t)slab * 256 + n * 32) * HW;

    GLOAD16((const char*)(QThi + qoff) + tid * 16,        (char*)qt_l[0] + tid * 16);
    GLOAD16((const char*)(QThi + qoff) + 4096 + tid * 16, (char*)qt_l[0] + 4096 + tid * 16);
    GLOAD16((const char*)(QTlo + qoff) + tid * 16,        (char*)qt_l[1] + tid * 16);
    GLOAD16((const char*)(QTlo + qoff) + 4096 + tid * 16, (char*)qt_l[1] + 4096 + tid * 16);

    const int vd = tid >> 3, vpc = tid & 7;
    const char* Vrow = (const char*)Vg + (size_t)vd * 2048 + ((vpc ^ (vd & 7)) * 16);
    auto stage = [&](int t, int buf) {
        GLOAD16((const char*)KTb + t * 4096 + tid * 16, (char*)kt_l[buf] + tid * 16);
        GLOAD16(Vrow + t * 128,                          (char*)v_l[buf] + tid * 16);
    };
    stage(0, 0);

    float rwc[2][8];
    if (br == 0) {
        #pragma unroll
        for (int m = 0; m < 2; ++m) {
            int q = q0 + wid * 32 + m * 16 + (lane & 15);
            const float* rwp = RWp + ((size_t)bn * 1024 + q) * 32;
            #pragma unroll
            for (int i = 0; i < 2; ++i)
                #pragma unroll
                for (int r = 0; r < 4; ++r)
                    rwc[m][i * 4 + r] = rwp[i * 16 + 4 * (lane >> 4) + r];
        }
    }

    asm volatile("s_waitcnt vmcnt(0)" ::: "memory");
    __builtin_amdgcn_s_barrier();

    bf16x8 qfh[2], qfl[2];
    #pragma unroll
    for (int m = 0; m < 2; ++m) {
        int off = (wid * 32 + m * 16 + (lane & 15)) * 32 + (lane >> 4) * 8;
        qfh[m] = *(const bf16x8*)(qt_l[0] + off);
        qfl[m] = *(const bf16x8*)(qt_l[1] + off);
    }

    f32x4 oacc[2][2];
    #pragma unroll
    for (int ds = 0; ds < 2; ++ds)
        #pragma unroll
        for (int m = 0; m < 2; ++m) oacc[ds][m] = (f32x4){0.f, 0.f, 0.f, 0.f};
    float m_run[2] = {-INFINITY, -INFINITY}, l_run[2] = {0.f, 0.f};
    const f32x4 zero4 = (f32x4){0.f, 0.f, 0.f, 0.f};

    for (int t = 0; t < 16; ++t) {
        int cur = t & 1;

        float rh[2][2];
        if (br == 0) {
            #pragma unroll
            for (int m = 0; m < 2; ++m) {
                int q = q0 + wid * 32 + m * 16 + (lane & 15);
                const float* rhp = RHp + ((size_t)bn * 1024 + q) * 32 + 2 * t;
                rh[m][0] = rhp[0];
                rh[m][1] = rhp[1];
            }
        }
        if (t < 15) stage(t + 1, cur ^ 1);

        bf16x8 kf[4];
        #pragma unroll
        for (int s = 0; s < 4; ++s)
            kf[s] = *(const bf16x8*)(kt_l[cur] + (s * 16 + (lane & 15)) * 32 + (lane >> 4) * 8);

        f32x4 sa[4][2];
        #pragma unroll
        for (int s = 0; s < 4; ++s)
            #pragma unroll
            for (int m = 0; m < 2; ++m) {
                sa[s][m] = __builtin_amdgcn_mfma_f32_16x16x32_bf16(kf[s], qfl[m], zero4, 0, 0, 0);
                sa[s][m] = __builtin_amdgcn_mfma_f32_16x16x32_bf16(kf[s], qfh[m], sa[s][m], 0, 0, 0);
            }

        if (br == 0) {
            #pragma unroll
            for (int s = 0; s < 4; ++s)
                #pragma unroll
                for (int m = 0; m < 2; ++m)
                    #pragma unroll
                    for (int r = 0; r < 4; ++r)
                        sa[s][m][r] += rwc[m][(s & 1) * 4 + r] + rh[m][s >> 1];
        }

        #pragma unroll
        for (int m = 0; m < 2; ++m) {
            float mx = sa[0][m][0];
            #pragma unroll
            for (int s = 0; s < 4; ++s)
                #pragma unroll
                for (int r = 0; r < 4; ++r) mx = fmaxf(mx, sa[s][m][r]);
            mx = fmaxf(mx, __shfl_xor(mx, 16));
            mx = fmaxf(mx, __shfl_xor(mx, 32));
            float mnew = fmaxf(m_run[m], mx);
            float sc = __expf(m_run[m] - mnew);
            float ps = 0.f;
            #pragma unroll
            for (int s = 0; s < 4; ++s)
                #pragma unroll
                for (int r = 0; r < 4; ++r) {
                    float p = __expf(sa[s][m][r] - mnew);
                    sa[s][m][r] = p;
                    ps += p;
                }
            ps += __shfl_xor(ps, 16);
            ps += __shfl_xor(ps, 32);
            l_run[m] = l_run[m] * sc + ps;
            m_run[m] = mnew;
            oacc[0][m] = oacc[0][m] * sc;
            oacc[1][m] = oacc[1][m] * sc;
        }

        // P -> bf16 (single plane) -> per-wave LDS (chunk-XOR swizzle)
        const int g = lane >> 4;
        #pragma unroll
        for (int s = 0; s < 4; ++s)
            #pragma unroll
            for (int m = 0; m < 2; ++m) {
                int qrow = m * 16 + (lane & 15);
                int chunk = (2 * s + (g >> 1)) ^ (qrow & 7);
                char* basep = (char*)p_l[wid] + qrow * 128 + chunk * 16 + 8 * (g & 1);
                #pragma unroll
                for (int h = 0; h < 2; ++h) {
                    unsigned pk = (unsigned)f2bf(sa[s][m][2 * h])
                                | ((unsigned)f2bf(sa[s][m][2 * h + 1]) << 16);
                    *(unsigned*)(basep + 4 * h) = pk;
                }
            }

        // PV: O^T += V^T x P
        #pragma unroll
        for (int ks = 0; ks < 2; ++ks) {
            bf16x8 vf[2], pfh[2];
            #pragma unroll
            for (int ds = 0; ds < 2; ++ds) {
                int drow = ds * 16 + (lane & 15);
                int chunk = (4 * ks + g) ^ (drow & 7);
                vf[ds] = *(const bf16x8*)((char*)v_l[cur] + drow * 128 + chunk * 16);
            }
            #pragma unroll
            for (int m = 0; m < 2; ++m) {
                int qrow = m * 16 + (lane & 15);
                int chunk = (4 * ks + g) ^ (qrow & 7);
                pfh[m] = *(const bf16x8*)((char*)p_l[wid] + qrow * 128 + chunk * 16);
            }
            #pragma unroll
            for (int ds = 0; ds < 2; ++ds)
                #pragma unroll
                for (int m = 0; m < 2; ++m)
                    oacc[ds][m] = __builtin_amdgcn_mfma_f32_16x16x32_bf16(vf[ds], pfh[m], oacc[ds][m], 0, 0, 0);
        }

        asm volatile("s_waitcnt vmcnt(0)" ::: "memory");
        __builtin_amdgcn_s_barrier();
    }

    #pragma unroll
    for (int m = 0; m < 2; ++m) {
        float inv = 1.0f / l_run[m];
        int q = q0 + wid * 32 + m * 16 + (lane & 15);
        int rr = q >> 5, cc = q & 31;
        float* yb = yw + ((size_t)((br * 4 + b) * 256 + n * 32 + rr)) * HW + cc * 32;
        #pragma unroll
        for (int ds = 0; ds < 2; ++ds) {
            int dbase = ds * 16 + (lane >> 4) * 4;
            float4 o = make_float4(oacc[ds][m][0] * inv, oacc[ds][m][1] * inv,
                                   oacc[ds][m][2] * inv, oacc[ds][m][3] * inv);
            *reinterpret_cast<float4*>(yb + dbase) = o;
        }
    }
}

// ---------------------------------------------------------------------------
// conv1x1: 512-pixel tile, 2 pixels/thread, ci-chunks of 16 (unchanged).
// ---------------------------------------------------------------------------
__global__ __launch_bounds__(256) void conv1x1_kernel(
    const float* __restrict__ yw, const float* __restrict__ Wo,
    const float* __restrict__ bo, float* __restrict__ out)
{
    const int co0  = blockIdx.x * 16;
    const int p0   = blockIdx.y * 512;
    const int slab = blockIdx.z;
    const float* yb = yw + (size_t)slab * 256 * HW;
    float* ob       = out + (size_t)slab * 256 * HW;

    __shared__ float ys[16][512];
    __shared__ float wsl[16][16];

    const int tid = threadIdx.x;
    float acc0[16], acc1[16];
    #pragma unroll
    for (int co = 0; co < 16; ++co) { acc0[co] = 0.f; acc1[co] = 0.f; }

    for (int ci0 = 0; ci0 < 256; ci0 += 16) {
        __syncthreads();
        for (int idx = tid; idx < 16 * 512; idx += 256) {
            int ci = idx >> 9, p = idx & 511;
            ys[ci][p] = yb[(size_t)(ci0 + ci) * HW + p0 + p];
        }
        {
            int ci = tid >> 4, co = tid & 15;
            wsl[ci][co] = Wo[(size_t)(co0 + co) * 256 + ci0 + ci];
        }
        __syncthreads();
        #pragma unroll
        for (int ci = 0; ci < 16; ++ci) {
            float xv0 = ys[ci][tid];
            float xv1 = ys[ci][tid + 256];
            const float4* wp = reinterpret_cast<const float4*>(&wsl[ci][0]);
            float4 w0 = wp[0], w1 = wp[1], w2 = wp[2], w3 = wp[3];
            acc0[0]  = fmaf(w0.x, xv0, acc0[0]);  acc1[0]  = fmaf(w0.x, xv1, acc1[0]);
            acc0[1]  = fmaf(w0.y, xv0, acc0[1]);  acc1[1]  = fmaf(w0.y, xv1, acc1[1]);
            acc0[2]  = fmaf(w0.z, xv0, acc0[2]);  acc1[2]  = fmaf(w0.z, xv1, acc1[2]);
            acc0[3]  = fmaf(w0.w, xv0, acc0[3]);  acc1[3]  = fmaf(w0.w, xv1, acc1[3]);
            acc0[4]  = fmaf(w1.x, xv0, acc0[4]);  acc1[4]  = fmaf(w1.x, xv1, acc1[4]);
            acc0[5]  = fmaf(w1.y, xv0, acc0[5]);  acc1[5]  = fmaf(w1.y, xv1, acc1[5]);
            acc0[6]  = fmaf(w1.z, xv0, acc0[6]);  acc1[6]  = fmaf(w1.z, xv1, acc1[6]);
            acc0[7]  = fmaf(w1.w, xv0, acc0[7]);  acc1[7]  = fmaf(w1.w, xv1, acc1[7]);
            acc0[8]  = fmaf(w2.x, xv0, acc0[8]);  acc1[8]  = fmaf(w2.x, xv1, acc1[8]);
            acc0[9]  = fmaf(w2.y, xv0, acc0[9]);  acc1[9]  = fmaf(w2.y, xv1, acc1[9]);
            acc0[10] = fmaf(w2.z, xv0, acc0[10]); acc1[10] = fmaf(w2.z, xv1, acc1[10]);
            acc0[11] = fmaf(w2.w, xv0, acc0[11]); acc1[11] = fmaf(w2.w, xv1, acc1[11]);
            acc0[12] = fmaf(w3.x, xv0, acc0[12]); acc1[12] = fmaf(w3.x, xv1, acc1[12]);
            acc0[13] = fmaf(w3.y, xv0, acc0[13]); acc1[13] = fmaf(w3.y, xv1, acc1[13]);
            acc0[14] = fmaf(w3.z, xv0, acc0[14]); acc1[14] = fmaf(w3.z, xv1, acc1[14]);
            acc0[15] = fmaf(w3.w, xv0, acc0[15]); acc1[15] = fmaf(w3.w, xv1, acc1[15]);
        }
    }
    #pragma unroll
    for (int co = 0; co < 16; ++co) {
        float bb = bo[co0 + co];
        ob[(size_t)(co0 + co) * HW + p0 + tid]       = acc0[co] + bb;
        ob[(size_t)(co0 + co) * HW + p0 + tid + 256] = acc1[co] + bb;
    }
}

// ---------------------------------------------------------------------------
extern "C" void kernel_launch(void* const* d_in, const int* in_sizes, int n_in,
                              void* d_out, int out_size, void* d_ws, size_t ws_size,
                              hipStream_t stream)
{
    const float* x1   = (const float*)d_in[0];
    const float* x2   = (const float*)d_in[1];
    const float* x12  = (const float*)d_in[2];
    const float* Wq1  = (const float*)d_in[3];
    const float* bq1  = (const float*)d_in[4];
    const float* Wq2  = (const float*)d_in[5];
    const float* bq2  = (const float*)d_in[6];
    const float* Wq12 = (const float*)d_in[7];
    const float* bq12 = (const float*)d_in[8];
    const float* Wo   = (const float*)d_in[9];
    const float* bo   = (const float*)d_in[10];
    const float* krw  = (const float*)d_in[11];
    const float* krh  = (const float*)d_in[12];

    // workspace layout (identical to R4/R6)
    char* base = (char*)d_ws;
    float*    Qf    = (float*)base;
    float*    yw    = (float*)base;                      // alias: attn out
    ushort_t* Kb    = (ushort_t*)(base + 12582912);
    ushort_t* Vb    = (ushort_t*)(base + 18874368);
    ushort_t* QThi  = (ushort_t*)(base + 25165824);
    ushort_t* QTlo  = (ushort_t*)(base + 31457280);
    ushort_t* K12T  = (ushort_t*)(base + 37748736);
    ushort_t* KdT   = (ushort_t*)(base + 39845888);
    float*    RWp   = (float*)(base + 41943040);
    float*    RHp   = (float*)(base + 46137344);
    ushort_t* Wb    = (ushort_t*)(base + 25165824);      // alias, dead after conv
    ushort_t* xpadT = (ushort_t*)(base + 35782656);      // alias, dead after conv
    float*    outf  = (float*)d_out;

    const size_t xpad_bytes = (size_t)12 * 34 * 34 * 256 * 2;
    hipMemsetAsync(xpadT, 0, xpad_bytes, stream);

    hipLaunchKernelGGL(prep_x_kernel, dim3(32, 12), dim3(256), 0, stream,
                       x1, x2, x12, xpadT);
    hipLaunchKernelGGL(prep_w_kernel, dim3(2304), dim3(256), 0, stream,
                       Wq1, Wq2, Wq12, Wb);
    hipLaunchKernelGGL(conv_mfma_kernel, dim3(16, 6, 12), dim3(256), 0, stream,
                       Wb, xpadT, bq1, bq2, bq12, Qf, Kb, Vb);
    hipLaunchKernelGGL(trans_kernel, dim3(4, 160), dim3(256), 0, stream,
                       Qf, Kb, QThi, QTlo, K12T, KdT);
    hipLaunchKernelGGL(rel_kernel, dim3(4, 2, 32), dim3(256), 0, stream,
                       Qf, krw, krh, RWp, RHp);
    hipLaunchKernelGGL(attn_mfma_kernel, dim3(8, 32, 3), dim3(256), 0, stream,
                       QThi, QTlo, K12T, KdT, Vb, RWp, RHp, yw);
    hipLaunchKernelGGL(conv1x1_kernel, dim3(16, 2, 12), dim3(256), 0, stream,
                       yw, Wo, bo, outf);
}

// Round 10
// 236.185 us; speedup vs baseline: 1.0711x; 1.0018x over previous
//
#include <hip/hip_runtime.h>
#include <math.h>

#define HW   1024
#define NCH  768

typedef __bf16 bf16x8 __attribute__((ext_vector_type(8)));
typedef float f32x4 __attribute__((ext_vector_type(4)));
typedef unsigned short ushort_t;

__device__ __forceinline__ ushort_t f2bf(float f) {
    unsigned u = __builtin_bit_cast(unsigned, f);
    u += 0x7fffu + ((u >> 16) & 1u);           // round-to-nearest-even
    return (ushort_t)(u >> 16);
}
__device__ __forceinline__ float bf2f(ushort_t s) {
    unsigned u = ((unsigned)s) << 16;
    return __builtin_bit_cast(float, u);
}

#define GLOAD16(g, l) __builtin_amdgcn_global_load_lds( \
    (const __attribute__((address_space(1))) void*)(g), \
    (__attribute__((address_space(3))) void*)(l), 16, 0, 0)

// ---------------------------------------------------------------------------
// prep_x: x [img][b][256][32][32] fp32 -> xpadT [slab][34][34][256] bf16.
// (halo zeroed by hipMemsetAsync before this kernel.)
// ---------------------------------------------------------------------------
__global__ __launch_bounds__(256) void prep_x_kernel(
    const float* __restrict__ x1, const float* __restrict__ x2, const float* __restrict__ x12,
    ushort_t* __restrict__ xpadT)
{
    const int row  = blockIdx.x;
    const int slab = blockIdx.y;
    const int img  = slab >> 2, b = slab & 3;
    const float* x  = (img == 0) ? x1 : (img == 1) ? x2 : x12;
    const float* xb = x + (size_t)b * 256 * HW + row * 32;

    __shared__ float xs[32][257];
    const int tid = threadIdx.x;
    for (int idx = tid; idx < 256 * 32; idx += 256) {
        int ci = idx >> 5, col = idx & 31;
        xs[col][ci] = xb[(size_t)ci * HW + col];
    }
    __syncthreads();
    ushort_t* ob = xpadT + ((size_t)slab * 34 * 34 + (size_t)(row + 1) * 34 + 1) * 256;
    for (int col = 0; col < 32; ++col)
        ob[(size_t)col * 256 + tid] = f2bf(xs[col][tid]);
}

// ---------------------------------------------------------------------------
// prep_w: pre-swizzled bf16 A-tiles for conv (unchanged).
// ---------------------------------------------------------------------------
__global__ __launch_bounds__(256) void prep_w_kernel(
    const float* __restrict__ W1, const float* __restrict__ W2, const float* __restrict__ W3,
    ushort_t* __restrict__ Wb)
{
    int g = blockIdx.x * 256 + threadIdx.x;
    if (g >= 3 * 768 * 256) return;
    int ci  = g & 255;
    int co  = (g >> 8) % 768;
    int img = g / (768 * 256);
    const float* Wt  = (img == 0) ? W1 : (img == 1) ? W2 : W3;
    const float* src = Wt + (size_t)co * (256 * 9) + ci * 9;

    int coc = co >> 7, row = co & 127;
    int cic = ci >> 5;
    int cil = ci & 31;
    int s = cil >> 3, e = cil & 7;
    int phys  = s ^ ((row ^ (row >> 2)) & 3);
    int inner = row * 32 + phys * 8 + e;
    #pragma unroll
    for (int t = 0; t < 9; ++t) {
        size_t tile = (((size_t)img * 9 + t) * 8 + cic) * 6 + coc;
        Wb[tile * 4096 + inner] = f2bf(src[t]);
    }
}

// ---------------------------------------------------------------------------
// conv_mfma: implicit-GEMM 3x3 conv. Tile 128co x 64p, 4 waves (2x2:
// wave = 64co x 32p, acc[4][2]). grid (16 p-tiles, 6 co-tiles, 12 slabs)
// = 1152 blocks (4.5/CU). LDS 24KB double-buffered, vmcnt(0) drain per iter.
// Outputs: ch<256 -> Qf fp32 (bias+q-scale), 256-511 -> Kb bf16, 512-767 -> Vb.
// ---------------------------------------------------------------------------
__global__ __launch_bounds__(256) void conv_mfma_kernel(
    const ushort_t* __restrict__ Wb, const ushort_t* __restrict__ xpadT,
    const float* __restrict__ B1, const float* __restrict__ B2, const float* __restrict__ B3,
    float* __restrict__ Qf, ushort_t* __restrict__ Kb, ushort_t* __restrict__ Vb)
{
    const int bx   = blockIdx.x;      // p-tile (64 pixels = 2 image rows)
    const int by   = blockIdx.y;      // co-tile (128 ch)
    const int slab = blockIdx.z;
    const int img  = slab >> 2;
    const float* Bs_bias = (img == 0) ? B1 : (img == 1) ? B2 : B3;

    __shared__ ushort_t As[2][4096];   // [128 co][4 slot][8] swizzled
    __shared__ ushort_t Bsh[2][2048];  // [64 p ][4 slot][8] swizzled

    const int tid  = threadIdx.x;
    const int lane = tid & 63;
    const int wid  = tid >> 6;
    const int wr   = wid >> 1, wc = wid & 1;

    const ushort_t* WbI = Wb + (size_t)img * 9 * 8 * 6 * 4096;
    const ushort_t* xpI = xpadT + (size_t)slab * 34 * 34 * 256;
    const int r0 = bx * 2;            // first image row of this tile

    // loop-invariant B staging offset (1 GLOAD16/thread)
    size_t pixoff;
    {
        int o    = tid * 16;          // dest byte offset in Bsh
        int p    = o >> 6;            // pixel row in tile [0,64)
        int phys = (o >> 4) & 3;
        int s    = phys ^ ((p ^ (p >> 2)) & 3);
        int pr   = p >> 5, c = p & 31;
        pixoff = ((size_t)((r0 + pr) * 34 + c)) * 256 + s * 8;
    }

    f32x4 acc[4][2];
    #pragma unroll
    for (int m = 0; m < 4; ++m)
        #pragma unroll
        for (int n = 0; n < 2; ++n) acc[m][n] = (f32x4){0.f, 0.f, 0.f, 0.f};

    int aoff[4], boff[2];
    #pragma unroll
    for (int m = 0; m < 4; ++m) {
        int row  = wr * 64 + m * 16 + (lane & 15);
        int phys = (lane >> 4) ^ ((row ^ (row >> 2)) & 3);
        aoff[m] = row * 32 + phys * 8;
    }
    #pragma unroll
    for (int n = 0; n < 2; ++n) {
        int row  = wc * 32 + n * 16 + (lane & 15);
        int phys = (lane >> 4) ^ ((row ^ (row >> 2)) & 3);
        boff[n] = row * 32 + phys * 8;
    }

    auto stage = [&](int kk, int buf) {
        int t = kk >> 3, cic = kk & 7;
        int dy = t / 3, dx = t - dy * 3;
        int koff = (dy * 34 + dx) * 256 + cic * 32;              // wave-uniform
        const ushort_t* wtile = WbI + ((size_t)(t * 8 + cic) * 6 + by) * 4096;
        #pragma unroll
        for (int r = 0; r < 2; ++r)
            GLOAD16(wtile + r * 2048 + tid * 8, (ushort_t*)As[buf] + r * 2048 + tid * 8);
        GLOAD16(xpI + pixoff + koff, (ushort_t*)Bsh[buf] + tid * 8);
    };

    stage(0, 0);
    asm volatile("s_waitcnt vmcnt(0)" ::: "memory");
    __builtin_amdgcn_s_barrier();

    for (int kk = 0; kk < 72; ++kk) {
        int cur = kk & 1;
        if (kk < 71) stage(kk + 1, cur ^ 1);

        const ushort_t* Ab = As[cur];
        const ushort_t* Bb = Bsh[cur];
        bf16x8 af[4], bfr[2];
        #pragma unroll
        for (int m = 0; m < 4; ++m) af[m] = *(const bf16x8*)(Ab + aoff[m]);
        #pragma unroll
        for (int n = 0; n < 2; ++n) bfr[n] = *(const bf16x8*)(Bb + boff[n]);

        #pragma unroll
        for (int m = 0; m < 4; ++m)
            #pragma unroll
            for (int n = 0; n < 2; ++n)
                acc[m][n] = __builtin_amdgcn_mfma_f32_16x16x32_bf16(af[m], bfr[n], acc[m][n], 0, 0, 0);

        asm volatile("s_waitcnt vmcnt(0)" ::: "memory");
        __builtin_amdgcn_s_barrier();
    }

    const int co_base = by * 128 + wr * 64;
    const int p_base  = bx * 64 + wc * 32;
    const int rsub = (lane >> 4) * 4;
    const int csub = lane & 15;
    #pragma unroll
    for (int m = 0; m < 4; ++m) {
        #pragma unroll
        for (int rg = 0; rg < 4; ++rg) {
            int ch = co_base + m * 16 + rsub + rg;
            float bias = Bs_bias[ch];
            #pragma unroll
            for (int nn = 0; nn < 2; ++nn) {
                int p = p_base + nn * 16 + csub;
                float v = acc[m][nn][rg] + bias;
                if (ch < 256)
                    Qf[((size_t)slab * 256 + ch) * HW + p] = v * 0.17677669529663687f;
                else if (ch < 512)
                    Kb[((size_t)slab * 256 + (ch - 256)) * HW + p] = f2bf(v);
                else
                    Vb[((size_t)slab * 256 + (ch - 512)) * HW + p] = f2bf(v);
            }
        }
    }
}

// ---------------------------------------------------------------------------
// trans_kernel: build attention MFMA operand tensors (unchanged).
// ---------------------------------------------------------------------------
__global__ __launch_bounds__(256) void trans_kernel(
    const float* __restrict__ Qf, const ushort_t* __restrict__ Kb,
    ushort_t* __restrict__ QThi, ushort_t* __restrict__ QTlo,
    ushort_t* __restrict__ K12T, ushort_t* __restrict__ KdT)
{
    const int z  = blockIdx.y;
    const int k0 = blockIdx.x * 256;
    const int tid = threadIdx.x;
    __shared__ float ts[32][257];

    if (z < 96) {
        int slab = z >> 3, n = z & 7;
        const float* src = Qf + ((size_t)slab * 256 + n * 32) * HW + k0;
        for (int idx = tid; idx < 8192; idx += 256) {
            int d = idx >> 8, k = idx & 255;
            ts[d][k] = src[(size_t)d * HW + k];
        }
        __syncthreads();
        ushort_t* dh = QThi + (size_t)z * 32768 + (size_t)k0 * 32;
        ushort_t* dl = QTlo + (size_t)z * 32768 + (size_t)k0 * 32;
        for (int idx = tid; idx < 8192; idx += 256) {
            int k = idx >> 5, d = idx & 31;
            float v = ts[d][k];
            ushort_t hi = f2bf(v);
            dh[(size_t)k * 32 + d] = hi;
            dl[(size_t)k * 32 + d] = f2bf(v - bf2f(hi));
        }
    } else if (z < 128) {
        int bn = z - 96, b = bn >> 3, n = bn & 7;
        const ushort_t* src = Kb + ((size_t)(8 + b) * 256 + n * 32) * HW + k0;
        for (int idx = tid; idx < 8192; idx += 256) {
            int d = idx >> 8, k = idx & 255;
            ts[d][k] = bf2f(src[(size_t)d * HW + k]);
        }
        __syncthreads();
        ushort_t* dst = K12T + (size_t)bn * 32768 + (size_t)k0 * 32;
        for (int idx = tid; idx < 8192; idx += 256) {
            int k = idx >> 5, d = idx & 31;
            dst[(size_t)k * 32 + d] = f2bf(ts[d][k]);
        }
    } else {
        int bn = z - 128, b = bn >> 3, n = bn & 7;
        const ushort_t* sA = Kb + ((size_t)b * 256 + n * 32) * HW + k0;
        const ushort_t* sB = Kb + ((size_t)(4 + b) * 256 + n * 32) * HW + k0;
        for (int idx = tid; idx < 8192; idx += 256) {
            int d = idx >> 8, k = idx & 255;
            ts[d][k] = bf2f(sA[(size_t)d * HW + k]) - bf2f(sB[(size_t)d * HW + k]);
        }
        __syncthreads();
        ushort_t* dst = KdT + (size_t)bn * 32768 + (size_t)k0 * 32;
        for (int idx = tid; idx < 8192; idx += 256) {
            int k = idx >> 5, d = idx & 31;
            dst[(size_t)k * 32 + d] = f2bf(ts[d][k]);
        }
    }
}

// ---------------------------------------------------------------------------
// rel_kernel: RW'/RH' tables from FP32 Q. grid (4 qchunk, 2 mhalf, 32 bn).
// ---------------------------------------------------------------------------
__global__ __launch_bounds__(256) void rel_kernel(
    const float* __restrict__ Qf,
    const float* __restrict__ krw, const float* __restrict__ krh,
    float* __restrict__ RWp, float* __restrict__ RHp)
{
    const int tid = threadIdx.x;
    const int mh  = blockIdx.y;
    const int bn  = blockIdx.z;
    const int b   = bn >> 3, n = bn & 7;
    const int q   = blockIdx.x * 256 + tid;
    const int r   = q >> 5, c = q & 31;

    __shared__ float rwl[63 * 33 + 1];
    __shared__ float rhl[63 * 33 + 1];
    for (int idx = tid; idx < 63 * 32; idx += 256) {
        int mp = idx >> 5, d = idx & 31;
        rwl[mp * 33 + d] = krw[idx];
        rhl[mp * 33 + d] = krh[idx];
    }
    __syncthreads();

    float qv[32];
    const float* qp = Qf + ((size_t)b * 256 + n * 32) * HW;
    #pragma unroll
    for (int d = 0; d < 32; ++d) qv[d] = qp[(size_t)d * HW + q];

    float* rw = RWp + ((size_t)bn * 1024 + q) * 32;
    float* rh = RHp + ((size_t)bn * 1024 + q) * 32;
    #pragma unroll
    for (int m = 0; m < 16; ++m) {
        int mm = mh * 16 + m;
        const float* t1 = rwl + (mm + 31 - c) * 33;
        const float* t2 = rhl + (mm + 31 - r) * 33;
        float s1 = 0.f, s2 = 0.f;
        #pragma unroll
        for (int d = 0; d < 32; ++d) { s1 = fmaf(qv[d], t1[d], s1); s2 = fmaf(qv[d], t2[d], s2); }
        rw[mm] = s1;
        rh[mm] = s2;
    }
}

// ---------------------------------------------------------------------------
// attn_mfma: flash attention, swapped operands (S^T = K x Q).
// Q hi/lo split via LDS staging; P SINGLE bf16 plane.
// LDS = qt 16KB + kt 8KB + v 8KB + p 16KB = 48KB -> 3 blocks/CU.
// ---------------------------------------------------------------------------
__global__ __launch_bounds__(256) void attn_mfma_kernel(
    const ushort_t* __restrict__ QThi, const ushort_t* __restrict__ QTlo,
    const ushort_t* __restrict__ K12T, const ushort_t* __restrict__ KdT,
    const ushort_t* __restrict__ Vb,
    const float* __restrict__ RWp, const float* __restrict__ RHp,
    float* __restrict__ yw)
{
    const int qt = blockIdx.x;
    const int bn = blockIdx.y;
    const int br = blockIdx.z;
    const int b  = bn >> 3, n = bn & 7;
    const int tid = threadIdx.x, lane = tid & 63, wid = tid >> 6;
    const int q0 = qt * 128;

    __shared__ ushort_t qt_l[2][4096];     // [hi/lo][128 q][32 d] linear
    __shared__ ushort_t kt_l[2][2048];     // [64 k][32 d] linear (dbuf)
    __shared__ ushort_t v_l[2][2048];      // [32 d][64 k], chunk^(d&7) (dbuf)
    __shared__ ushort_t p_l[4][2048];      // per-wave [32 q][64 k], chunk-XOR

    const int slab = br * 4 + b;
    const size_t qoff = ((size_t)(slab * 8 + n) * 1024 + q0) * 32;
    const ushort_t* KTb = ((br == 2) ? KdT : K12T) + (size_t)bn * 32768;
    const ushort_t* Vg  = Vb + ((size_t)slab * 256 + n * 32) * HW;

    GLOAD16((const char*)(QThi + qoff) + tid * 16,        (char*)qt_l[0] + tid * 16);
    GLOAD16((const char*)(QThi + qoff) + 4096 + tid * 16, (char*)qt_l[0] + 4096 + tid * 16);
    GLOAD16((const char*)(QTlo + qoff) + tid * 16,        (char*)qt_l[1] + tid * 16);
    GLOAD16((const char*)(QTlo + qoff) + 4096 + tid * 16, (char*)qt_l[1] + 4096 + tid * 16);

    const int vd = tid >> 3, vpc = tid & 7;
    const char* Vrow = (const char*)Vg + (size_t)vd * 2048 + ((vpc ^ (vd & 7)) * 16);
    auto stage = [&](int t, int buf) {
        GLOAD16((const char*)KTb + t * 4096 + tid * 16, (char*)kt_l[buf] + tid * 16);
        GLOAD16(Vrow + t * 128,                          (char*)v_l[buf] + tid * 16);
    };
    stage(0, 0);

    float rwc[2][8];
    if (br == 0) {
        #pragma unroll
        for (int m = 0; m < 2; ++m) {
            int q = q0 + wid * 32 + m * 16 + (lane & 15);
            const float* rwp = RWp + ((size_t)bn * 1024 + q) * 32;
            #pragma unroll
            for (int i = 0; i < 2; ++i)
                #pragma unroll
                for (int r = 0; r < 4; ++r)
                    rwc[m][i * 4 + r] = rwp[i * 16 + 4 * (lane >> 4) + r];
        }
    }

    asm volatile("s_waitcnt vmcnt(0)" ::: "memory");
    __builtin_amdgcn_s_barrier();

    bf16x8 qfh[2], qfl[2];
    #pragma unroll
    for (int m = 0; m < 2; ++m) {
        int off = (wid * 32 + m * 16 + (lane & 15)) * 32 + (lane >> 4) * 8;
        qfh[m] = *(const bf16x8*)(qt_l[0] + off);
        qfl[m] = *(const bf16x8*)(qt_l[1] + off);
    }

    f32x4 oacc[2][2];
    #pragma unroll
    for (int ds = 0; ds < 2; ++ds)
        #pragma unroll
        for (int m = 0; m < 2; ++m) oacc[ds][m] = (f32x4){0.f, 0.f, 0.f, 0.f};
    float m_run[2] = {-INFINITY, -INFINITY}, l_run[2] = {0.f, 0.f};
    const f32x4 zero4 = (f32x4){0.f, 0.f, 0.f, 0.f};

    for (int t = 0; t < 16; ++t) {
        int cur = t & 1;

        float rh[2][2];
        if (br == 0) {
            #pragma unroll
            for (int m = 0; m < 2; ++m) {
                int q = q0 + wid * 32 + m * 16 + (lane & 15);
                const float* rhp = RHp + ((size_t)bn * 1024 + q) * 32 + 2 * t;
                rh[m][0] = rhp[0];
                rh[m][1] = rhp[1];
            }
        }
        if (t < 15) stage(t + 1, cur ^ 1);

        bf16x8 kf[4];
        #pragma unroll
        for (int s = 0; s < 4; ++s)
            kf[s] = *(const bf16x8*)(kt_l[cur] + (s * 16 + (lane & 15)) * 32 + (lane >> 4) * 8);

        f32x4 sa[4][2];
        #pragma unroll
        for (int s = 0; s < 4; ++s)
            #pragma unroll
            for (int m = 0; m < 2; ++m) {
                sa[s][m] = __builtin_amdgcn_mfma_f32_16x16x32_bf16(kf[s], qfl[m], zero4, 0, 0, 0);
                sa[s][m] = __builtin_amdgcn_mfma_f32_16x16x32_bf16(kf[s], qfh[m], sa[s][m], 0, 0, 0);
            }

        if (br == 0) {
            #pragma unroll
            for (int s = 0; s < 4; ++s)
                #pragma unroll
                for (int m = 0; m < 2; ++m)
                    #pragma unroll
                    for (int r = 0; r < 4; ++r)
                        sa[s][m][r] += rwc[m][(s & 1) * 4 + r] + rh[m][s >> 1];
        }

        #pragma unroll
        for (int m = 0; m < 2; ++m) {
            float mx = sa[0][m][0];
            #pragma unroll
            for (int s = 0; s < 4; ++s)
                #pragma unroll
                for (int r = 0; r < 4; ++r) mx = fmaxf(mx, sa[s][m][r]);
            mx = fmaxf(mx, __shfl_xor(mx, 16));
            mx = fmaxf(mx, __shfl_xor(mx, 32));
            float mnew = fmaxf(m_run[m], mx);
            float sc = __expf(m_run[m] - mnew);
            float ps = 0.f;
            #pragma unroll
            for (int s = 0; s < 4; ++s)
                #pragma unroll
                for (int r = 0; r < 4; ++r) {
                    float p = __expf(sa[s][m][r] - mnew);
                    sa[s][m][r] = p;
                    ps += p;
                }
            ps += __shfl_xor(ps, 16);
            ps += __shfl_xor(ps, 32);
            l_run[m] = l_run[m] * sc + ps;
            m_run[m] = mnew;
            oacc[0][m] = oacc[0][m] * sc;
            oacc[1][m] = oacc[1][m] * sc;
        }

        // P -> bf16 (single plane) -> per-wave LDS (chunk-XOR swizzle)
        const int g = lane >> 4;
        #pragma unroll
        for (int s = 0; s < 4; ++s)
            #pragma unroll
            for (int m = 0; m < 2; ++m) {
                int qrow = m * 16 + (lane & 15);
                int chunk = (2 * s + (g >> 1)) ^ (qrow & 7);
                char* basep = (char*)p_l[wid] + qrow * 128 + chunk * 16 + 8 * (g & 1);
                #pragma unroll
                for (int h = 0; h < 2; ++h) {
                    unsigned pk = (unsigned)f2bf(sa[s][m][2 * h])
                                | ((unsigned)f2bf(sa[s][m][2 * h + 1]) << 16);
                    *(unsigned*)(basep + 4 * h) = pk;
                }
            }

        // PV: O^T += V^T x P
        #pragma unroll
        for (int ks = 0; ks < 2; ++ks) {
            bf16x8 vf[2], pfh[2];
            #pragma unroll
            for (int ds = 0; ds < 2; ++ds) {
                int drow = ds * 16 + (lane & 15);
                int chunk = (4 * ks + g) ^ (drow & 7);
                vf[ds] = *(const bf16x8*)((char*)v_l[cur] + drow * 128 + chunk * 16);
            }
            #pragma unroll
            for (int m = 0; m < 2; ++m) {
                int qrow = m * 16 + (lane & 15);
                int chunk = (4 * ks + g) ^ (qrow & 7);
                pfh[m] = *(const bf16x8*)((char*)p_l[wid] + qrow * 128 + chunk * 16);
            }
            #pragma unroll
            for (int ds = 0; ds < 2; ++ds)
                #pragma unroll
                for (int m = 0; m < 2; ++m)
                    oacc[ds][m] = __builtin_amdgcn_mfma_f32_16x16x32_bf16(vf[ds], pfh[m], oacc[ds][m], 0, 0, 0);
        }

        asm volatile("s_waitcnt vmcnt(0)" ::: "memory");
        __builtin_amdgcn_s_barrier();
    }

    #pragma unroll
    for (int m = 0; m < 2; ++m) {
        float inv = 1.0f / l_run[m];
        int q = q0 + wid * 32 + m * 16 + (lane & 15);
        int rr = q >> 5, cc = q & 31;
        float* yb = yw + ((size_t)((br * 4 + b) * 256 + n * 32 + rr)) * HW + cc * 32;
        #pragma unroll
        for (int ds = 0; ds < 2; ++ds) {
            int dbase = ds * 16 + (lane >> 4) * 4;
            float4 o = make_float4(oacc[ds][m][0] * inv, oacc[ds][m][1] * inv,
                                   oacc[ds][m][2] * inv, oacc[ds][m][3] * inv);
            *reinterpret_cast<float4*>(yb + dbase) = o;
        }
    }
}

// ---------------------------------------------------------------------------
// conv1x1: 512-pixel tile, 2 pixels/thread, ci-chunks of 16 (unchanged).
// ---------------------------------------------------------------------------
__global__ __launch_bounds__(256) void conv1x1_kernel(
    const float* __restrict__ yw, const float* __restrict__ Wo,
    const float* __restrict__ bo, float* __restrict__ out)
{
    const int co0  = blockIdx.x * 16;
    const int p0   = blockIdx.y * 512;
    const int slab = blockIdx.z;
    const float* yb = yw + (size_t)slab * 256 * HW;
    float* ob       = out + (size_t)slab * 256 * HW;

    __shared__ float ys[16][512];
    __shared__ float wsl[16][16];

    const int tid = threadIdx.x;
    float acc0[16], acc1[16];
    #pragma unroll
    for (int co = 0; co < 16; ++co) { acc0[co] = 0.f; acc1[co] = 0.f; }

    for (int ci0 = 0; ci0 < 256; ci0 += 16) {
        __syncthreads();
        for (int idx = tid; idx < 16 * 512; idx += 256) {
            int ci = idx >> 9, p = idx & 511;
            ys[ci][p] = yb[(size_t)(ci0 + ci) * HW + p0 + p];
        }
        {
            int ci = tid >> 4, co = tid & 15;
            wsl[ci][co] = Wo[(size_t)(co0 + co) * 256 + ci0 + ci];
        }
        __syncthreads();
        #pragma unroll
        for (int ci = 0; ci < 16; ++ci) {
            float xv0 = ys[ci][tid];
            float xv1 = ys[ci][tid + 256];
            const float4* wp = reinterpret_cast<const float4*>(&wsl[ci][0]);
            float4 w0 = wp[0], w1 = wp[1], w2 = wp[2], w3 = wp[3];
            acc0[0]  = fmaf(w0.x, xv0, acc0[0]);  acc1[0]  = fmaf(w0.x, xv1, acc1[0]);
            acc0[1]  = fmaf(w0.y, xv0, acc0[1]);  acc1[1]  = fmaf(w0.y, xv1, acc1[1]);
            acc0[2]  = fmaf(w0.z, xv0, acc0[2]);  acc1[2]  = fmaf(w0.z, xv1, acc1[2]);
            acc0[3]  = fmaf(w0.w, xv0, acc0[3]);  acc1[3]  = fmaf(w0.w, xv1, acc1[3]);
            acc0[4]  = fmaf(w1.x, xv0, acc0[4]);  acc1[4]  = fmaf(w1.x, xv1, acc1[4]);
            acc0[5]  = fmaf(w1.y, xv0, acc0[5]);  acc1[5]  = fmaf(w1.y, xv1, acc1[5]);
            acc0[6]  = fmaf(w1.z, xv0, acc0[6]);  acc1[6]  = fmaf(w1.z, xv1, acc1[6]);
            acc0[7]  = fmaf(w1.w, xv0, acc0[7]);  acc1[7]  = fmaf(w1.w, xv1, acc1[7]);
            acc0[8]  = fmaf(w2.x, xv0, acc0[8]);  acc1[8]  = fmaf(w2.x, xv1, acc1[8]);
            acc0[9]  = fmaf(w2.y, xv0, acc0[9]);  acc1[9]  = fmaf(w2.y, xv1, acc1[9]);
            acc0[10] = fmaf(w2.z, xv0, acc0[10]); acc1[10] = fmaf(w2.z, xv1, acc1[10]);
            acc0[11] = fmaf(w2.w, xv0, acc0[11]); acc1[11] = fmaf(w2.w, xv1, acc1[11]);
            acc0[12] = fmaf(w3.x, xv0, acc0[12]); acc1[12] = fmaf(w3.x, xv1, acc1[12]);
            acc0[13] = fmaf(w3.y, xv0, acc0[13]); acc1[13] = fmaf(w3.y, xv1, acc1[13]);
            acc0[14] = fmaf(w3.z, xv0, acc0[14]); acc1[14] = fmaf(w3.z, xv1, acc1[14]);
            acc0[15] = fmaf(w3.w, xv0, acc0[15]); acc1[15] = fmaf(w3.w, xv1, acc1[15]);
        }
    }
    #pragma unroll
    for (int co = 0; co < 16; ++co) {
        float bb = bo[co0 + co];
        ob[(size_t)(co0 + co) * HW + p0 + tid]       = acc0[co] + bb;
        ob[(size_t)(co0 + co) * HW + p0 + tid + 256] = acc1[co] + bb;
    }
}

// ---------------------------------------------------------------------------
extern "C" void kernel_launch(void* const* d_in, const int* in_sizes, int n_in,
                              void* d_out, int out_size, void* d_ws, size_t ws_size,
                              hipStream_t stream)
{
    const float* x1   = (const float*)d_in[0];
    const float* x2   = (const float*)d_in[1];
    const float* x12  = (const float*)d_in[2];
    const float* Wq1  = (const float*)d_in[3];
    const float* bq1  = (const float*)d_in[4];
    const float* Wq2  = (const float*)d_in[5];
    const float* bq2  = (const float*)d_in[6];
    const float* Wq12 = (const float*)d_in[7];
    const float* bq12 = (const float*)d_in[8];
    const float* Wo   = (const float*)d_in[9];
    const float* bo   = (const float*)d_in[10];
    const float* krw  = (const float*)d_in[11];
    const float* krh  = (const float*)d_in[12];

    // workspace layout (identical to R4/R6/R7)
    char* base = (char*)d_ws;
    float*    Qf    = (float*)base;
    float*    yw    = (float*)base;                      // alias: attn out
    ushort_t* Kb    = (ushort_t*)(base + 12582912);
    ushort_t* Vb    = (ushort_t*)(base + 18874368);
    ushort_t* QThi  = (ushort_t*)(base + 25165824);
    ushort_t* QTlo  = (ushort_t*)(base + 31457280);
    ushort_t* K12T  = (ushort_t*)(base + 37748736);
    ushort_t* KdT   = (ushort_t*)(base + 39845888);
    float*    RWp   = (float*)(base + 41943040);
    float*    RHp   = (float*)(base + 46137344);
    ushort_t* Wb    = (ushort_t*)(base + 25165824);      // alias, dead after conv
    ushort_t* xpadT = (ushort_t*)(base + 35782656);      // alias, dead after conv
    float*    outf  = (float*)d_out;

    const size_t xpad_bytes = (size_t)12 * 34 * 34 * 256 * 2;
    hipMemsetAsync(xpadT, 0, xpad_bytes, stream);

    hipLaunchKernelGGL(prep_x_kernel, dim3(32, 12), dim3(256), 0, stream,
                       x1, x2, x12, xpadT);
    hipLaunchKernelGGL(prep_w_kernel, dim3(2304), dim3(256), 0, stream,
                       Wq1, Wq2, Wq12, Wb);
    hipLaunchKernelGGL(conv_mfma_kernel, dim3(16, 6, 12), dim3(256), 0, stream,
                       Wb, xpadT, bq1, bq2, bq12, Qf, Kb, Vb);
    hipLaunchKernelGGL(trans_kernel, dim3(4, 160), dim3(256), 0, stream,
                       Qf, Kb, QThi, QTlo, K12T, KdT);
    hipLaunchKernelGGL(rel_kernel, dim3(4, 2, 32), dim3(256), 0, stream,
                       Qf, krw, krh, RWp, RHp);
    hipLaunchKernelGGL(attn_mfma_kernel, dim3(8, 32, 3), dim3(256), 0, stream,
                       QThi, QTlo, K12T, KdT, Vb, RWp, RHp, yw);
    hipLaunchKernelGGL(conv1x1_kernel, dim3(16, 2, 12), dim3(256), 0, stream,
                       yw, Wo, bo, outf);
}

// Round 11
// 235.091 us; speedup vs baseline: 1.0761x; 1.0047x over previous
//
#include <hip/hip_runtime.h>
#include <math.h>

#define HW   1024
#define NCH  768

typedef __bf16 bf16x8 __attribute__((ext_vector_type(8)));
typedef float f32x4 __attribute__((ext_vector_type(4)));
typedef unsigned short ushort_t;

__device__ __forceinline__ ushort_t f2bf(float f) {
    unsigned u = __builtin_bit_cast(unsigned, f);
    u += 0x7fffu + ((u >> 16) & 1u);           // round-to-nearest-even
    return (ushort_t)(u >> 16);
}
__device__ __forceinline__ float bf2f(ushort_t s) {
    unsigned u = ((unsigned)s) << 16;
    return __builtin_bit_cast(float, u);
}

#define GLOAD16(g, l) __builtin_amdgcn_global_load_lds( \
    (const __attribute__((address_space(1))) void*)(g), \
    (__attribute__((address_space(3))) void*)(l), 16, 0, 0)

// ---------------------------------------------------------------------------
// prep_x: x [img][b][256][32][32] fp32 -> xpadT [slab][34][34][256] bf16.
// (halo zeroed by hipMemsetAsync before this kernel.)
// ---------------------------------------------------------------------------
__global__ __launch_bounds__(256) void prep_x_kernel(
    const float* __restrict__ x1, const float* __restrict__ x2, const float* __restrict__ x12,
    ushort_t* __restrict__ xpadT)
{
    const int row  = blockIdx.x;
    const int slab = blockIdx.y;
    const int img  = slab >> 2, b = slab & 3;
    const float* x  = (img == 0) ? x1 : (img == 1) ? x2 : x12;
    const float* xb = x + (size_t)b * 256 * HW + row * 32;

    __shared__ float xs[32][257];
    const int tid = threadIdx.x;
    for (int idx = tid; idx < 256 * 32; idx += 256) {
        int ci = idx >> 5, col = idx & 31;
        xs[col][ci] = xb[(size_t)ci * HW + col];
    }
    __syncthreads();
    ushort_t* ob = xpadT + ((size_t)slab * 34 * 34 + (size_t)(row + 1) * 34 + 1) * 256;
    for (int col = 0; col < 32; ++col)
        ob[(size_t)col * 256 + tid] = f2bf(xs[col][tid]);
}

// ---------------------------------------------------------------------------
// prep_w: pre-swizzled bf16 A-tiles for conv (unchanged).
// ---------------------------------------------------------------------------
__global__ __launch_bounds__(256) void prep_w_kernel(
    const float* __restrict__ W1, const float* __restrict__ W2, const float* __restrict__ W3,
    ushort_t* __restrict__ Wb)
{
    int g = blockIdx.x * 256 + threadIdx.x;
    if (g >= 3 * 768 * 256) return;
    int ci  = g & 255;
    int co  = (g >> 8) % 768;
    int img = g / (768 * 256);
    const float* Wt  = (img == 0) ? W1 : (img == 1) ? W2 : W3;
    const float* src = Wt + (size_t)co * (256 * 9) + ci * 9;

    int coc = co >> 7, row = co & 127;
    int cic = ci >> 5;
    int cil = ci & 31;
    int s = cil >> 3, e = cil & 7;
    int phys  = s ^ ((row ^ (row >> 2)) & 3);
    int inner = row * 32 + phys * 8 + e;
    #pragma unroll
    for (int t = 0; t < 9; ++t) {
        size_t tile = (((size_t)img * 9 + t) * 8 + cic) * 6 + coc;
        Wb[tile * 4096 + inner] = f2bf(src[t]);
    }
}

// ---------------------------------------------------------------------------
// conv_mfma: implicit-GEMM 3x3 conv. Identical compute to R10; ONLY change:
// XCD-aware bijective block remap (T1). nwg = 16*6*12 = 1152, 1152/8 = 144:
//   orig = dispatch-linear id; swz = (orig&7)*144 + (orig>>3)
// gives each XCD a contiguous 144-block chunk (9 complete (by,slab) panels)
// so W-panel re-reads hit the XCD-private L2 instead of HBM.
// ---------------------------------------------------------------------------
__global__ __launch_bounds__(256) void conv_mfma_kernel(
    const ushort_t* __restrict__ Wb, const ushort_t* __restrict__ xpadT,
    const float* __restrict__ B1, const float* __restrict__ B2, const float* __restrict__ B3,
    float* __restrict__ Qf, ushort_t* __restrict__ Kb, ushort_t* __restrict__ Vb)
{
    // XCD-aware remap (pure index math; per-block work unchanged)
    const int orig = blockIdx.x + 16 * (blockIdx.y + 6 * blockIdx.z);
    const int swz  = (orig & 7) * 144 + (orig >> 3);
    const int bx   = swz & 15;            // p-tile (64 pixels = 2 image rows)
    const int by   = (swz >> 4) % 6;      // co-tile (128 ch)
    const int slab = swz / 96;            // img*4 + b
    const int img  = slab >> 2;
    const float* Bs_bias = (img == 0) ? B1 : (img == 1) ? B2 : B3;

    __shared__ ushort_t As[2][4096];   // [128 co][4 slot][8] swizzled
    __shared__ ushort_t Bsh[2][2048];  // [64 p ][4 slot][8] swizzled

    const int tid  = threadIdx.x;
    const int lane = tid & 63;
    const int wid  = tid >> 6;
    const int wr   = wid >> 1, wc = wid & 1;

    const ushort_t* WbI = Wb + (size_t)img * 9 * 8 * 6 * 4096;
    const ushort_t* xpI = xpadT + (size_t)slab * 34 * 34 * 256;
    const int r0 = bx * 2;            // first image row of this tile

    // loop-invariant B staging offset (1 GLOAD16/thread)
    size_t pixoff;
    {
        int o    = tid * 16;          // dest byte offset in Bsh
        int p    = o >> 6;            // pixel row in tile [0,64)
        int phys = (o >> 4) & 3;
        int s    = phys ^ ((p ^ (p >> 2)) & 3);
        int pr   = p >> 5, c = p & 31;
        pixoff = ((size_t)((r0 + pr) * 34 + c)) * 256 + s * 8;
    }

    f32x4 acc[4][2];
    #pragma unroll
    for (int m = 0; m < 4; ++m)
        #pragma unroll
        for (int n = 0; n < 2; ++n) acc[m][n] = (f32x4){0.f, 0.f, 0.f, 0.f};

    int aoff[4], boff[2];
    #pragma unroll
    for (int m = 0; m < 4; ++m) {
        int row  = wr * 64 + m * 16 + (lane & 15);
        int phys = (lane >> 4) ^ ((row ^ (row >> 2)) & 3);
        aoff[m] = row * 32 + phys * 8;
    }
    #pragma unroll
    for (int n = 0; n < 2; ++n) {
        int row  = wc * 32 + n * 16 + (lane & 15);
        int phys = (lane >> 4) ^ ((row ^ (row >> 2)) & 3);
        boff[n] = row * 32 + phys * 8;
    }

    auto stage = [&](int kk, int buf) {
        int t = kk >> 3, cic = kk & 7;
        int dy = t / 3, dx = t - dy * 3;
        int koff = (dy * 34 + dx) * 256 + cic * 32;              // wave-uniform
        const ushort_t* wtile = WbI + ((size_t)(t * 8 + cic) * 6 + by) * 4096;
        #pragma unroll
        for (int r = 0; r < 2; ++r)
            GLOAD16(wtile + r * 2048 + tid * 8, (ushort_t*)As[buf] + r * 2048 + tid * 8);
        GLOAD16(xpI + pixoff + koff, (ushort_t*)Bsh[buf] + tid * 8);
    };

    stage(0, 0);
    asm volatile("s_waitcnt vmcnt(0)" ::: "memory");
    __builtin_amdgcn_s_barrier();

    for (int kk = 0; kk < 72; ++kk) {
        int cur = kk & 1;
        if (kk < 71) stage(kk + 1, cur ^ 1);

        const ushort_t* Ab = As[cur];
        const ushort_t* Bb = Bsh[cur];
        bf16x8 af[4], bfr[2];
        #pragma unroll
        for (int m = 0; m < 4; ++m) af[m] = *(const bf16x8*)(Ab + aoff[m]);
        #pragma unroll
        for (int n = 0; n < 2; ++n) bfr[n] = *(const bf16x8*)(Bb + boff[n]);

        #pragma unroll
        for (int m = 0; m < 4; ++m)
            #pragma unroll
            for (int n = 0; n < 2; ++n)
                acc[m][n] = __builtin_amdgcn_mfma_f32_16x16x32_bf16(af[m], bfr[n], acc[m][n], 0, 0, 0);

        asm volatile("s_waitcnt vmcnt(0)" ::: "memory");
        __builtin_amdgcn_s_barrier();
    }

    const int co_base = by * 128 + wr * 64;
    const int p_base  = bx * 64 + wc * 32;
    const int rsub = (lane >> 4) * 4;
    const int csub = lane & 15;
    #pragma unroll
    for (int m = 0; m < 4; ++m) {
        #pragma unroll
        for (int rg = 0; rg < 4; ++rg) {
            int ch = co_base + m * 16 + rsub + rg;
            float bias = Bs_bias[ch];
            #pragma unroll
            for (int nn = 0; nn < 2; ++nn) {
                int p = p_base + nn * 16 + csub;
                float v = acc[m][nn][rg] + bias;
                if (ch < 256)
                    Qf[((size_t)slab * 256 + ch) * HW + p] = v * 0.17677669529663687f;
                else if (ch < 512)
                    Kb[((size_t)slab * 256 + (ch - 256)) * HW + p] = f2bf(v);
                else
                    Vb[((size_t)slab * 256 + (ch - 512)) * HW + p] = f2bf(v);
            }
        }
    }
}

// ---------------------------------------------------------------------------
// trans_kernel: build attention MFMA operand tensors (unchanged).
// ---------------------------------------------------------------------------
__global__ __launch_bounds__(256) void trans_kernel(
    const float* __restrict__ Qf, const ushort_t* __restrict__ Kb,
    ushort_t* __restrict__ QThi, ushort_t* __restrict__ QTlo,
    ushort_t* __restrict__ K12T, ushort_t* __restrict__ KdT)
{
    const int z  = blockIdx.y;
    const int k0 = blockIdx.x * 256;
    const int tid = threadIdx.x;
    __shared__ float ts[32][257];

    if (z < 96) {
        int slab = z >> 3, n = z & 7;
        const float* src = Qf + ((size_t)slab * 256 + n * 32) * HW + k0;
        for (int idx = tid; idx < 8192; idx += 256) {
            int d = idx >> 8, k = idx & 255;
            ts[d][k] = src[(size_t)d * HW + k];
        }
        __syncthreads();
        ushort_t* dh = QThi + (size_t)z * 32768 + (size_t)k0 * 32;
        ushort_t* dl = QTlo + (size_t)z * 32768 + (size_t)k0 * 32;
        for (int idx = tid; idx < 8192; idx += 256) {
            int k = idx >> 5, d = idx & 31;
            float v = ts[d][k];
            ushort_t hi = f2bf(v);
            dh[(size_t)k * 32 + d] = hi;
            dl[(size_t)k * 32 + d] = f2bf(v - bf2f(hi));
        }
    } else if (z < 128) {
        int bn = z - 96, b = bn >> 3, n = bn & 7;
        const ushort_t* src = Kb + ((size_t)(8 + b) * 256 + n * 32) * HW + k0;
        for (int idx = tid; idx < 8192; idx += 256) {
            int d = idx >> 8, k = idx & 255;
            ts[d][k] = bf2f(src[(size_t)d * HW + k]);
        }
        __syncthreads();
        ushort_t* dst = K12T + (size_t)bn * 32768 + (size_t)k0 * 32;
        for (int idx = tid; idx < 8192; idx += 256) {
            int k = idx >> 5, d = idx & 31;
            dst[(size_t)k * 32 + d] = f2bf(ts[d][k]);
        }
    } else {
        int bn = z - 128, b = bn >> 3, n = bn & 7;
        const ushort_t* sA = Kb + ((size_t)b * 256 + n * 32) * HW + k0;
        const ushort_t* sB = Kb + ((size_t)(4 + b) * 256 + n * 32) * HW + k0;
        for (int idx = tid; idx < 8192; idx += 256) {
            int d = idx >> 8, k = idx & 255;
            ts[d][k] = bf2f(sA[(size_t)d * HW + k]) - bf2f(sB[(size_t)d * HW + k]);
        }
        __syncthreads();
        ushort_t* dst = KdT + (size_t)bn * 32768 + (size_t)k0 * 32;
        for (int idx = tid; idx < 8192; idx += 256) {
            int k = idx >> 5, d = idx & 31;
            dst[(size_t)k * 32 + d] = f2bf(ts[d][k]);
        }
    }
}

// ---------------------------------------------------------------------------
// rel_kernel: RW'/RH' tables from FP32 Q. grid (4 qchunk, 2 mhalf, 32 bn).
// ---------------------------------------------------------------------------
__global__ __launch_bounds__(256) void rel_kernel(
    const float* __restrict__ Qf,
    const float* __restrict__ krw, const float* __restrict__ krh,
    float* __restrict__ RWp, float* __restrict__ RHp)
{
    const int tid = threadIdx.x;
    const int mh  = blockIdx.y;
    const int bn  = blockIdx.z;
    const int b   = bn >> 3, n = bn & 7;
    const int q   = blockIdx.x * 256 + tid;
    const int r   = q >> 5, c = q & 31;

    __shared__ float rwl[63 * 33 + 1];
    __shared__ float rhl[63 * 33 + 1];
    for (int idx = tid; idx < 63 * 32; idx += 256) {
        int mp = idx >> 5, d = idx & 31;
        rwl[mp * 33 + d] = krw[idx];
        rhl[mp * 33 + d] = krh[idx];
    }
    __syncthreads();

    float qv[32];
    const float* qp = Qf + ((size_t)b * 256 + n * 32) * HW;
    #pragma unroll
    for (int d = 0; d < 32; ++d) qv[d] = qp[(size_t)d * HW + q];

    float* rw = RWp + ((size_t)bn * 1024 + q) * 32;
    float* rh = RHp + ((size_t)bn * 1024 + q) * 32;
    #pragma unroll
    for (int m = 0; m < 16; ++m) {
        int mm = mh * 16 + m;
        const float* t1 = rwl + (mm + 31 - c) * 33;
        const float* t2 = rhl + (mm + 31 - r) * 33;
        float s1 = 0.f, s2 = 0.f;
        #pragma unroll
        for (int d = 0; d < 32; ++d) { s1 = fmaf(qv[d], t1[d], s1); s2 = fmaf(qv[d], t2[d], s2); }
        rw[mm] = s1;
        rh[mm] = s2;
    }
}

// ---------------------------------------------------------------------------
// attn_mfma: flash attention, swapped operands (S^T = K x Q). R10 EXACT.
// ---------------------------------------------------------------------------
__global__ __launch_bounds__(256) void attn_mfma_kernel(
    const ushort_t* __restrict__ QThi, const ushort_t* __restrict__ QTlo,
    const ushort_t* __restrict__ K12T, const ushort_t* __restrict__ KdT,
    const ushort_t* __restrict__ Vb,
    const float* __restrict__ RWp, const float* __restrict__ RHp,
    float* __restrict__ yw)
{
    const int qt = blockIdx.x;
    const int bn = blockIdx.y;
    const int br = blockIdx.z;
    const int b  = bn >> 3, n = bn & 7;
    const int tid = threadIdx.x, lane = tid & 63, wid = tid >> 6;
    const int q0 = qt * 128;

    __shared__ ushort_t qt_l[2][4096];     // [hi/lo][128 q][32 d] linear
    __shared__ ushort_t kt_l[2][2048];     // [64 k][32 d] linear (dbuf)
    __shared__ ushort_t v_l[2][2048];      // [32 d][64 k], chunk^(d&7) (dbuf)
    __shared__ ushort_t p_l[4][2048];      // per-wave [32 q][64 k], chunk-XOR

    const int slab = br * 4 + b;
    const size_t qoff = ((size_t)(slab * 8 + n) * 1024 + q0) * 32;
    const ushort_t* KTb = ((br == 2) ? KdT : K12T) + (size_t)bn * 32768;
    const ushort_t* Vg  = Vb + ((size_t)slab * 256 + n * 32) * HW;

    GLOAD16((const char*)(QThi + qoff) + tid * 16,        (char*)qt_l[0] + tid * 16);
    GLOAD16((const char*)(QThi + qoff) + 4096 + tid * 16, (char*)qt_l[0] + 4096 + tid * 16);
    GLOAD16((const char*)(QTlo + qoff) + tid * 16,        (char*)qt_l[1] + tid * 16);
    GLOAD16((const char*)(QTlo + qoff) + 4096 + tid * 16, (char*)qt_l[1] + 4096 + tid * 16);

    const int vd = tid >> 3, vpc = tid & 7;
    const char* Vrow = (const char*)Vg + (size_t)vd * 2048 + ((vpc ^ (vd & 7)) * 16);
    auto stage = [&](int t, int buf) {
        GLOAD16((const char*)KTb + t * 4096 + tid * 16, (char*)kt_l[buf] + tid * 16);
        GLOAD16(Vrow + t * 128,                          (char*)v_l[buf] + tid * 16);
    };
    stage(0, 0);

    float rwc[2][8];
    if (br == 0) {
        #pragma unroll
        for (int m = 0; m < 2; ++m) {
            int q = q0 + wid * 32 + m * 16 + (lane & 15);
            const float* rwp = RWp + ((size_t)bn * 1024 + q) * 32;
            #pragma unroll
            for (int i = 0; i < 2; ++i)
                #pragma unroll
                for (int r = 0; r < 4; ++r)
                    rwc[m][i * 4 + r] = rwp[i * 16 + 4 * (lane >> 4) + r];
        }
    }

    asm volatile("s_waitcnt vmcnt(0)" ::: "memory");
    __builtin_amdgcn_s_barrier();

    bf16x8 qfh[2], qfl[2];
    #pragma unroll
    for (int m = 0; m < 2; ++m) {
        int off = (wid * 32 + m * 16 + (lane & 15)) * 32 + (lane >> 4) * 8;
        qfh[m] = *(const bf16x8*)(qt_l[0] + off);
        qfl[m] = *(const bf16x8*)(qt_l[1] + off);
    }

    f32x4 oacc[2][2];
    #pragma unroll
    for (int ds = 0; ds < 2; ++ds)
        #pragma unroll
        for (int m = 0; m < 2; ++m) oacc[ds][m] = (f32x4){0.f, 0.f, 0.f, 0.f};
    float m_run[2] = {-INFINITY, -INFINITY}, l_run[2] = {0.f, 0.f};
    const f32x4 zero4 = (f32x4){0.f, 0.f, 0.f, 0.f};

    for (int t = 0; t < 16; ++t) {
        int cur = t & 1;

        float rh[2][2];
        if (br == 0) {
            #pragma unroll
            for (int m = 0; m < 2; ++m) {
                int q = q0 + wid * 32 + m * 16 + (lane & 15);
                const float* rhp = RHp + ((size_t)bn * 1024 + q) * 32 + 2 * t;
                rh[m][0] = rhp[0];
                rh[m][1] = rhp[1];
            }
        }
        if (t < 15) stage(t + 1, cur ^ 1);

        bf16x8 kf[4];
        #pragma unroll
        for (int s = 0; s < 4; ++s)
            kf[s] = *(const bf16x8*)(kt_l[cur] + (s * 16 + (lane & 15)) * 32 + (lane >> 4) * 8);

        f32x4 sa[4][2];
        #pragma unroll
        for (int s = 0; s < 4; ++s)
            #pragma unroll
            for (int m = 0; m < 2; ++m) {
                sa[s][m] = __builtin_amdgcn_mfma_f32_16x16x32_bf16(kf[s], qfl[m], zero4, 0, 0, 0);
                sa[s][m] = __builtin_amdgcn_mfma_f32_16x16x32_bf16(kf[s], qfh[m], sa[s][m], 0, 0, 0);
            }

        if (br == 0) {
            #pragma unroll
            for (int s = 0; s < 4; ++s)
                #pragma unroll
                for (int m = 0; m < 2; ++m)
                    #pragma unroll
                    for (int r = 0; r < 4; ++r)
                        sa[s][m][r] += rwc[m][(s & 1) * 4 + r] + rh[m][s >> 1];
        }

        #pragma unroll
        for (int m = 0; m < 2; ++m) {
            float mx = sa[0][m][0];
            #pragma unroll
            for (int s = 0; s < 4; ++s)
                #pragma unroll
                for (int r = 0; r < 4; ++r) mx = fmaxf(mx, sa[s][m][r]);
            mx = fmaxf(mx, __shfl_xor(mx, 16));
            mx = fmaxf(mx, __shfl_xor(mx, 32));
            float mnew = fmaxf(m_run[m], mx);
            float sc = __expf(m_run[m] - mnew);
            float ps = 0.f;
            #pragma unroll
            for (int s = 0; s < 4; ++s)
                #pragma unroll
                for (int r = 0; r < 4; ++r) {
                    float p = __expf(sa[s][m][r] - mnew);
                    sa[s][m][r] = p;
                    ps += p;
                }
            ps += __shfl_xor(ps, 16);
            ps += __shfl_xor(ps, 32);
            l_run[m] = l_run[m] * sc + ps;
            m_run[m] = mnew;
            oacc[0][m] = oacc[0][m] * sc;
            oacc[1][m] = oacc[1][m] * sc;
        }

        // P -> bf16 (single plane) -> per-wave LDS (chunk-XOR swizzle)
        const int g = lane >> 4;
        #pragma unroll
        for (int s = 0; s < 4; ++s)
            #pragma unroll
            for (int m = 0; m < 2; ++m) {
                int qrow = m * 16 + (lane & 15);
                int chunk = (2 * s + (g >> 1)) ^ (qrow & 7);
                char* basep = (char*)p_l[wid] + qrow * 128 + chunk * 16 + 8 * (g & 1);
                #pragma unroll
                for (int h = 0; h < 2; ++h) {
                    unsigned pk = (unsigned)f2bf(sa[s][m][2 * h])
                                | ((unsigned)f2bf(sa[s][m][2 * h + 1]) << 16);
                    *(unsigned*)(basep + 4 * h) = pk;
                }
            }

        // PV: O^T += V^T x P
        #pragma unroll
        for (int ks = 0; ks < 2; ++ks) {
            bf16x8 vf[2], pfh[2];
            #pragma unroll
            for (int ds = 0; ds < 2; ++ds) {
                int drow = ds * 16 + (lane & 15);
                int chunk = (4 * ks + g) ^ (drow & 7);
                vf[ds] = *(const bf16x8*)((char*)v_l[cur] + drow * 128 + chunk * 16);
            }
            #pragma unroll
            for (int m = 0; m < 2; ++m) {
                int qrow = m * 16 + (lane & 15);
                int chunk = (4 * ks + g) ^ (qrow & 7);
                pfh[m] = *(const bf16x8*)((char*)p_l[wid] + qrow * 128 + chunk * 16);
            }
            #pragma unroll
            for (int ds = 0; ds < 2; ++ds)
                #pragma unroll
                for (int m = 0; m < 2; ++m)
                    oacc[ds][m] = __builtin_amdgcn_mfma_f32_16x16x32_bf16(vf[ds], pfh[m], oacc[ds][m], 0, 0, 0);
        }

        asm volatile("s_waitcnt vmcnt(0)" ::: "memory");
        __builtin_amdgcn_s_barrier();
    }

    #pragma unroll
    for (int m = 0; m < 2; ++m) {
        float inv = 1.0f / l_run[m];
        int q = q0 + wid * 32 + m * 16 + (lane & 15);
        int rr = q >> 5, cc = q & 31;
        float* yb = yw + ((size_t)((br * 4 + b) * 256 + n * 32 + rr)) * HW + cc * 32;
        #pragma unroll
        for (int ds = 0; ds < 2; ++ds) {
            int dbase = ds * 16 + (lane >> 4) * 4;
            float4 o = make_float4(oacc[ds][m][0] * inv, oacc[ds][m][1] * inv,
                                   oacc[ds][m][2] * inv, oacc[ds][m][3] * inv);
            *reinterpret_cast<float4*>(yb + dbase) = o;
        }
    }
}

// ---------------------------------------------------------------------------
// conv1x1: 512-pixel tile, 2 pixels/thread, ci-chunks of 16 (unchanged).
// ---------------------------------------------------------------------------
__global__ __launch_bounds__(256) void conv1x1_kernel(
    const float* __restrict__ yw, const float* __restrict__ Wo,
    const float* __restrict__ bo, float* __restrict__ out)
{
    const int co0  = blockIdx.x * 16;
    const int p0   = blockIdx.y * 512;
    const int slab = blockIdx.z;
    const float* yb = yw + (size_t)slab * 256 * HW;
    float* ob       = out + (size_t)slab * 256 * HW;

    __shared__ float ys[16][512];
    __shared__ float wsl[16][16];

    const int tid = threadIdx.x;
    float acc0[16], acc1[16];
    #pragma unroll
    for (int co = 0; co < 16; ++co) { acc0[co] = 0.f; acc1[co] = 0.f; }

    for (int ci0 = 0; ci0 < 256; ci0 += 16) {
        __syncthreads();
        for (int idx = tid; idx < 16 * 512; idx += 256) {
            int ci = idx >> 9, p = idx & 511;
            ys[ci][p] = yb[(size_t)(ci0 + ci) * HW + p0 + p];
        }
        {
            int ci = tid >> 4, co = tid & 15;
            wsl[ci][co] = Wo[(size_t)(co0 + co) * 256 + ci0 + ci];
        }
        __syncthreads();
        #pragma unroll
        for (int ci = 0; ci < 16; ++ci) {
            float xv0 = ys[ci][tid];
            float xv1 = ys[ci][tid + 256];
            const float4* wp = reinterpret_cast<const float4*>(&wsl[ci][0]);
            float4 w0 = wp[0], w1 = wp[1], w2 = wp[2], w3 = wp[3];
            acc0[0]  = fmaf(w0.x, xv0, acc0[0]);  acc1[0]  = fmaf(w0.x, xv1, acc1[0]);
            acc0[1]  = fmaf(w0.y, xv0, acc0[1]);  acc1[1]  = fmaf(w0.y, xv1, acc1[1]);
            acc0[2]  = fmaf(w0.z, xv0, acc0[2]);  acc1[2]  = fmaf(w0.z, xv1, acc1[2]);
            acc0[3]  = fmaf(w0.w, xv0, acc0[3]);  acc1[3]  = fmaf(w0.w, xv1, acc1[3]);
            acc0[4]  = fmaf(w1.x, xv0, acc0[4]);  acc1[4]  = fmaf(w1.x, xv1, acc1[4]);
            acc0[5]  = fmaf(w1.y, xv0, acc0[5]);  acc1[5]  = fmaf(w1.y, xv1, acc1[5]);
            acc0[6]  = fmaf(w1.z, xv0, acc0[6]);  acc1[6]  = fmaf(w1.z, xv1, acc1[6]);
            acc0[7]  = fmaf(w1.w, xv0, acc0[7]);  acc1[7]  = fmaf(w1.w, xv1, acc1[7]);
            acc0[8]  = fmaf(w2.x, xv0, acc0[8]);  acc1[8]  = fmaf(w2.x, xv1, acc1[8]);
            acc0[9]  = fmaf(w2.y, xv0, acc0[9]);  acc1[9]  = fmaf(w2.y, xv1, acc1[9]);
            acc0[10] = fmaf(w2.z, xv0, acc0[10]); acc1[10] = fmaf(w2.z, xv1, acc1[10]);
            acc0[11] = fmaf(w2.w, xv0, acc0[11]); acc1[11] = fmaf(w2.w, xv1, acc1[11]);
            acc0[12] = fmaf(w3.x, xv0, acc0[12]); acc1[12] = fmaf(w3.x, xv1, acc1[12]);
            acc0[13] = fmaf(w3.y, xv0, acc0[13]); acc1[13] = fmaf(w3.y, xv1, acc1[13]);
            acc0[14] = fmaf(w3.z, xv0, acc0[14]); acc1[14] = fmaf(w3.z, xv1, acc1[14]);
            acc0[15] = fmaf(w3.w, xv0, acc0[15]); acc1[15] = fmaf(w3.w, xv1, acc1[15]);
        }
    }
    #pragma unroll
    for (int co = 0; co < 16; ++co) {
        float bb = bo[co0 + co];
        ob[(size_t)(co0 + co) * HW + p0 + tid]       = acc0[co] + bb;
        ob[(size_t)(co0 + co) * HW + p0 + tid + 256] = acc1[co] + bb;
    }
}

// ---------------------------------------------------------------------------
extern "C" void kernel_launch(void* const* d_in, const int* in_sizes, int n_in,
                              void* d_out, int out_size, void* d_ws, size_t ws_size,
                              hipStream_t stream)
{
    const float* x1   = (const float*)d_in[0];
    const float* x2   = (const float*)d_in[1];
    const float* x12  = (const float*)d_in[2];
    const float* Wq1  = (const float*)d_in[3];
    const float* bq1  = (const float*)d_in[4];
    const float* Wq2  = (const float*)d_in[5];
    const float* bq2  = (const float*)d_in[6];
    const float* Wq12 = (const float*)d_in[7];
    const float* bq12 = (const float*)d_in[8];
    const float* Wo   = (const float*)d_in[9];
    const float* bo   = (const float*)d_in[10];
    const float* krw  = (const float*)d_in[11];
    const float* krh  = (const float*)d_in[12];

    // workspace layout (identical to R4/R6/R7/R10)
    char* base = (char*)d_ws;
    float*    Qf    = (float*)base;
    float*    yw    = (float*)base;                      // alias: attn out
    ushort_t* Kb    = (ushort_t*)(base + 12582912);
    ushort_t* Vb    = (ushort_t*)(base + 18874368);
    ushort_t* QThi  = (ushort_t*)(base + 25165824);
    ushort_t* QTlo  = (ushort_t*)(base + 31457280);
    ushort_t* K12T  = (ushort_t*)(base + 37748736);
    ushort_t* KdT   = (ushort_t*)(base + 39845888);
    float*    RWp   = (float*)(base + 41943040);
    float*    RHp   = (float*)(base + 46137344);
    ushort_t* Wb    = (ushort_t*)(base + 25165824);      // alias, dead after conv
    ushort_t* xpadT = (ushort_t*)(base + 35782656);      // alias, dead after conv
    float*    outf  = (float*)d_out;

    const size_t xpad_bytes = (size_t)12 * 34 * 34 * 256 * 2;
    hipMemsetAsync(xpadT, 0, xpad_bytes, stream);

    hipLaunchKernelGGL(prep_x_kernel, dim3(32, 12), dim3(256), 0, stream,
                       x1, x2, x12, xpadT);
    hipLaunchKernelGGL(prep_w_kernel, dim3(2304), dim3(256), 0, stream,
                       Wq1, Wq2, Wq12, Wb);
    hipLaunchKernelGGL(conv_mfma_kernel, dim3(16, 6, 12), dim3(256), 0, stream,
                       Wb, xpadT, bq1, bq2, bq12, Qf, Kb, Vb);
    hipLaunchKernelGGL(trans_kernel, dim3(4, 160), dim3(256), 0, stream,
                       Qf, Kb, QThi, QTlo, K12T, KdT);
    hipLaunchKernelGGL(rel_kernel, dim3(4, 2, 32), dim3(256), 0, stream,
                       Qf, krw, krh, RWp, RHp);
    hipLaunchKernelGGL(attn_mfma_kernel, dim3(8, 32, 3), dim3(256), 0, stream,
                       QThi, QTlo, K12T, KdT, Vb, RWp, RHp, yw);
    hipLaunchKernelGGL(conv1x1_kernel, dim3(16, 2, 12), dim3(256), 0, stream,
                       yw, Wo, bo, outf);
}

// Round 13
// 234.515 us; speedup vs baseline: 1.0787x; 1.0025x over previous
//
#include <hip/hip_runtime.h>
#include <math.h>

#define HW   1024
#define NCH  768

typedef __bf16 bf16x8 __attribute__((ext_vector_type(8)));
typedef float f32x4 __attribute__((ext_vector_type(4)));
typedef unsigned short ushort_t;

__device__ __forceinline__ ushort_t f2bf(float f) {
    unsigned u = __builtin_bit_cast(unsigned, f);
    u += 0x7fffu + ((u >> 16) & 1u);           // round-to-nearest-even
    return (ushort_t)(u >> 16);
}
__device__ __forceinline__ float bf2f(ushort_t s) {
    unsigned u = ((unsigned)s) << 16;
    return __builtin_bit_cast(float, u);
}

#define GLOAD16(g, l) __builtin_amdgcn_global_load_lds( \
    (const __attribute__((address_space(1))) void*)(g), \
    (__attribute__((address_space(3))) void*)(l), 16, 0, 0)

// ---------------------------------------------------------------------------
// prep_x: x [img][b][256][32][32] fp32 -> xpadT [slab][34][34][256] bf16.
// (halo zeroed by hipMemsetAsync before this kernel.)
// ---------------------------------------------------------------------------
__global__ __launch_bounds__(256) void prep_x_kernel(
    const float* __restrict__ x1, const float* __restrict__ x2, const float* __restrict__ x12,
    ushort_t* __restrict__ xpadT)
{
    const int row  = blockIdx.x;
    const int slab = blockIdx.y;
    const int img  = slab >> 2, b = slab & 3;
    const float* x  = (img == 0) ? x1 : (img == 1) ? x2 : x12;
    const float* xb = x + (size_t)b * 256 * HW + row * 32;

    __shared__ float xs[32][257];
    const int tid = threadIdx.x;
    for (int idx = tid; idx < 256 * 32; idx += 256) {
        int ci = idx >> 5, col = idx & 31;
        xs[col][ci] = xb[(size_t)ci * HW + col];
    }
    __syncthreads();
    ushort_t* ob = xpadT + ((size_t)slab * 34 * 34 + (size_t)(row + 1) * 34 + 1) * 256;
    for (int col = 0; col < 32; ++col)
        ob[(size_t)col * 256 + tid] = f2bf(xs[col][tid]);
}

// ---------------------------------------------------------------------------
// prep_w: pre-swizzled bf16 A-tiles for conv (unchanged).
// ---------------------------------------------------------------------------
__global__ __launch_bounds__(256) void prep_w_kernel(
    const float* __restrict__ W1, const float* __restrict__ W2, const float* __restrict__ W3,
    ushort_t* __restrict__ Wb)
{
    int g = blockIdx.x * 256 + threadIdx.x;
    if (g >= 3 * 768 * 256) return;
    int ci  = g & 255;
    int co  = (g >> 8) % 768;
    int img = g / (768 * 256);
    const float* Wt  = (img == 0) ? W1 : (img == 1) ? W2 : W3;
    const float* src = Wt + (size_t)co * (256 * 9) + ci * 9;

    int coc = co >> 7, row = co & 127;
    int cic = ci >> 5;
    int cil = ci & 31;
    int s = cil >> 3, e = cil & 7;
    int phys  = s ^ ((row ^ (row >> 2)) & 3);
    int inner = row * 32 + phys * 8 + e;
    #pragma unroll
    for (int t = 0; t < 9; ++t) {
        size_t tile = (((size_t)img * 9 + t) * 8 + cic) * 6 + coc;
        Wb[tile * 4096 + inner] = f2bf(src[t]);
    }
}

// ---------------------------------------------------------------------------
// conv_mfma: implicit-GEMM 3x3 conv with XCD-aware bijective block remap
// (R11 exact; FETCH_SIZE 49->21 MB verified).
// ---------------------------------------------------------------------------
__global__ __launch_bounds__(256) void conv_mfma_kernel(
    const ushort_t* __restrict__ Wb, const ushort_t* __restrict__ xpadT,
    const float* __restrict__ B1, const float* __restrict__ B2, const float* __restrict__ B3,
    float* __restrict__ Qf, ushort_t* __restrict__ Kb, ushort_t* __restrict__ Vb)
{
    // XCD-aware remap (pure index math; per-block work unchanged)
    const int orig = blockIdx.x + 16 * (blockIdx.y + 6 * blockIdx.z);
    const int swz  = (orig & 7) * 144 + (orig >> 3);
    const int bx   = swz & 15;            // p-tile (64 pixels = 2 image rows)
    const int by   = (swz >> 4) % 6;      // co-tile (128 ch)
    const int slab = swz / 96;            // img*4 + b
    const int img  = slab >> 2;
    const float* Bs_bias = (img == 0) ? B1 : (img == 1) ? B2 : B3;

    __shared__ ushort_t As[2][4096];   // [128 co][4 slot][8] swizzled
    __shared__ ushort_t Bsh[2][2048];  // [64 p ][4 slot][8] swizzled

    const int tid  = threadIdx.x;
    const int lane = tid & 63;
    const int wid  = tid >> 6;
    const int wr   = wid >> 1, wc = wid & 1;

    const ushort_t* WbI = Wb + (size_t)img * 9 * 8 * 6 * 4096;
    const ushort_t* xpI = xpadT + (size_t)slab * 34 * 34 * 256;
    const int r0 = bx * 2;            // first image row of this tile

    size_t pixoff;
    {
        int o    = tid * 16;
        int p    = o >> 6;
        int phys = (o >> 4) & 3;
        int s    = phys ^ ((p ^ (p >> 2)) & 3);
        int pr   = p >> 5, c = p & 31;
        pixoff = ((size_t)((r0 + pr) * 34 + c)) * 256 + s * 8;
    }

    f32x4 acc[4][2];
    #pragma unroll
    for (int m = 0; m < 4; ++m)
        #pragma unroll
        for (int n = 0; n < 2; ++n) acc[m][n] = (f32x4){0.f, 0.f, 0.f, 0.f};

    int aoff[4], boff[2];
    #pragma unroll
    for (int m = 0; m < 4; ++m) {
        int row  = wr * 64 + m * 16 + (lane & 15);
        int phys = (lane >> 4) ^ ((row ^ (row >> 2)) & 3);
        aoff[m] = row * 32 + phys * 8;
    }
    #pragma unroll
    for (int n = 0; n < 2; ++n) {
        int row  = wc * 32 + n * 16 + (lane & 15);
        int phys = (lane >> 4) ^ ((row ^ (row >> 2)) & 3);
        boff[n] = row * 32 + phys * 8;
    }

    auto stage = [&](int kk, int buf) {
        int t = kk >> 3, cic = kk & 7;
        int dy = t / 3, dx = t - dy * 3;
        int koff = (dy * 34 + dx) * 256 + cic * 32;              // wave-uniform
        const ushort_t* wtile = WbI + ((size_t)(t * 8 + cic) * 6 + by) * 4096;
        #pragma unroll
        for (int r = 0; r < 2; ++r)
            GLOAD16(wtile + r * 2048 + tid * 8, (ushort_t*)As[buf] + r * 2048 + tid * 8);
        GLOAD16(xpI + pixoff + koff, (ushort_t*)Bsh[buf] + tid * 8);
    };

    stage(0, 0);
    asm volatile("s_waitcnt vmcnt(0)" ::: "memory");
    __builtin_amdgcn_s_barrier();

    for (int kk = 0; kk < 72; ++kk) {
        int cur = kk & 1;
        if (kk < 71) stage(kk + 1, cur ^ 1);

        const ushort_t* Ab = As[cur];
        const ushort_t* Bb = Bsh[cur];
        bf16x8 af[4], bfr[2];
        #pragma unroll
        for (int m = 0; m < 4; ++m) af[m] = *(const bf16x8*)(Ab + aoff[m]);
        #pragma unroll
        for (int n = 0; n < 2; ++n) bfr[n] = *(const bf16x8*)(Bb + boff[n]);

        #pragma unroll
        for (int m = 0; m < 4; ++m)
            #pragma unroll
            for (int n = 0; n < 2; ++n)
                acc[m][n] = __builtin_amdgcn_mfma_f32_16x16x32_bf16(af[m], bfr[n], acc[m][n], 0, 0, 0);

        asm volatile("s_waitcnt vmcnt(0)" ::: "memory");
        __builtin_amdgcn_s_barrier();
    }

    const int co_base = by * 128 + wr * 64;
    const int p_base  = bx * 64 + wc * 32;
    const int rsub = (lane >> 4) * 4;
    const int csub = lane & 15;
    #pragma unroll
    for (int m = 0; m < 4; ++m) {
        #pragma unroll
        for (int rg = 0; rg < 4; ++rg) {
            int ch = co_base + m * 16 + rsub + rg;
            float bias = Bs_bias[ch];
            #pragma unroll
            for (int nn = 0; nn < 2; ++nn) {
                int p = p_base + nn * 16 + csub;
                float v = acc[m][nn][rg] + bias;
                if (ch < 256)
                    Qf[((size_t)slab * 256 + ch) * HW + p] = v * 0.17677669529663687f;
                else if (ch < 512)
                    Kb[((size_t)slab * 256 + (ch - 256)) * HW + p] = f2bf(v);
                else
                    Vb[((size_t)slab * 256 + (ch - 512)) * HW + p] = f2bf(v);
            }
        }
    }
}

// ---------------------------------------------------------------------------
// trans_kernel: build attention MFMA operand tensors (unchanged).
// ---------------------------------------------------------------------------
__global__ __launch_bounds__(256) void trans_kernel(
    const float* __restrict__ Qf, const ushort_t* __restrict__ Kb,
    ushort_t* __restrict__ QThi, ushort_t* __restrict__ QTlo,
    ushort_t* __restrict__ K12T, ushort_t* __restrict__ KdT)
{
    const int z  = blockIdx.y;
    const int k0 = blockIdx.x * 256;
    const int tid = threadIdx.x;
    __shared__ float ts[32][257];

    if (z < 96) {
        int slab = z >> 3, n = z & 7;
        const float* src = Qf + ((size_t)slab * 256 + n * 32) * HW + k0;
        for (int idx = tid; idx < 8192; idx += 256) {
            int d = idx >> 8, k = idx & 255;
            ts[d][k] = src[(size_t)d * HW + k];
        }
        __syncthreads();
        ushort_t* dh = QThi + (size_t)z * 32768 + (size_t)k0 * 32;
        ushort_t* dl = QTlo + (size_t)z * 32768 + (size_t)k0 * 32;
        for (int idx = tid; idx < 8192; idx += 256) {
            int k = idx >> 5, d = idx & 31;
            float v = ts[d][k];
            ushort_t hi = f2bf(v);
            dh[(size_t)k * 32 + d] = hi;
            dl[(size_t)k * 32 + d] = f2bf(v - bf2f(hi));
        }
    } else if (z < 128) {
        int bn = z - 96, b = bn >> 3, n = bn & 7;
        const ushort_t* src = Kb + ((size_t)(8 + b) * 256 + n * 32) * HW + k0;
        for (int idx = tid; idx < 8192; idx += 256) {
            int d = idx >> 8, k = idx & 255;
            ts[d][k] = bf2f(src[(size_t)d * HW + k]);
        }
        __syncthreads();
        ushort_t* dst = K12T + (size_t)bn * 32768 + (size_t)k0 * 32;
        for (int idx = tid; idx < 8192; idx += 256) {
            int k = idx >> 5, d = idx & 31;
            dst[(size_t)k * 32 + d] = f2bf(ts[d][k]);
        }
    } else {
        int bn = z - 128, b = bn >> 3, n = bn & 7;
        const ushort_t* sA = Kb + ((size_t)b * 256 + n * 32) * HW + k0;
        const ushort_t* sB = Kb + ((size_t)(4 + b) * 256 + n * 32) * HW + k0;
        for (int idx = tid; idx < 8192; idx += 256) {
            int d = idx >> 8, k = idx & 255;
            ts[d][k] = bf2f(sA[(size_t)d * HW + k]) - bf2f(sB[(size_t)d * HW + k]);
        }
        __syncthreads();
        ushort_t* dst = KdT + (size_t)bn * 32768 + (size_t)k0 * 32;
        for (int idx = tid; idx < 8192; idx += 256) {
            int k = idx >> 5, d = idx & 31;
            dst[(size_t)k * 32 + d] = f2bf(ts[d][k]);
        }
    }
}

// ---------------------------------------------------------------------------
// rel_kernel: RW'/RH' tables from FP32 Q. grid (4 qchunk, 2 mhalf, 32 bn).
// ---------------------------------------------------------------------------
__global__ __launch_bounds__(256) void rel_kernel(
    const float* __restrict__ Qf,
    const float* __restrict__ krw, const float* __restrict__ krh,
    float* __restrict__ RWp, float* __restrict__ RHp)
{
    const int tid = threadIdx.x;
    const int mh  = blockIdx.y;
    const int bn  = blockIdx.z;
    const int b   = bn >> 3, n = bn & 7;
    const int q   = blockIdx.x * 256 + tid;
    const int r   = q >> 5, c = q & 31;

    __shared__ float rwl[63 * 33 + 1];
    __shared__ float rhl[63 * 33 + 1];
    for (int idx = tid; idx < 63 * 32; idx += 256) {
        int mp = idx >> 5, d = idx & 31;
        rwl[mp * 33 + d] = krw[idx];
        rhl[mp * 33 + d] = krh[idx];
    }
    __syncthreads();

    float qv[32];
    const float* qp = Qf + ((size_t)b * 256 + n * 32) * HW;
    #pragma unroll
    for (int d = 0; d < 32; ++d) qv[d] = qp[(size_t)d * HW + q];

    float* rw = RWp + ((size_t)bn * 1024 + q) * 32;
    float* rh = RHp + ((size_t)bn * 1024 + q) * 32;
    #pragma unroll
    for (int m = 0; m < 16; ++m) {
        int mm = mh * 16 + m;
        const float* t1 = rwl + (mm + 31 - c) * 33;
        const float* t2 = rhl + (mm + 31 - r) * 33;
        float s1 = 0.f, s2 = 0.f;
        #pragma unroll
        for (int d = 0; d < 32; ++d) { s1 = fmaf(qv[d], t1[d], s1); s2 = fmaf(qv[d], t2[d], s2); }
        rw[mm] = s1;
        rh[mm] = s2;
    }
}

// ---------------------------------------------------------------------------
// attn_mfma: flash attention, swapped operands (S^T = K x Q). R10/R11 EXACT.
// ---------------------------------------------------------------------------
__global__ __launch_bounds__(256) void attn_mfma_kernel(
    const ushort_t* __restrict__ QThi, const ushort_t* __restrict__ QTlo,
    const ushort_t* __restrict__ K12T, const ushort_t* __restrict__ KdT,
    const ushort_t* __restrict__ Vb,
    const float* __restrict__ RWp, const float* __restrict__ RHp,
    float* __restrict__ yw)
{
    const int qt = blockIdx.x;
    const int bn = blockIdx.y;
    const int br = blockIdx.z;
    const int b  = bn >> 3, n = bn & 7;
    const int tid = threadIdx.x, lane = tid & 63, wid = tid >> 6;
    const int q0 = qt * 128;

    __shared__ ushort_t qt_l[2][4096];     // [hi/lo][128 q][32 d] linear
    __shared__ ushort_t kt_l[2][2048];     // [64 k][32 d] linear (dbuf)
    __shared__ ushort_t v_l[2][2048];      // [32 d][64 k], chunk^(d&7) (dbuf)
    __shared__ ushort_t p_l[4][2048];      // per-wave [32 q][64 k], chunk-XOR

    const int slab = br * 4 + b;
    const size_t qoff = ((size_t)(slab * 8 + n) * 1024 + q0) * 32;
    const ushort_t* KTb = ((br == 2) ? KdT : K12T) + (size_t)bn * 32768;
    const ushort_t* Vg  = Vb + ((size_t)slab * 256 + n * 32) * HW;

    GLOAD16((const char*)(QThi + qoff) + tid * 16,        (char*)qt_l[0] + tid * 16);
    GLOAD16((const char*)(QThi + qoff) + 4096 + tid * 16, (char*)qt_l[0] + 4096 + tid * 16);
    GLOAD16((const char*)(QTlo + qoff) + tid * 16,        (char*)qt_l[1] + tid * 16);
    GLOAD16((const char*)(QTlo + qoff) + 4096 + tid * 16, (char*)qt_l[1] + 4096 + tid * 16);

    const int vd = tid >> 3, vpc = tid & 7;
    const char* Vrow = (const char*)Vg + (size_t)vd * 2048 + ((vpc ^ (vd & 7)) * 16);
    auto stage = [&](int t, int buf) {
        GLOAD16((const char*)KTb + t * 4096 + tid * 16, (char*)kt_l[buf] + tid * 16);
        GLOAD16(Vrow + t * 128,                          (char*)v_l[buf] + tid * 16);
    };
    stage(0, 0);

    float rwc[2][8];
    if (br == 0) {
        #pragma unroll
        for (int m = 0; m < 2; ++m) {
            int q = q0 + wid * 32 + m * 16 + (lane & 15);
            const float* rwp = RWp + ((size_t)bn * 1024 + q) * 32;
            #pragma unroll
            for (int i = 0; i < 2; ++i)
                #pragma unroll
                for (int r = 0; r < 4; ++r)
                    rwc[m][i * 4 + r] = rwp[i * 16 + 4 * (lane >> 4) + r];
        }
    }

    asm volatile("s_waitcnt vmcnt(0)" ::: "memory");
    __builtin_amdgcn_s_barrier();

    bf16x8 qfh[2], qfl[2];
    #pragma unroll
    for (int m = 0; m < 2; ++m) {
        int off = (wid * 32 + m * 16 + (lane & 15)) * 32 + (lane >> 4) * 8;
        qfh[m] = *(const bf16x8*)(qt_l[0] + off);
        qfl[m] = *(const bf16x8*)(qt_l[1] + off);
    }

    f32x4 oacc[2][2];
    #pragma unroll
    for (int ds = 0; ds < 2; ++ds)
        #pragma unroll
        for (int m = 0; m < 2; ++m) oacc[ds][m] = (f32x4){0.f, 0.f, 0.f, 0.f};
    float m_run[2] = {-INFINITY, -INFINITY}, l_run[2] = {0.f, 0.f};
    const f32x4 zero4 = (f32x4){0.f, 0.f, 0.f, 0.f};

    for (int t = 0; t < 16; ++t) {
        int cur = t & 1;

        float rh[2][2];
        if (br == 0) {
            #pragma unroll
            for (int m = 0; m < 2; ++m) {
                int q = q0 + wid * 32 + m * 16 + (lane & 15);
                const float* rhp = RHp + ((size_t)bn * 1024 + q) * 32 + 2 * t;
                rh[m][0] = rhp[0];
                rh[m][1] = rhp[1];
            }
        }
        if (t < 15) stage(t + 1, cur ^ 1);

        bf16x8 kf[4];
        #pragma unroll
        for (int s = 0; s < 4; ++s)
            kf[s] = *(const bf16x8*)(kt_l[cur] + (s * 16 + (lane & 15)) * 32 + (lane >> 4) * 8);

        f32x4 sa[4][2];
        #pragma unroll
        for (int s = 0; s < 4; ++s)
            #pragma unroll
            for (int m = 0; m < 2; ++m) {
                sa[s][m] = __builtin_amdgcn_mfma_f32_16x16x32_bf16(kf[s], qfl[m], zero4, 0, 0, 0);
                sa[s][m] = __builtin_amdgcn_mfma_f32_16x16x32_bf16(kf[s], qfh[m], sa[s][m], 0, 0, 0);
            }

        if (br == 0) {
            #pragma unroll
            for (int s = 0; s < 4; ++s)
                #pragma unroll
                for (int m = 0; m < 2; ++m)
                    #pragma unroll
                    for (int r = 0; r < 4; ++r)
                        sa[s][m][r] += rwc[m][(s & 1) * 4 + r] + rh[m][s >> 1];
        }

        #pragma unroll
        for (int m = 0; m < 2; ++m) {
            float mx = sa[0][m][0];
            #pragma unroll
            for (int s = 0; s < 4; ++s)
                #pragma unroll
                for (int r = 0; r < 4; ++r) mx = fmaxf(mx, sa[s][m][r]);
            mx = fmaxf(mx, __shfl_xor(mx, 16));
            mx = fmaxf(mx, __shfl_xor(mx, 32));
            float mnew = fmaxf(m_run[m], mx);
            float sc = __expf(m_run[m] - mnew);
            float ps = 0.f;
            #pragma unroll
            for (int s = 0; s < 4; ++s)
                #pragma unroll
                for (int r = 0; r < 4; ++r) {
                    float p = __expf(sa[s][m][r] - mnew);
                    sa[s][m][r] = p;
                    ps += p;
                }
            ps += __shfl_xor(ps, 16);
            ps += __shfl_xor(ps, 32);
            l_run[m] = l_run[m] * sc + ps;
            m_run[m] = mnew;
            oacc[0][m] = oacc[0][m] * sc;
            oacc[1][m] = oacc[1][m] * sc;
        }

        // P -> bf16 (single plane) -> per-wave LDS (chunk-XOR swizzle)
        const int g = lane >> 4;
        #pragma unroll
        for (int s = 0; s < 4; ++s)
            #pragma unroll
            for (int m = 0; m < 2; ++m) {
                int qrow = m * 16 + (lane & 15);
                int chunk = (2 * s + (g >> 1)) ^ (qrow & 7);
                char* basep = (char*)p_l[wid] + qrow * 128 + chunk * 16 + 8 * (g & 1);
                #pragma unroll
                for (int h = 0; h < 2; ++h) {
                    unsigned pk = (unsigned)f2bf(sa[s][m][2 * h])
                                | ((unsigned)f2bf(sa[s][m][2 * h + 1]) << 16);
                    *(unsigned*)(basep + 4 * h) = pk;
                }
            }

        // PV: O^T += V^T x P
        #pragma unroll
        for (int ks = 0; ks < 2; ++ks) {
            bf16x8 vf[2], pfh[2];
            #pragma unroll
            for (int ds = 0; ds < 2; ++ds) {
                int drow = ds * 16 + (lane & 15);
                int chunk = (4 * ks + g) ^ (drow & 7);
                vf[ds] = *(const bf16x8*)((char*)v_l[cur] + drow * 128 + chunk * 16);
            }
            #pragma unroll
            for (int m = 0; m < 2; ++m) {
                int qrow = m * 16 + (lane & 15);
                int chunk = (4 * ks + g) ^ (qrow & 7);
                pfh[m] = *(const bf16x8*)((char*)p_l[wid] + qrow * 128 + chunk * 16);
            }
            #pragma unroll
            for (int ds = 0; ds < 2; ++ds)
                #pragma unroll
                for (int m = 0; m < 2; ++m)
                    oacc[ds][m] = __builtin_amdgcn_mfma_f32_16x16x32_bf16(vf[ds], pfh[m], oacc[ds][m], 0, 0, 0);
        }

        asm volatile("s_waitcnt vmcnt(0)" ::: "memory");
        __builtin_amdgcn_s_barrier();
    }

    #pragma unroll
    for (int m = 0; m < 2; ++m) {
        float inv = 1.0f / l_run[m];
        int q = q0 + wid * 32 + m * 16 + (lane & 15);
        int rr = q >> 5, cc = q & 31;
        float* yb = yw + ((size_t)((br * 4 + b) * 256 + n * 32 + rr)) * HW + cc * 32;
        #pragma unroll
        for (int ds = 0; ds < 2; ++ds) {
            int dbase = ds * 16 + (lane >> 4) * 4;
            float4 o = make_float4(oacc[ds][m][0] * inv, oacc[ds][m][1] * inv,
                                   oacc[ds][m][2] * inv, oacc[ds][m][3] * inv);
            *reinterpret_cast<float4*>(yb + dbase) = o;
        }
    }
}

// ---------------------------------------------------------------------------
// conv1x1: 512-pixel tile, 2 pixels/thread, ci-chunks of 16 (unchanged).
// ---------------------------------------------------------------------------
__global__ __launch_bounds__(256) void conv1x1_kernel(
    const float* __restrict__ yw, const float* __restrict__ Wo,
    const float* __restrict__ bo, float* __restrict__ out)
{
    const int co0  = blockIdx.x * 16;
    const int p0   = blockIdx.y * 512;
    const int slab = blockIdx.z;
    const float* yb = yw + (size_t)slab * 256 * HW;
    float* ob       = out + (size_t)slab * 256 * HW;

    __shared__ float ys[16][512];
    __shared__ float wsl[16][16];

    const int tid = threadIdx.x;
    float acc0[16], acc1[16];
    #pragma unroll
    for (int co = 0; co < 16; ++co) { acc0[co] = 0.f; acc1[co] = 0.f; }

    for (int ci0 = 0; ci0 < 256; ci0 += 16) {
        __syncthreads();
        for (int idx = tid; idx < 16 * 512; idx += 256) {
            int ci = idx >> 9, p = idx & 511;
            ys[ci][p] = yb[(size_t)(ci0 + ci) * HW + p0 + p];
        }
        {
            int ci = tid >> 4, co = tid & 15;
            wsl[ci][co] = Wo[(size_t)(co0 + co) * 256 + ci0 + ci];
        }
        __syncthreads();
        #pragma unroll
        for (int ci = 0; ci < 16; ++ci) {
            float xv0 = ys[ci][tid];
            float xv1 = ys[ci][tid + 256];
            const float4* wp = reinterpret_cast<const float4*>(&wsl[ci][0]);
            float4 w0 = wp[0], w1 = wp[1], w2 = wp[2], w3 = wp[3];
            acc0[0]  = fmaf(w0.x, xv0, acc0[0]);  acc1[0]  = fmaf(w0.x, xv1, acc1[0]);
            acc0[1]  = fmaf(w0.y, xv0, acc0[1]);  acc1[1]  = fmaf(w0.y, xv1, acc1[1]);
            acc0[2]  = fmaf(w0.z, xv0, acc0[2]);  acc1[2]  = fmaf(w0.z, xv1, acc1[2]);
            acc0[3]  = fmaf(w0.w, xv0, acc0[3]);  acc1[3]  = fmaf(w0.w, xv1, acc1[3]);
            acc0[4]  = fmaf(w1.x, xv0, acc0[4]);  acc1[4]  = fmaf(w1.x, xv1, acc1[4]);
            acc0[5]  = fmaf(w1.y, xv0, acc0[5]);  acc1[5]  = fmaf(w1.y, xv1, acc1[5]);
            acc0[6]  = fmaf(w1.z, xv0, acc0[6]);  acc1[6]  = fmaf(w1.z, xv1, acc1[6]);
            acc0[7]  = fmaf(w1.w, xv0, acc0[7]);  acc1[7]  = fmaf(w1.w, xv1, acc1[7]);
            acc0[8]  = fmaf(w2.x, xv0, acc0[8]);  acc1[8]  = fmaf(w2.x, xv1, acc1[8]);
            acc0[9]  = fmaf(w2.y, xv0, acc0[9]);  acc1[9]  = fmaf(w2.y, xv1, acc1[9]);
            acc0[10] = fmaf(w2.z, xv0, acc0[10]); acc1[10] = fmaf(w2.z, xv1, acc1[10]);
            acc0[11] = fmaf(w2.w, xv0, acc0[11]); acc1[11] = fmaf(w2.w, xv1, acc1[11]);
            acc0[12] = fmaf(w3.x, xv0, acc0[12]); acc1[12] = fmaf(w3.x, xv1, acc1[12]);
            acc0[13] = fmaf(w3.y, xv0, acc0[13]); acc1[13] = fmaf(w3.y, xv1, acc1[13]);
            acc0[14] = fmaf(w3.z, xv0, acc0[14]); acc1[14] = fmaf(w3.z, xv1, acc1[14]);
            acc0[15] = fmaf(w3.w, xv0, acc0[15]); acc1[15] = fmaf(w3.w, xv1, acc1[15]);
        }
    }
    #pragma unroll
    for (int co = 0; co < 16; ++co) {
        float bb = bo[co0 + co];
        ob[(size_t)(co0 + co) * HW + p0 + tid]       = acc0[co] + bb;
        ob[(size_t)(co0 + co) * HW + p0 + tid + 256] = acc1[co] + bb;
    }
}

// ---------------------------------------------------------------------------
extern "C" void kernel_launch(void* const* d_in, const int* in_sizes, int n_in,
                              void* d_out, int out_size, void* d_ws, size_t ws_size,
                              hipStream_t stream)
{
    const float* x1   = (const float*)d_in[0];
    const float* x2   = (const float*)d_in[1];
    const float* x12  = (const float*)d_in[2];
    const float* Wq1  = (const float*)d_in[3];
    const float* bq1  = (const float*)d_in[4];
    const float* Wq2  = (const float*)d_in[5];
    const float* bq2  = (const float*)d_in[6];
    const float* Wq12 = (const float*)d_in[7];
    const float* bq12 = (const float*)d_in[8];
    const float* Wo   = (const float*)d_in[9];
    const float* bo   = (const float*)d_in[10];
    const float* krw  = (const float*)d_in[11];
    const float* krh  = (const float*)d_in[12];

    // workspace layout (identical to R4/R6/R7/R10/R11)
    char* base = (char*)d_ws;
    float*    Qf    = (float*)base;
    float*    yw    = (float*)base;                      // alias: attn out
    ushort_t* Kb    = (ushort_t*)(base + 12582912);
    ushort_t* Vb    = (ushort_t*)(base + 18874368);
    ushort_t* QThi  = (ushort_t*)(base + 25165824);
    ushort_t* QTlo  = (ushort_t*)(base + 31457280);
    ushort_t* K12T  = (ushort_t*)(base + 37748736);
    ushort_t* KdT   = (ushort_t*)(base + 39845888);
    float*    RWp   = (float*)(base + 41943040);
    float*    RHp   = (float*)(base + 46137344);
    ushort_t* Wb    = (ushort_t*)(base + 25165824);      // alias, dead after conv
    ushort_t* xpadT = (ushort_t*)(base + 35782656);      // alias, dead after conv
    float*    outf  = (float*)d_out;

    const size_t xpad_bytes = (size_t)12 * 34 * 34 * 256 * 2;
    hipMemsetAsync(xpadT, 0, xpad_bytes, stream);

    hipLaunchKernelGGL(prep_x_kernel, dim3(32, 12), dim3(256), 0, stream,
                       x1, x2, x12, xpadT);
    hipLaunchKernelGGL(prep_w_kernel, dim3(2304), dim3(256), 0, stream,
                       Wq1, Wq2, Wq12, Wb);
    hipLaunchKernelGGL(conv_mfma_kernel, dim3(16, 6, 12), dim3(256), 0, stream,
                       Wb, xpadT, bq1, bq2, bq12, Qf, Kb, Vb);
    hipLaunchKernelGGL(trans_kernel, dim3(4, 160), dim3(256), 0, stream,
                       Qf, Kb, QThi, QTlo, K12T, KdT);
    hipLaunchKernelGGL(rel_kernel, dim3(4, 2, 32), dim3(256), 0, stream,
                       Qf, krw, krh, RWp, RHp);
    hipLaunchKernelGGL(attn_mfma_kernel, dim3(8, 32, 3), dim3(256), 0, stream,
                       QThi, QTlo, K12T, KdT, Vb, RWp, RHp, yw);
    hipLaunchKernelGGL(conv1x1_kernel, dim3(16, 2, 12), dim3(256), 0, stream,
                       yw, Wo, bo, outf);
}

// Round 14
// 228.947 us; speedup vs baseline: 1.1050x; 1.0243x over previous
//
#include <hip/hip_runtime.h>
#include <math.h>

#define HW   1024
#define NCH  768

typedef __bf16 bf16x8 __attribute__((ext_vector_type(8)));
typedef float f32x4 __attribute__((ext_vector_type(4)));
typedef unsigned short ushort_t;

__device__ __forceinline__ ushort_t f2bf(float f) {
    unsigned u = __builtin_bit_cast(unsigned, f);
    u += 0x7fffu + ((u >> 16) & 1u);           // round-to-nearest-even
    return (ushort_t)(u >> 16);
}
__device__ __forceinline__ float bf2f(ushort_t s) {
    unsigned u = ((unsigned)s) << 16;
    return __builtin_bit_cast(float, u);
}

#define GLOAD16(g, l) __builtin_amdgcn_global_load_lds( \
    (const __attribute__((address_space(1))) void*)(g), \
    (__attribute__((address_space(3))) void*)(l), 16, 0, 0)

// ---------------------------------------------------------------------------
// prep_x: x [img][b][256][32][32] fp32 -> xpadT [slab][34][34][256] bf16.
// (halo zeroed by hipMemsetAsync before this kernel.)
// ---------------------------------------------------------------------------
__global__ __launch_bounds__(256) void prep_x_kernel(
    const float* __restrict__ x1, const float* __restrict__ x2, const float* __restrict__ x12,
    ushort_t* __restrict__ xpadT)
{
    const int row  = blockIdx.x;
    const int slab = blockIdx.y;
    const int img  = slab >> 2, b = slab & 3;
    const float* x  = (img == 0) ? x1 : (img == 1) ? x2 : x12;
    const float* xb = x + (size_t)b * 256 * HW + row * 32;

    __shared__ float xs[32][257];
    const int tid = threadIdx.x;
    for (int idx = tid; idx < 256 * 32; idx += 256) {
        int ci = idx >> 5, col = idx & 31;
        xs[col][ci] = xb[(size_t)ci * HW + col];
    }
    __syncthreads();
    ushort_t* ob = xpadT + ((size_t)slab * 34 * 34 + (size_t)(row + 1) * 34 + 1) * 256;
    for (int col = 0; col < 32; ++col)
        ob[(size_t)col * 256 + tid] = f2bf(xs[col][tid]);
}

// ---------------------------------------------------------------------------
// prep_w: pre-swizzled bf16 A-tiles for conv (unchanged).
// ---------------------------------------------------------------------------
__global__ __launch_bounds__(256) void prep_w_kernel(
    const float* __restrict__ W1, const float* __restrict__ W2, const float* __restrict__ W3,
    ushort_t* __restrict__ Wb)
{
    int g = blockIdx.x * 256 + threadIdx.x;
    if (g >= 3 * 768 * 256) return;
    int ci  = g & 255;
    int co  = (g >> 8) % 768;
    int img = g / (768 * 256);
    const float* Wt  = (img == 0) ? W1 : (img == 1) ? W2 : W3;
    const float* src = Wt + (size_t)co * (256 * 9) + ci * 9;

    int coc = co >> 7, row = co & 127;
    int cic = ci >> 5;
    int cil = ci & 31;
    int s = cil >> 3, e = cil & 7;
    int phys  = s ^ ((row ^ (row >> 2)) & 3);
    int inner = row * 32 + phys * 8 + e;
    #pragma unroll
    for (int t = 0; t < 9; ++t) {
        size_t tile = (((size_t)img * 9 + t) * 8 + cic) * 6 + coc;
        Wb[tile * 4096 + inner] = f2bf(src[t]);
    }
}

// ---------------------------------------------------------------------------
// conv_mfma: implicit-GEMM 3x3 conv with XCD-aware bijective block remap
// (R11/R13 exact; FETCH_SIZE 49->21 MB verified).
// ---------------------------------------------------------------------------
__global__ __launch_bounds__(256) void conv_mfma_kernel(
    const ushort_t* __restrict__ Wb, const ushort_t* __restrict__ xpadT,
    const float* __restrict__ B1, const float* __restrict__ B2, const float* __restrict__ B3,
    float* __restrict__ Qf, ushort_t* __restrict__ Kb, ushort_t* __restrict__ Vb)
{
    // XCD-aware remap (pure index math; per-block work unchanged)
    const int orig = blockIdx.x + 16 * (blockIdx.y + 6 * blockIdx.z);
    const int swz  = (orig & 7) * 144 + (orig >> 3);
    const int bx   = swz & 15;            // p-tile (64 pixels = 2 image rows)
    const int by   = (swz >> 4) % 6;      // co-tile (128 ch)
    const int slab = swz / 96;            // img*4 + b
    const int img  = slab >> 2;
    const float* Bs_bias = (img == 0) ? B1 : (img == 1) ? B2 : B3;

    __shared__ ushort_t As[2][4096];   // [128 co][4 slot][8] swizzled
    __shared__ ushort_t Bsh[2][2048];  // [64 p ][4 slot][8] swizzled

    const int tid  = threadIdx.x;
    const int lane = tid & 63;
    const int wid  = tid >> 6;
    const int wr   = wid >> 1, wc = wid & 1;

    const ushort_t* WbI = Wb + (size_t)img * 9 * 8 * 6 * 4096;
    const ushort_t* xpI = xpadT + (size_t)slab * 34 * 34 * 256;
    const int r0 = bx * 2;            // first image row of this tile

    size_t pixoff;
    {
        int o    = tid * 16;
        int p    = o >> 6;
        int phys = (o >> 4) & 3;
        int s    = phys ^ ((p ^ (p >> 2)) & 3);
        int pr   = p >> 5, c = p & 31;
        pixoff = ((size_t)((r0 + pr) * 34 + c)) * 256 + s * 8;
    }

    f32x4 acc[4][2];
    #pragma unroll
    for (int m = 0; m < 4; ++m)
        #pragma unroll
        for (int n = 0; n < 2; ++n) acc[m][n] = (f32x4){0.f, 0.f, 0.f, 0.f};

    int aoff[4], boff[2];
    #pragma unroll
    for (int m = 0; m < 4; ++m) {
        int row  = wr * 64 + m * 16 + (lane & 15);
        int phys = (lane >> 4) ^ ((row ^ (row >> 2)) & 3);
        aoff[m] = row * 32 + phys * 8;
    }
    #pragma unroll
    for (int n = 0; n < 2; ++n) {
        int row  = wc * 32 + n * 16 + (lane & 15);
        int phys = (lane >> 4) ^ ((row ^ (row >> 2)) & 3);
        boff[n] = row * 32 + phys * 8;
    }

    auto stage = [&](int kk, int buf) {
        int t = kk >> 3, cic = kk & 7;
        int dy = t / 3, dx = t - dy * 3;
        int koff = (dy * 34 + dx) * 256 + cic * 32;              // wave-uniform
        const ushort_t* wtile = WbI + ((size_t)(t * 8 + cic) * 6 + by) * 4096;
        #pragma unroll
        for (int r = 0; r < 2; ++r)
            GLOAD16(wtile + r * 2048 + tid * 8, (ushort_t*)As[buf] + r * 2048 + tid * 8);
        GLOAD16(xpI + pixoff + koff, (ushort_t*)Bsh[buf] + tid * 8);
    };

    stage(0, 0);
    asm volatile("s_waitcnt vmcnt(0)" ::: "memory");
    __builtin_amdgcn_s_barrier();

    for (int kk = 0; kk < 72; ++kk) {
        int cur = kk & 1;
        if (kk < 71) stage(kk + 1, cur ^ 1);

        const ushort_t* Ab = As[cur];
        const ushort_t* Bb = Bsh[cur];
        bf16x8 af[4], bfr[2];
        #pragma unroll
        for (int m = 0; m < 4; ++m) af[m] = *(const bf16x8*)(Ab + aoff[m]);
        #pragma unroll
        for (int n = 0; n < 2; ++n) bfr[n] = *(const bf16x8*)(Bb + boff[n]);

        #pragma unroll
        for (int m = 0; m < 4; ++m)
            #pragma unroll
            for (int n = 0; n < 2; ++n)
                acc[m][n] = __builtin_amdgcn_mfma_f32_16x16x32_bf16(af[m], bfr[n], acc[m][n], 0, 0, 0);

        asm volatile("s_waitcnt vmcnt(0)" ::: "memory");
        __builtin_amdgcn_s_barrier();
    }

    const int co_base = by * 128 + wr * 64;
    const int p_base  = bx * 64 + wc * 32;
    const int rsub = (lane >> 4) * 4;
    const int csub = lane & 15;
    #pragma unroll
    for (int m = 0; m < 4; ++m) {
        #pragma unroll
        for (int rg = 0; rg < 4; ++rg) {
            int ch = co_base + m * 16 + rsub + rg;
            float bias = Bs_bias[ch];
            #pragma unroll
            for (int nn = 0; nn < 2; ++nn) {
                int p = p_base + nn * 16 + csub;
                float v = acc[m][nn][rg] + bias;
                if (ch < 256)
                    Qf[((size_t)slab * 256 + ch) * HW + p] = v * 0.17677669529663687f;
                else if (ch < 512)
                    Kb[((size_t)slab * 256 + (ch - 256)) * HW + p] = f2bf(v);
                else
                    Vb[((size_t)slab * 256 + (ch - 512)) * HW + p] = f2bf(v);
            }
        }
    }
}

// ---------------------------------------------------------------------------
// trans_kernel: build attention MFMA operand tensors (unchanged).
// ---------------------------------------------------------------------------
__global__ __launch_bounds__(256) void trans_kernel(
    const float* __restrict__ Qf, const ushort_t* __restrict__ Kb,
    ushort_t* __restrict__ QThi, ushort_t* __restrict__ QTlo,
    ushort_t* __restrict__ K12T, ushort_t* __restrict__ KdT)
{
    const int z  = blockIdx.y;
    const int k0 = blockIdx.x * 256;
    const int tid = threadIdx.x;
    __shared__ float ts[32][257];

    if (z < 96) {
        int slab = z >> 3, n = z & 7;
        const float* src = Qf + ((size_t)slab * 256 + n * 32) * HW + k0;
        for (int idx = tid; idx < 8192; idx += 256) {
            int d = idx >> 8, k = idx & 255;
            ts[d][k] = src[(size_t)d * HW + k];
        }
        __syncthreads();
        ushort_t* dh = QThi + (size_t)z * 32768 + (size_t)k0 * 32;
        ushort_t* dl = QTlo + (size_t)z * 32768 + (size_t)k0 * 32;
        for (int idx = tid; idx < 8192; idx += 256) {
            int k = idx >> 5, d = idx & 31;
            float v = ts[d][k];
            ushort_t hi = f2bf(v);
            dh[(size_t)k * 32 + d] = hi;
            dl[(size_t)k * 32 + d] = f2bf(v - bf2f(hi));
        }
    } else if (z < 128) {
        int bn = z - 96, b = bn >> 3, n = bn & 7;
        const ushort_t* src = Kb + ((size_t)(8 + b) * 256 + n * 32) * HW + k0;
        for (int idx = tid; idx < 8192; idx += 256) {
            int d = idx >> 8, k = idx & 255;
            ts[d][k] = bf2f(src[(size_t)d * HW + k]);
        }
        __syncthreads();
        ushort_t* dst = K12T + (size_t)bn * 32768 + (size_t)k0 * 32;
        for (int idx = tid; idx < 8192; idx += 256) {
            int k = idx >> 5, d = idx & 31;
            dst[(size_t)k * 32 + d] = f2bf(ts[d][k]);
        }
    } else {
        int bn = z - 128, b = bn >> 3, n = bn & 7;
        const ushort_t* sA = Kb + ((size_t)b * 256 + n * 32) * HW + k0;
        const ushort_t* sB = Kb + ((size_t)(4 + b) * 256 + n * 32) * HW + k0;
        for (int idx = tid; idx < 8192; idx += 256) {
            int d = idx >> 8, k = idx & 255;
            ts[d][k] = bf2f(sA[(size_t)d * HW + k]) - bf2f(sB[(size_t)d * HW + k]);
        }
        __syncthreads();
        ushort_t* dst = KdT + (size_t)bn * 32768 + (size_t)k0 * 32;
        for (int idx = tid; idx < 8192; idx += 256) {
            int k = idx >> 5, d = idx & 31;
            dst[(size_t)k * 32 + d] = f2bf(ts[d][k]);
        }
    }
}

// ---------------------------------------------------------------------------
// rel_kernel: RW'/RH' tables from FP32 Q. grid (4 qchunk, 2 mhalf, 32 bn).
// ---------------------------------------------------------------------------
__global__ __launch_bounds__(256) void rel_kernel(
    const float* __restrict__ Qf,
    const float* __restrict__ krw, const float* __restrict__ krh,
    float* __restrict__ RWp, float* __restrict__ RHp)
{
    const int tid = threadIdx.x;
    const int mh  = blockIdx.y;
    const int bn  = blockIdx.z;
    const int b   = bn >> 3, n = bn & 7;
    const int q   = blockIdx.x * 256 + tid;
    const int r   = q >> 5, c = q & 31;

    __shared__ float rwl[63 * 33 + 1];
    __shared__ float rhl[63 * 33 + 1];
    for (int idx = tid; idx < 63 * 32; idx += 256) {
        int mp = idx >> 5, d = idx & 31;
        rwl[mp * 33 + d] = krw[idx];
        rhl[mp * 33 + d] = krh[idx];
    }
    __syncthreads();

    float qv[32];
    const float* qp = Qf + ((size_t)b * 256 + n * 32) * HW;
    #pragma unroll
    for (int d = 0; d < 32; ++d) qv[d] = qp[(size_t)d * HW + q];

    float* rw = RWp + ((size_t)bn * 1024 + q) * 32;
    float* rh = RHp + ((size_t)bn * 1024 + q) * 32;
    #pragma unroll
    for (int m = 0; m < 16; ++m) {
        int mm = mh * 16 + m;
        const float* t1 = rwl + (mm + 31 - c) * 33;
        const float* t2 = rhl + (mm + 31 - r) * 33;
        float s1 = 0.f, s2 = 0.f;
        #pragma unroll
        for (int d = 0; d < 32; ++d) { s1 = fmaf(qv[d], t1[d], s1); s2 = fmaf(qv[d], t2[d], s2); }
        rw[mm] = s1;
        rh[mm] = s2;
    }
}

// ---------------------------------------------------------------------------
// attn_mfma: flash attention, swapped operands (S^T = K x Q).
// Q-SPLIT version: 64 queries/block (wave owns 16 q; the m-loop of the
// R13 kernel deleted — every output element's FMA/MFMA graph unchanged).
// grid (16 qtiles, 32 bn, 3 br) = 1536 blocks (6/CU vs 3/CU before).
// LDS = qt 8KB + kt 8KB + v 8KB + p 8KB = 32KB -> 5 blocks/CU cap.
// Sync pattern per tile identical to R13 (stage -> vmcnt(0) -> barrier).
// ---------------------------------------------------------------------------
__global__ __launch_bounds__(256) void attn_mfma_kernel(
    const ushort_t* __restrict__ QThi, const ushort_t* __restrict__ QTlo,
    const ushort_t* __restrict__ K12T, const ushort_t* __restrict__ KdT,
    const ushort_t* __restrict__ Vb,
    const float* __restrict__ RWp, const float* __restrict__ RHp,
    float* __restrict__ yw)
{
    const int qt = blockIdx.x;
    const int bn = blockIdx.y;
    const int br = blockIdx.z;
    const int b  = bn >> 3, n = bn & 7;
    const int tid = threadIdx.x, lane = tid & 63, wid = tid >> 6;
    const int q0 = qt * 64;

    __shared__ ushort_t qt_l[2][2048];     // [hi/lo][64 q][32 d] linear
    __shared__ ushort_t kt_l[2][2048];     // [64 k][32 d] linear (dbuf)
    __shared__ ushort_t v_l[2][2048];      // [32 d][64 k], chunk^(d&7) (dbuf)
    __shared__ ushort_t p_l[4][1024];      // per-wave [16 q][64 k], chunk-XOR

    const int slab = br * 4 + b;
    const size_t qoff = ((size_t)(slab * 8 + n) * 1024 + q0) * 32;
    const ushort_t* KTb = ((br == 2) ? KdT : K12T) + (size_t)bn * 32768;
    const ushort_t* Vg  = Vb + ((size_t)slab * 256 + n * 32) * HW;

    GLOAD16((const char*)(QThi + qoff) + tid * 16, (char*)qt_l[0] + tid * 16);
    GLOAD16((const char*)(QTlo + qoff) + tid * 16, (char*)qt_l[1] + tid * 16);

    const int vd = tid >> 3, vpc = tid & 7;
    const char* Vrow = (const char*)Vg + (size_t)vd * 2048 + ((vpc ^ (vd & 7)) * 16);
    auto stage = [&](int t, int buf) {
        GLOAD16((const char*)KTb + t * 4096 + tid * 16, (char*)kt_l[buf] + tid * 16);
        GLOAD16(Vrow + t * 128,                          (char*)v_l[buf] + tid * 16);
    };
    stage(0, 0);

    float rwc[8];
    if (br == 0) {
        int q = q0 + wid * 16 + (lane & 15);
        const float* rwp = RWp + ((size_t)bn * 1024 + q) * 32;
        #pragma unroll
        for (int i = 0; i < 2; ++i)
            #pragma unroll
            for (int r = 0; r < 4; ++r)
                rwc[i * 4 + r] = rwp[i * 16 + 4 * (lane >> 4) + r];
    }

    asm volatile("s_waitcnt vmcnt(0)" ::: "memory");
    __builtin_amdgcn_s_barrier();

    bf16x8 qfh, qfl;
    {
        int off = (wid * 16 + (lane & 15)) * 32 + (lane >> 4) * 8;
        qfh = *(const bf16x8*)(qt_l[0] + off);
        qfl = *(const bf16x8*)(qt_l[1] + off);
    }

    f32x4 oacc[2];
    #pragma unroll
    for (int ds = 0; ds < 2; ++ds) oacc[ds] = (f32x4){0.f, 0.f, 0.f, 0.f};
    float m_run = -INFINITY, l_run = 0.f;
    const f32x4 zero4 = (f32x4){0.f, 0.f, 0.f, 0.f};

    for (int t = 0; t < 16; ++t) {
        int cur = t & 1;

        float rh[2];
        if (br == 0) {
            int q = q0 + wid * 16 + (lane & 15);
            const float* rhp = RHp + ((size_t)bn * 1024 + q) * 32 + 2 * t;
            rh[0] = rhp[0];
            rh[1] = rhp[1];
        }
        if (t < 15) stage(t + 1, cur ^ 1);

        bf16x8 kf[4];
        #pragma unroll
        for (int s = 0; s < 4; ++s)
            kf[s] = *(const bf16x8*)(kt_l[cur] + (s * 16 + (lane & 15)) * 32 + (lane >> 4) * 8);

        f32x4 sa[4];
        #pragma unroll
        for (int s = 0; s < 4; ++s) {
            sa[s] = __builtin_amdgcn_mfma_f32_16x16x32_bf16(kf[s], qfl, zero4, 0, 0, 0);
            sa[s] = __builtin_amdgcn_mfma_f32_16x16x32_bf16(kf[s], qfh, sa[s], 0, 0, 0);
        }

        if (br == 0) {
            #pragma unroll
            for (int s = 0; s < 4; ++s)
                #pragma unroll
                for (int r = 0; r < 4; ++r)
                    sa[s][r] += rwc[(s & 1) * 4 + r] + rh[s >> 1];
        }

        {
            float mx = sa[0][0];
            #pragma unroll
            for (int s = 0; s < 4; ++s)
                #pragma unroll
                for (int r = 0; r < 4; ++r) mx = fmaxf(mx, sa[s][r]);
            mx = fmaxf(mx, __shfl_xor(mx, 16));
            mx = fmaxf(mx, __shfl_xor(mx, 32));
            float mnew = fmaxf(m_run, mx);
            float sc = __expf(m_run - mnew);
            float ps = 0.f;
            #pragma unroll
            for (int s = 0; s < 4; ++s)
                #pragma unroll
                for (int r = 0; r < 4; ++r) {
                    float p = __expf(sa[s][r] - mnew);
                    sa[s][r] = p;
                    ps += p;
                }
            ps += __shfl_xor(ps, 16);
            ps += __shfl_xor(ps, 32);
            l_run = l_run * sc + ps;
            m_run = mnew;
            oacc[0] = oacc[0] * sc;
            oacc[1] = oacc[1] * sc;
        }

        // P -> bf16 (single plane) -> per-wave LDS (chunk-XOR swizzle)
        const int g = lane >> 4;
        #pragma unroll
        for (int s = 0; s < 4; ++s) {
            int qrow = lane & 15;
            int chunk = (2 * s + (g >> 1)) ^ (qrow & 7);
            char* basep = (char*)p_l[wid] + qrow * 128 + chunk * 16 + 8 * (g & 1);
            #pragma unroll
            for (int h = 0; h < 2; ++h) {
                unsigned pk = (unsigned)f2bf(sa[s][2 * h])
                            | ((unsigned)f2bf(sa[s][2 * h + 1]) << 16);
                *(unsigned*)(basep + 4 * h) = pk;
            }
        }

        // PV: O^T += V^T x P
        #pragma unroll
        for (int ks = 0; ks < 2; ++ks) {
            bf16x8 vf[2], pfh;
            #pragma unroll
            for (int ds = 0; ds < 2; ++ds) {
                int drow = ds * 16 + (lane & 15);
                int chunk = (4 * ks + g) ^ (drow & 7);
                vf[ds] = *(const bf16x8*)((char*)v_l[cur] + drow * 128 + chunk * 16);
            }
            {
                int qrow = lane & 15;
                int chunk = (4 * ks + g) ^ (qrow & 7);
                pfh = *(const bf16x8*)((char*)p_l[wid] + qrow * 128 + chunk * 16);
            }
            #pragma unroll
            for (int ds = 0; ds < 2; ++ds)
                oacc[ds] = __builtin_amdgcn_mfma_f32_16x16x32_bf16(vf[ds], pfh, oacc[ds], 0, 0, 0);
        }

        asm volatile("s_waitcnt vmcnt(0)" ::: "memory");
        __builtin_amdgcn_s_barrier();
    }

    {
        float inv = 1.0f / l_run;
        int q = q0 + wid * 16 + (lane & 15);
        int rr = q >> 5, cc = q & 31;
        float* yb = yw + ((size_t)((br * 4 + b) * 256 + n * 32 + rr)) * HW + cc * 32;
        #pragma unroll
        for (int ds = 0; ds < 2; ++ds) {
            int dbase = ds * 16 + (lane >> 4) * 4;
            float4 o = make_float4(oacc[ds][0] * inv, oacc[ds][1] * inv,
                                   oacc[ds][2] * inv, oacc[ds][3] * inv);
            *reinterpret_cast<float4*>(yb + dbase) = o;
        }
    }
}

// ---------------------------------------------------------------------------
// conv1x1: 512-pixel tile, 2 pixels/thread, ci-chunks of 16 (unchanged).
// ---------------------------------------------------------------------------
__global__ __launch_bounds__(256) void conv1x1_kernel(
    const float* __restrict__ yw, const float* __restrict__ Wo,
    const float* __restrict__ bo, float* __restrict__ out)
{
    const int co0  = blockIdx.x * 16;
    const int p0   = blockIdx.y * 512;
    const int slab = blockIdx.z;
    const float* yb = yw + (size_t)slab * 256 * HW;
    float* ob       = out + (size_t)slab * 256 * HW;

    __shared__ float ys[16][512];
    __shared__ float wsl[16][16];

    const int tid = threadIdx.x;
    float acc0[16], acc1[16];
    #pragma unroll
    for (int co = 0; co < 16; ++co) { acc0[co] = 0.f; acc1[co] = 0.f; }

    for (int ci0 = 0; ci0 < 256; ci0 += 16) {
        __syncthreads();
        for (int idx = tid; idx < 16 * 512; idx += 256) {
            int ci = idx >> 9, p = idx & 511;
            ys[ci][p] = yb[(size_t)(ci0 + ci) * HW + p0 + p];
        }
        {
            int ci = tid >> 4, co = tid & 15;
            wsl[ci][co] = Wo[(size_t)(co0 + co) * 256 + ci0 + ci];
        }
        __syncthreads();
        #pragma unroll
        for (int ci = 0; ci < 16; ++ci) {
            float xv0 = ys[ci][tid];
            float xv1 = ys[ci][tid + 256];
            const float4* wp = reinterpret_cast<const float4*>(&wsl[ci][0]);
            float4 w0 = wp[0], w1 = wp[1], w2 = wp[2], w3 = wp[3];
            acc0[0]  = fmaf(w0.x, xv0, acc0[0]);  acc1[0]  = fmaf(w0.x, xv1, acc1[0]);
            acc0[1]  = fmaf(w0.y, xv0, acc0[1]);  acc1[1]  = fmaf(w0.y, xv1, acc1[1]);
            acc0[2]  = fmaf(w0.z, xv0, acc0[2]);  acc1[2]  = fmaf(w0.z, xv1, acc1[2]);
            acc0[3]  = fmaf(w0.w, xv0, acc0[3]);  acc1[3]  = fmaf(w0.w, xv1, acc1[3]);
            acc0[4]  = fmaf(w1.x, xv0, acc0[4]);  acc1[4]  = fmaf(w1.x, xv1, acc1[4]);
            acc0[5]  = fmaf(w1.y, xv0, acc0[5]);  acc1[5]  = fmaf(w1.y, xv1, acc1[5]);
            acc0[6]  = fmaf(w1.z, xv0, acc0[6]);  acc1[6]  = fmaf(w1.z, xv1, acc1[6]);
            acc0[7]  = fmaf(w1.w, xv0, acc0[7]);  acc1[7]  = fmaf(w1.w, xv1, acc1[7]);
            acc0[8]  = fmaf(w2.x, xv0, acc0[8]);  acc1[8]  = fmaf(w2.x, xv1, acc1[8]);
            acc0[9]  = fmaf(w2.y, xv0, acc0[9]);  acc1[9]  = fmaf(w2.y, xv1, acc1[9]);
            acc0[10] = fmaf(w2.z, xv0, acc0[10]); acc1[10] = fmaf(w2.z, xv1, acc1[10]);
            acc0[11] = fmaf(w2.w, xv0, acc0[11]); acc1[11] = fmaf(w2.w, xv1, acc1[11]);
            acc0[12] = fmaf(w3.x, xv0, acc0[12]); acc1[12] = fmaf(w3.x, xv1, acc1[12]);
            acc0[13] = fmaf(w3.y, xv0, acc0[13]); acc1[13] = fmaf(w3.y, xv1, acc1[13]);
            acc0[14] = fmaf(w3.z, xv0, acc0[14]); acc1[14] = fmaf(w3.z, xv1, acc1[14]);
            acc0[15] = fmaf(w3.w, xv0, acc0[15]); acc1[15] = fmaf(w3.w, xv1, acc1[15]);
        }
    }
    #pragma unroll
    for (int co = 0; co < 16; ++co) {
        float bb = bo[co0 + co];
        ob[(size_t)(co0 + co) * HW + p0 + tid]       = acc0[co] + bb;
        ob[(size_t)(co0 + co) * HW + p0 + tid + 256] = acc1[co] + bb;
    }
}

// ---------------------------------------------------------------------------
extern "C" void kernel_launch(void* const* d_in, const int* in_sizes, int n_in,
                              void* d_out, int out_size, void* d_ws, size_t ws_size,
                              hipStream_t stream)
{
    const float* x1   = (const float*)d_in[0];
    const float* x2   = (const float*)d_in[1];
    const float* x12  = (const float*)d_in[2];
    const float* Wq1  = (const float*)d_in[3];
    const float* bq1  = (const float*)d_in[4];
    const float* Wq2  = (const float*)d_in[5];
    const float* bq2  = (const float*)d_in[6];
    const float* Wq12 = (const float*)d_in[7];
    const float* bq12 = (const float*)d_in[8];
    const float* Wo   = (const float*)d_in[9];
    const float* bo   = (const float*)d_in[10];
    const float* krw  = (const float*)d_in[11];
    const float* krh  = (const float*)d_in[12];

    // workspace layout (identical to R4-R13)
    char* base = (char*)d_ws;
    float*    Qf    = (float*)base;
    float*    yw    = (float*)base;                      // alias: attn out
    ushort_t* Kb    = (ushort_t*)(base + 12582912);
    ushort_t* Vb    = (ushort_t*)(base + 18874368);
    ushort_t* QThi  = (ushort_t*)(base + 25165824);
    ushort_t* QTlo  = (ushort_t*)(base + 31457280);
    ushort_t* K12T  = (ushort_t*)(base + 37748736);
    ushort_t* KdT   = (ushort_t*)(base + 39845888);
    float*    RWp   = (float*)(base + 41943040);
    float*    RHp   = (float*)(base + 46137344);
    ushort_t* Wb    = (ushort_t*)(base + 25165824);      // alias, dead after conv
    ushort_t* xpadT = (ushort_t*)(base + 35782656);      // alias, dead after conv
    float*    outf  = (float*)d_out;

    const size_t xpad_bytes = (size_t)12 * 34 * 34 * 256 * 2;
    hipMemsetAsync(xpadT, 0, xpad_bytes, stream);

    hipLaunchKernelGGL(prep_x_kernel, dim3(32, 12), dim3(256), 0, stream,
                       x1, x2, x12, xpadT);
    hipLaunchKernelGGL(prep_w_kernel, dim3(2304), dim3(256), 0, stream,
                       Wq1, Wq2, Wq12, Wb);
    hipLaunchKernelGGL(conv_mfma_kernel, dim3(16, 6, 12), dim3(256), 0, stream,
                       Wb, xpadT, bq1, bq2, bq12, Qf, Kb, Vb);
    hipLaunchKernelGGL(trans_kernel, dim3(4, 160), dim3(256), 0, stream,
                       Qf, Kb, QThi, QTlo, K12T, KdT);
    hipLaunchKernelGGL(rel_kernel, dim3(4, 2, 32), dim3(256), 0, stream,
                       Qf, krw, krh, RWp, RHp);
    hipLaunchKernelGGL(attn_mfma_kernel, dim3(16, 32, 3), dim3(256), 0, stream,
                       QThi, QTlo, K12T, KdT, Vb, RWp, RHp, yw);
    hipLaunchKernelGGL(conv1x1_kernel, dim3(16, 2, 12), dim3(256), 0, stream,
                       yw, Wo, bo, outf);
}

// Round 15
// 228.631 us; speedup vs baseline: 1.1065x; 1.0014x over previous
//
#include <hip/hip_runtime.h>
#include <math.h>

#define HW   1024
#define NCH  768

typedef __bf16 bf16x8 __attribute__((ext_vector_type(8)));
typedef float f32x4 __attribute__((ext_vector_type(4)));
typedef unsigned short ushort_t;

__device__ __forceinline__ ushort_t f2bf(float f) {
    unsigned u = __builtin_bit_cast(unsigned, f);
    u += 0x7fffu + ((u >> 16) & 1u);           // round-to-nearest-even
    return (ushort_t)(u >> 16);
}
__device__ __forceinline__ float bf2f(ushort_t s) {
    unsigned u = ((unsigned)s) << 16;
    return __builtin_bit_cast(float, u);
}

#define GLOAD16(g, l) __builtin_amdgcn_global_load_lds( \
    (const __attribute__((address_space(1))) void*)(g), \
    (__attribute__((address_space(3))) void*)(l), 16, 0, 0)

// ---------------------------------------------------------------------------
// prep_x: x [img][b][256][32][32] fp32 -> xpadT [slab][34][34][256] bf16.
// (halo zeroed by hipMemsetAsync before this kernel.)
// ---------------------------------------------------------------------------
__global__ __launch_bounds__(256) void prep_x_kernel(
    const float* __restrict__ x1, const float* __restrict__ x2, const float* __restrict__ x12,
    ushort_t* __restrict__ xpadT)
{
    const int row  = blockIdx.x;
    const int slab = blockIdx.y;
    const int img  = slab >> 2, b = slab & 3;
    const float* x  = (img == 0) ? x1 : (img == 1) ? x2 : x12;
    const float* xb = x + (size_t)b * 256 * HW + row * 32;

    __shared__ float xs[32][257];
    const int tid = threadIdx.x;
    for (int idx = tid; idx < 256 * 32; idx += 256) {
        int ci = idx >> 5, col = idx & 31;
        xs[col][ci] = xb[(size_t)ci * HW + col];
    }
    __syncthreads();
    ushort_t* ob = xpadT + ((size_t)slab * 34 * 34 + (size_t)(row + 1) * 34 + 1) * 256;
    for (int col = 0; col < 32; ++col)
        ob[(size_t)col * 256 + tid] = f2bf(xs[col][tid]);
}

// ---------------------------------------------------------------------------
// prep_w: pre-swizzled bf16 A-tiles for conv (unchanged).
// ---------------------------------------------------------------------------
__global__ __launch_bounds__(256) void prep_w_kernel(
    const float* __restrict__ W1, const float* __restrict__ W2, const float* __restrict__ W3,
    ushort_t* __restrict__ Wb)
{
    int g = blockIdx.x * 256 + threadIdx.x;
    if (g >= 3 * 768 * 256) return;
    int ci  = g & 255;
    int co  = (g >> 8) % 768;
    int img = g / (768 * 256);
    const float* Wt  = (img == 0) ? W1 : (img == 1) ? W2 : W3;
    const float* src = Wt + (size_t)co * (256 * 9) + ci * 9;

    int coc = co >> 7, row = co & 127;
    int cic = ci >> 5;
    int cil = ci & 31;
    int s = cil >> 3, e = cil & 7;
    int phys  = s ^ ((row ^ (row >> 2)) & 3);
    int inner = row * 32 + phys * 8 + e;
    #pragma unroll
    for (int t = 0; t < 9; ++t) {
        size_t tile = (((size_t)img * 9 + t) * 8 + cic) * 6 + coc;
        Wb[tile * 4096 + inner] = f2bf(src[t]);
    }
}

// ---------------------------------------------------------------------------
// conv_mfma: implicit-GEMM 3x3 conv with XCD-aware bijective block remap
// (R11/R13 exact; FETCH_SIZE 49->21 MB verified).
// ---------------------------------------------------------------------------
__global__ __launch_bounds__(256) void conv_mfma_kernel(
    const ushort_t* __restrict__ Wb, const ushort_t* __restrict__ xpadT,
    const float* __restrict__ B1, const float* __restrict__ B2, const float* __restrict__ B3,
    float* __restrict__ Qf, ushort_t* __restrict__ Kb, ushort_t* __restrict__ Vb)
{
    // XCD-aware remap (pure index math; per-block work unchanged)
    const int orig = blockIdx.x + 16 * (blockIdx.y + 6 * blockIdx.z);
    const int swz  = (orig & 7) * 144 + (orig >> 3);
    const int bx   = swz & 15;            // p-tile (64 pixels = 2 image rows)
    const int by   = (swz >> 4) % 6;      // co-tile (128 ch)
    const int slab = swz / 96;            // img*4 + b
    const int img  = slab >> 2;
    const float* Bs_bias = (img == 0) ? B1 : (img == 1) ? B2 : B3;

    __shared__ ushort_t As[2][4096];   // [128 co][4 slot][8] swizzled
    __shared__ ushort_t Bsh[2][2048];  // [64 p ][4 slot][8] swizzled

    const int tid  = threadIdx.x;
    const int lane = tid & 63;
    const int wid  = tid >> 6;
    const int wr   = wid >> 1, wc = wid & 1;

    const ushort_t* WbI = Wb + (size_t)img * 9 * 8 * 6 * 4096;
    const ushort_t* xpI = xpadT + (size_t)slab * 34 * 34 * 256;
    const int r0 = bx * 2;            // first image row of this tile

    size_t pixoff;
    {
        int o    = tid * 16;
        int p    = o >> 6;
        int phys = (o >> 4) & 3;
        int s    = phys ^ ((p ^ (p >> 2)) & 3);
        int pr   = p >> 5, c = p & 31;
        pixoff = ((size_t)((r0 + pr) * 34 + c)) * 256 + s * 8;
    }

    f32x4 acc[4][2];
    #pragma unroll
    for (int m = 0; m < 4; ++m)
        #pragma unroll
        for (int n = 0; n < 2; ++n) acc[m][n] = (f32x4){0.f, 0.f, 0.f, 0.f};

    int aoff[4], boff[2];
    #pragma unroll
    for (int m = 0; m < 4; ++m) {
        int row  = wr * 64 + m * 16 + (lane & 15);
        int phys = (lane >> 4) ^ ((row ^ (row >> 2)) & 3);
        aoff[m] = row * 32 + phys * 8;
    }
    #pragma unroll
    for (int n = 0; n < 2; ++n) {
        int row  = wc * 32 + n * 16 + (lane & 15);
        int phys = (lane >> 4) ^ ((row ^ (row >> 2)) & 3);
        boff[n] = row * 32 + phys * 8;
    }

    auto stage = [&](int kk, int buf) {
        int t = kk >> 3, cic = kk & 7;
        int dy = t / 3, dx = t - dy * 3;
        int koff = (dy * 34 + dx) * 256 + cic * 32;              // wave-uniform
        const ushort_t* wtile = WbI + ((size_t)(t * 8 + cic) * 6 + by) * 4096;
        #pragma unroll
        for (int r = 0; r < 2; ++r)
            GLOAD16(wtile + r * 2048 + tid * 8, (ushort_t*)As[buf] + r * 2048 + tid * 8);
        GLOAD16(xpI + pixoff + koff, (ushort_t*)Bsh[buf] + tid * 8);
    };

    stage(0, 0);
    asm volatile("s_waitcnt vmcnt(0)" ::: "memory");
    __builtin_amdgcn_s_barrier();

    for (int kk = 0; kk < 72; ++kk) {
        int cur = kk & 1;
        if (kk < 71) stage(kk + 1, cur ^ 1);

        const ushort_t* Ab = As[cur];
        const ushort_t* Bb = Bsh[cur];
        bf16x8 af[4], bfr[2];
        #pragma unroll
        for (int m = 0; m < 4; ++m) af[m] = *(const bf16x8*)(Ab + aoff[m]);
        #pragma unroll
        for (int n = 0; n < 2; ++n) bfr[n] = *(const bf16x8*)(Bb + boff[n]);

        #pragma unroll
        for (int m = 0; m < 4; ++m)
            #pragma unroll
            for (int n = 0; n < 2; ++n)
                acc[m][n] = __builtin_amdgcn_mfma_f32_16x16x32_bf16(af[m], bfr[n], acc[m][n], 0, 0, 0);

        asm volatile("s_waitcnt vmcnt(0)" ::: "memory");
        __builtin_amdgcn_s_barrier();
    }

    const int co_base = by * 128 + wr * 64;
    const int p_base  = bx * 64 + wc * 32;
    const int rsub = (lane >> 4) * 4;
    const int csub = lane & 15;
    #pragma unroll
    for (int m = 0; m < 4; ++m) {
        #pragma unroll
        for (int rg = 0; rg < 4; ++rg) {
            int ch = co_base + m * 16 + rsub + rg;
            float bias = Bs_bias[ch];
            #pragma unroll
            for (int nn = 0; nn < 2; ++nn) {
                int p = p_base + nn * 16 + csub;
                float v = acc[m][nn][rg] + bias;
                if (ch < 256)
                    Qf[((size_t)slab * 256 + ch) * HW + p] = v * 0.17677669529663687f;
                else if (ch < 512)
                    Kb[((size_t)slab * 256 + (ch - 256)) * HW + p] = f2bf(v);
                else
                    Vb[((size_t)slab * 256 + (ch - 512)) * HW + p] = f2bf(v);
            }
        }
    }
}

// ---------------------------------------------------------------------------
// trans_kernel: build attention MFMA operand tensors (unchanged).
// ---------------------------------------------------------------------------
__global__ __launch_bounds__(256) void trans_kernel(
    const float* __restrict__ Qf, const ushort_t* __restrict__ Kb,
    ushort_t* __restrict__ QThi, ushort_t* __restrict__ QTlo,
    ushort_t* __restrict__ K12T, ushort_t* __restrict__ KdT)
{
    const int z  = blockIdx.y;
    const int k0 = blockIdx.x * 256;
    const int tid = threadIdx.x;
    __shared__ float ts[32][257];

    if (z < 96) {
        int slab = z >> 3, n = z & 7;
        const float* src = Qf + ((size_t)slab * 256 + n * 32) * HW + k0;
        for (int idx = tid; idx < 8192; idx += 256) {
            int d = idx >> 8, k = idx & 255;
            ts[d][k] = src[(size_t)d * HW + k];
        }
        __syncthreads();
        ushort_t* dh = QThi + (size_t)z * 32768 + (size_t)k0 * 32;
        ushort_t* dl = QTlo + (size_t)z * 32768 + (size_t)k0 * 32;
        for (int idx = tid; idx < 8192; idx += 256) {
            int k = idx >> 5, d = idx & 31;
            float v = ts[d][k];
            ushort_t hi = f2bf(v);
            dh[(size_t)k * 32 + d] = hi;
            dl[(size_t)k * 32 + d] = f2bf(v - bf2f(hi));
        }
    } else if (z < 128) {
        int bn = z - 96, b = bn >> 3, n = bn & 7;
        const ushort_t* src = Kb + ((size_t)(8 + b) * 256 + n * 32) * HW + k0;
        for (int idx = tid; idx < 8192; idx += 256) {
            int d = idx >> 8, k = idx & 255;
            ts[d][k] = bf2f(src[(size_t)d * HW + k]);
        }
        __syncthreads();
        ushort_t* dst = K12T + (size_t)bn * 32768 + (size_t)k0 * 32;
        for (int idx = tid; idx < 8192; idx += 256) {
            int k = idx >> 5, d = idx & 31;
            dst[(size_t)k * 32 + d] = f2bf(ts[d][k]);
        }
    } else {
        int bn = z - 128, b = bn >> 3, n = bn & 7;
        const ushort_t* sA = Kb + ((size_t)b * 256 + n * 32) * HW + k0;
        const ushort_t* sB = Kb + ((size_t)(4 + b) * 256 + n * 32) * HW + k0;
        for (int idx = tid; idx < 8192; idx += 256) {
            int d = idx >> 8, k = idx & 255;
            ts[d][k] = bf2f(sA[(size_t)d * HW + k]) - bf2f(sB[(size_t)d * HW + k]);
        }
        __syncthreads();
        ushort_t* dst = KdT + (size_t)bn * 32768 + (size_t)k0 * 32;
        for (int idx = tid; idx < 8192; idx += 256) {
            int k = idx >> 5, d = idx & 31;
            dst[(size_t)k * 32 + d] = f2bf(ts[d][k]);
        }
    }
}

// ---------------------------------------------------------------------------
// rel_kernel: RW'/RH' tables from FP32 Q. grid (4 qchunk, 2 mhalf, 32 bn).
// ---------------------------------------------------------------------------
__global__ __launch_bounds__(256) void rel_kernel(
    const float* __restrict__ Qf,
    const float* __restrict__ krw, const float* __restrict__ krh,
    float* __restrict__ RWp, float* __restrict__ RHp)
{
    const int tid = threadIdx.x;
    const int mh  = blockIdx.y;
    const int bn  = blockIdx.z;
    const int b   = bn >> 3, n = bn & 7;
    const int q   = blockIdx.x * 256 + tid;
    const int r   = q >> 5, c = q & 31;

    __shared__ float rwl[63 * 33 + 1];
    __shared__ float rhl[63 * 33 + 1];
    for (int idx = tid; idx < 63 * 32; idx += 256) {
        int mp = idx >> 5, d = idx & 31;
        rwl[mp * 33 + d] = krw[idx];
        rhl[mp * 33 + d] = krh[idx];
    }
    __syncthreads();

    float qv[32];
    const float* qp = Qf + ((size_t)b * 256 + n * 32) * HW;
    #pragma unroll
    for (int d = 0; d < 32; ++d) qv[d] = qp[(size_t)d * HW + q];

    float* rw = RWp + ((size_t)bn * 1024 + q) * 32;
    float* rh = RHp + ((size_t)bn * 1024 + q) * 32;
    #pragma unroll
    for (int m = 0; m < 16; ++m) {
        int mm = mh * 16 + m;
        const float* t1 = rwl + (mm + 31 - c) * 33;
        const float* t2 = rhl + (mm + 31 - r) * 33;
        float s1 = 0.f, s2 = 0.f;
        #pragma unroll
        for (int d = 0; d < 32; ++d) { s1 = fmaf(qv[d], t1[d], s1); s2 = fmaf(qv[d], t2[d], s2); }
        rw[mm] = s1;
        rh[mm] = s2;
    }
}

// ---------------------------------------------------------------------------
// attn_mfma: flash attention, swapped operands (S^T = K x Q).
// Q-SPLIT version (R14 exact): 64 queries/block, wave owns 16 q.
// grid (16 qtiles, 32 bn, 3 br) = 1536 blocks (6/CU).
// LDS = qt 8KB + kt 8KB + v 8KB + p 8KB = 32KB -> 5 blocks/CU cap.
// ---------------------------------------------------------------------------
__global__ __launch_bounds__(256) void attn_mfma_kernel(
    const ushort_t* __restrict__ QThi, const ushort_t* __restrict__ QTlo,
    const ushort_t* __restrict__ K12T, const ushort_t* __restrict__ KdT,
    const ushort_t* __restrict__ Vb,
    const float* __restrict__ RWp, const float* __restrict__ RHp,
    float* __restrict__ yw)
{
    const int qt = blockIdx.x;
    const int bn = blockIdx.y;
    const int br = blockIdx.z;
    const int b  = bn >> 3, n = bn & 7;
    const int tid = threadIdx.x, lane = tid & 63, wid = tid >> 6;
    const int q0 = qt * 64;

    __shared__ ushort_t qt_l[2][2048];     // [hi/lo][64 q][32 d] linear
    __shared__ ushort_t kt_l[2][2048];     // [64 k][32 d] linear (dbuf)
    __shared__ ushort_t v_l[2][2048];      // [32 d][64 k], chunk^(d&7) (dbuf)
    __shared__ ushort_t p_l[4][1024];      // per-wave [16 q][64 k], chunk-XOR

    const int slab = br * 4 + b;
    const size_t qoff = ((size_t)(slab * 8 + n) * 1024 + q0) * 32;
    const ushort_t* KTb = ((br == 2) ? KdT : K12T) + (size_t)bn * 32768;
    const ushort_t* Vg  = Vb + ((size_t)slab * 256 + n * 32) * HW;

    GLOAD16((const char*)(QThi + qoff) + tid * 16, (char*)qt_l[0] + tid * 16);
    GLOAD16((const char*)(QTlo + qoff) + tid * 16, (char*)qt_l[1] + tid * 16);

    const int vd = tid >> 3, vpc = tid & 7;
    const char* Vrow = (const char*)Vg + (size_t)vd * 2048 + ((vpc ^ (vd & 7)) * 16);
    auto stage = [&](int t, int buf) {
        GLOAD16((const char*)KTb + t * 4096 + tid * 16, (char*)kt_l[buf] + tid * 16);
        GLOAD16(Vrow + t * 128,                          (char*)v_l[buf] + tid * 16);
    };
    stage(0, 0);

    float rwc[8];
    if (br == 0) {
        int q = q0 + wid * 16 + (lane & 15);
        const float* rwp = RWp + ((size_t)bn * 1024 + q) * 32;
        #pragma unroll
        for (int i = 0; i < 2; ++i)
            #pragma unroll
            for (int r = 0; r < 4; ++r)
                rwc[i * 4 + r] = rwp[i * 16 + 4 * (lane >> 4) + r];
    }

    asm volatile("s_waitcnt vmcnt(0)" ::: "memory");
    __builtin_amdgcn_s_barrier();

    bf16x8 qfh, qfl;
    {
        int off = (wid * 16 + (lane & 15)) * 32 + (lane >> 4) * 8;
        qfh = *(const bf16x8*)(qt_l[0] + off);
        qfl = *(const bf16x8*)(qt_l[1] + off);
    }

    f32x4 oacc[2];
    #pragma unroll
    for (int ds = 0; ds < 2; ++ds) oacc[ds] = (f32x4){0.f, 0.f, 0.f, 0.f};
    float m_run = -INFINITY, l_run = 0.f;
    const f32x4 zero4 = (f32x4){0.f, 0.f, 0.f, 0.f};

    for (int t = 0; t < 16; ++t) {
        int cur = t & 1;

        float rh[2];
        if (br == 0) {
            int q = q0 + wid * 16 + (lane & 15);
            const float* rhp = RHp + ((size_t)bn * 1024 + q) * 32 + 2 * t;
            rh[0] = rhp[0];
            rh[1] = rhp[1];
        }
        if (t < 15) stage(t + 1, cur ^ 1);

        bf16x8 kf[4];
        #pragma unroll
        for (int s = 0; s < 4; ++s)
            kf[s] = *(const bf16x8*)(kt_l[cur] + (s * 16 + (lane & 15)) * 32 + (lane >> 4) * 8);

        f32x4 sa[4];
        #pragma unroll
        for (int s = 0; s < 4; ++s) {
            sa[s] = __builtin_amdgcn_mfma_f32_16x16x32_bf16(kf[s], qfl, zero4, 0, 0, 0);
            sa[s] = __builtin_amdgcn_mfma_f32_16x16x32_bf16(kf[s], qfh, sa[s], 0, 0, 0);
        }

        if (br == 0) {
            #pragma unroll
            for (int s = 0; s < 4; ++s)
                #pragma unroll
                for (int r = 0; r < 4; ++r)
                    sa[s][r] += rwc[(s & 1) * 4 + r] + rh[s >> 1];
        }

        {
            float mx = sa[0][0];
            #pragma unroll
            for (int s = 0; s < 4; ++s)
                #pragma unroll
                for (int r = 0; r < 4; ++r) mx = fmaxf(mx, sa[s][r]);
            mx = fmaxf(mx, __shfl_xor(mx, 16));
            mx = fmaxf(mx, __shfl_xor(mx, 32));
            float mnew = fmaxf(m_run, mx);
            float sc = __expf(m_run - mnew);
            float ps = 0.f;
            #pragma unroll
            for (int s = 0; s < 4; ++s)
                #pragma unroll
                for (int r = 0; r < 4; ++r) {
                    float p = __expf(sa[s][r] - mnew);
                    sa[s][r] = p;
                    ps += p;
                }
            ps += __shfl_xor(ps, 16);
            ps += __shfl_xor(ps, 32);
            l_run = l_run * sc + ps;
            m_run = mnew;
            oacc[0] = oacc[0] * sc;
            oacc[1] = oacc[1] * sc;
        }

        // P -> bf16 (single plane) -> per-wave LDS (chunk-XOR swizzle)
        const int g = lane >> 4;
        #pragma unroll
        for (int s = 0; s < 4; ++s) {
            int qrow = lane & 15;
            int chunk = (2 * s + (g >> 1)) ^ (qrow & 7);
            char* basep = (char*)p_l[wid] + qrow * 128 + chunk * 16 + 8 * (g & 1);
            #pragma unroll
            for (int h = 0; h < 2; ++h) {
                unsigned pk = (unsigned)f2bf(sa[s][2 * h])
                            | ((unsigned)f2bf(sa[s][2 * h + 1]) << 16);
                *(unsigned*)(basep + 4 * h) = pk;
            }
        }

        // PV: O^T += V^T x P
        #pragma unroll
        for (int ks = 0; ks < 2; ++ks) {
            bf16x8 vf[2], pfh;
            #pragma unroll
            for (int ds = 0; ds < 2; ++ds) {
                int drow = ds * 16 + (lane & 15);
                int chunk = (4 * ks + g) ^ (drow & 7);
                vf[ds] = *(const bf16x8*)((char*)v_l[cur] + drow * 128 + chunk * 16);
            }
            {
                int qrow = lane & 15;
                int chunk = (4 * ks + g) ^ (qrow & 7);
                pfh = *(const bf16x8*)((char*)p_l[wid] + qrow * 128 + chunk * 16);
            }
            #pragma unroll
            for (int ds = 0; ds < 2; ++ds)
                oacc[ds] = __builtin_amdgcn_mfma_f32_16x16x32_bf16(vf[ds], pfh, oacc[ds], 0, 0, 0);
        }

        asm volatile("s_waitcnt vmcnt(0)" ::: "memory");
        __builtin_amdgcn_s_barrier();
    }

    {
        float inv = 1.0f / l_run;
        int q = q0 + wid * 16 + (lane & 15);
        int rr = q >> 5, cc = q & 31;
        float* yb = yw + ((size_t)((br * 4 + b) * 256 + n * 32 + rr)) * HW + cc * 32;
        #pragma unroll
        for (int ds = 0; ds < 2; ++ds) {
            int dbase = ds * 16 + (lane >> 4) * 4;
            float4 o = make_float4(oacc[ds][0] * inv, oacc[ds][1] * inv,
                                   oacc[ds][2] * inv, oacc[ds][3] * inv);
            *reinterpret_cast<float4*>(yb + dbase) = o;
        }
    }
}

// ---------------------------------------------------------------------------
// conv1x1: 512-pixel tile, 2 pixels/thread, ci-chunks of 16 (unchanged).
// ---------------------------------------------------------------------------
__global__ __launch_bounds__(256) void conv1x1_kernel(
    const float* __restrict__ yw, const float* __restrict__ Wo,
    const float* __restrict__ bo, float* __restrict__ out)
{
    const int co0  = blockIdx.x * 16;
    const int p0   = blockIdx.y * 512;
    const int slab = blockIdx.z;
    const float* yb = yw + (size_t)slab * 256 * HW;
    float* ob       = out + (size_t)slab * 256 * HW;

    __shared__ float ys[16][512];
    __shared__ float wsl[16][16];

    const int tid = threadIdx.x;
    float acc0[16], acc1[16];
    #pragma unroll
    for (int co = 0; co < 16; ++co) { acc0[co] = 0.f; acc1[co] = 0.f; }

    for (int ci0 = 0; ci0 < 256; ci0 += 16) {
        __syncthreads();
        for (int idx = tid; idx < 16 * 512; idx += 256) {
            int ci = idx >> 9, p = idx & 511;
            ys[ci][p] = yb[(size_t)(ci0 + ci) * HW + p0 + p];
        }
        {
            int ci = tid >> 4, co = tid & 15;
            wsl[ci][co] = Wo[(size_t)(co0 + co) * 256 + ci0 + ci];
        }
        __syncthreads();
        #pragma unroll
        for (int ci = 0; ci < 16; ++ci) {
            float xv0 = ys[ci][tid];
            float xv1 = ys[ci][tid + 256];
            const float4* wp = reinterpret_cast<const float4*>(&wsl[ci][0]);
            float4 w0 = wp[0], w1 = wp[1], w2 = wp[2], w3 = wp[3];
            acc0[0]  = fmaf(w0.x, xv0, acc0[0]);  acc1[0]  = fmaf(w0.x, xv1, acc1[0]);
            acc0[1]  = fmaf(w0.y, xv0, acc0[1]);  acc1[1]  = fmaf(w0.y, xv1, acc1[1]);
            acc0[2]  = fmaf(w0.z, xv0, acc0[2]);  acc1[2]  = fmaf(w0.z, xv1, acc1[2]);
            acc0[3]  = fmaf(w0.w, xv0, acc0[3]);  acc1[3]  = fmaf(w0.w, xv1, acc1[3]);
            acc0[4]  = fmaf(w1.x, xv0, acc0[4]);  acc1[4]  = fmaf(w1.x, xv1, acc1[4]);
            acc0[5]  = fmaf(w1.y, xv0, acc0[5]);  acc1[5]  = fmaf(w1.y, xv1, acc1[5]);
            acc0[6]  = fmaf(w1.z, xv0, acc0[6]);  acc1[6]  = fmaf(w1.z, xv1, acc1[6]);
            acc0[7]  = fmaf(w1.w, xv0, acc0[7]);  acc1[7]  = fmaf(w1.w, xv1, acc1[7]);
            acc0[8]  = fmaf(w2.x, xv0, acc0[8]);  acc1[8]  = fmaf(w2.x, xv1, acc1[8]);
            acc0[9]  = fmaf(w2.y, xv0, acc0[9]);  acc1[9]  = fmaf(w2.y, xv1, acc1[9]);
            acc0[10] = fmaf(w2.z, xv0, acc0[10]); acc1[10] = fmaf(w2.z, xv1, acc1[10]);
            acc0[11] = fmaf(w2.w, xv0, acc0[11]); acc1[11] = fmaf(w2.w, xv1, acc1[11]);
            acc0[12] = fmaf(w3.x, xv0, acc0[12]); acc1[12] = fmaf(w3.x, xv1, acc1[12]);
            acc0[13] = fmaf(w3.y, xv0, acc0[13]); acc1[13] = fmaf(w3.y, xv1, acc1[13]);
            acc0[14] = fmaf(w3.z, xv0, acc0[14]); acc1[14] = fmaf(w3.z, xv1, acc1[14]);
            acc0[15] = fmaf(w3.w, xv0, acc0[15]); acc1[15] = fmaf(w3.w, xv1, acc1[15]);
        }
    }
    #pragma unroll
    for (int co = 0; co < 16; ++co) {
        float bb = bo[co0 + co];
        ob[(size_t)(co0 + co) * HW + p0 + tid]       = acc0[co] + bb;
        ob[(size_t)(co0 + co) * HW + p0 + tid + 256] = acc1[co] + bb;
    }
}

// ---------------------------------------------------------------------------
extern "C" void kernel_launch(void* const* d_in, const int* in_sizes, int n_in,
                              void* d_out, int out_size, void* d_ws, size_t ws_size,
                              hipStream_t stream)
{
    const float* x1   = (const float*)d_in[0];
    const float* x2   = (const float*)d_in[1];
    const float* x12  = (const float*)d_in[2];
    const float* Wq1  = (const float*)d_in[3];
    const float* bq1  = (const float*)d_in[4];
    const float* Wq2  = (const float*)d_in[5];
    const float* bq2  = (const float*)d_in[6];
    const float* Wq12 = (const float*)d_in[7];
    const float* bq12 = (const float*)d_in[8];
    const float* Wo   = (const float*)d_in[9];
    const float* bo   = (const float*)d_in[10];
    const float* krw  = (const float*)d_in[11];
    const float* krh  = (const float*)d_in[12];

    // workspace layout (identical to R4-R14)
    char* base = (char*)d_ws;
    float*    Qf    = (float*)base;
    float*    yw    = (float*)base;                      // alias: attn out
    ushort_t* Kb    = (ushort_t*)(base + 12582912);
    ushort_t* Vb    = (ushort_t*)(base + 18874368);
    ushort_t* QThi  = (ushort_t*)(base + 25165824);
    ushort_t* QTlo  = (ushort_t*)(base + 31457280);
    ushort_t* K12T  = (ushort_t*)(base + 37748736);
    ushort_t* KdT   = (ushort_t*)(base + 39845888);
    float*    RWp   = (float*)(base + 41943040);
    float*    RHp   = (float*)(base + 46137344);
    ushort_t* Wb    = (ushort_t*)(base + 25165824);      // alias, dead after conv
    ushort_t* xpadT = (ushort_t*)(base + 35782656);      // alias, dead after conv
    float*    outf  = (float*)d_out;

    const size_t xpad_bytes = (size_t)12 * 34 * 34 * 256 * 2;
    hipMemsetAsync(xpadT, 0, xpad_bytes, stream);

    hipLaunchKernelGGL(prep_x_kernel, dim3(32, 12), dim3(256), 0, stream,
                       x1, x2, x12, xpadT);
    hipLaunchKernelGGL(prep_w_kernel, dim3(2304), dim3(256), 0, stream,
                       Wq1, Wq2, Wq12, Wb);
    hipLaunchKernelGGL(conv_mfma_kernel, dim3(16, 6, 12), dim3(256), 0, stream,
                       Wb, xpadT, bq1, bq2, bq12, Qf, Kb, Vb);
    hipLaunchKernelGGL(trans_kernel, dim3(4, 160), dim3(256), 0, stream,
                       Qf, Kb, QThi, QTlo, K12T, KdT);
    hipLaunchKernelGGL(rel_kernel, dim3(4, 2, 32), dim3(256), 0, stream,
                       Qf, krw, krh, RWp, RHp);
    hipLaunchKernelGGL(attn_mfma_kernel, dim3(16, 32, 3), dim3(256), 0, stream,
                       QThi, QTlo, K12T, KdT, Vb, RWp, RHp, yw);
    hipLaunchKernelGGL(conv1x1_kernel, dim3(16, 2, 12), dim3(256), 0, stream,
                       yw, Wo, bo, outf);
}